// Round 12
// baseline (970.683 us; speedup 1.0000x reference)
//
#include <hip/hip_runtime.h>
#include <hip/hip_fp16.h>
#include <math.h>

#define DEV __device__ __forceinline__

constexpr int NGAUSS = 50;
constexpr int LAY = 6;
constexpr int K_TAB = 8192;
constexpr float DMAX = 40.0f;
constexpr float TSCALE = (float)(K_TAB - 1) / DMAX;   // fid = d * TSCALE
constexpr float STEP = 6.0f / 49.0f;
constexpr float COEFF = -0.5f / (STEP * STEP);
constexpr float LN2F = 0.69314718055994531f;
constexpr float PI_OVER_CUT = 0.52359877559829887f;  // pi/6

using f16x8 = __attribute__((ext_vector_type(8))) _Float16;
using f16x4 = __attribute__((ext_vector_type(4))) _Float16;
using f32x4 = __attribute__((ext_vector_type(4))) float;

#define MFMA16(a, b, c) __builtin_amdgcn_mfma_f32_16x16x32_f16(a, b, c, 0, 0, 0)

DEV float sspf(float x) {
    float ax = fabsf(x);
    float e = __expf(-ax);
    return fmaxf(x, 0.f) + __logf(1.f + e) - LN2F;
}

// ---- fp16 pack/unpack helpers (storage fp16, math f32) ----
DEV float4 ld_h4(const ushort* p) {          // 8B load -> 4 floats
    uint2 r = *(const uint2*)p;
    __half2 a = __builtin_bit_cast(__half2, r.x);
    __half2 b = __builtin_bit_cast(__half2, r.y);
    float2 fa = __half22float2(a), fb = __half22float2(b);
    return make_float4(fa.x, fa.y, fb.x, fb.y);
}
DEV void st_h4(ushort* p, float4 v) {        // 4 floats -> 8B store
    uint2 r;
    r.x = __builtin_bit_cast(uint, __float22half2_rn(make_float2(v.x, v.y)));
    r.y = __builtin_bit_cast(uint, __float22half2_rn(make_float2(v.z, v.w)));
    *(uint2*)p = r;
}

// ---------------- weight convert+transpose (fp32 [K][C] -> fp16 [C][K]) ----------------
__global__ void k_cvtT128(const float* __restrict__ src, ushort* __restrict__ dst) {
    const float* s = src + (size_t)blockIdx.x * 16384;
    ushort* d = dst + (size_t)blockIdx.x * 16384;
    for (int i = threadIdx.x; i < 16384; i += 256) {
        int k = i >> 7, c = i & 127;
        d[(c << 7) + k] = __builtin_bit_cast(ushort, (_Float16)s[i]);
    }
}
__global__ void k_cvtT_fe(const float* __restrict__ src, ushort* __restrict__ dst) {
    // fe_w2: [64][128] -> dst[c(128)][k(64)]
    for (int i = threadIdx.x; i < 8192; i += 256) {
        int k = i >> 7, c = i & 127;
        dst[(c << 6) + k] = __builtin_bit_cast(ushort, (_Float16)src[i]);
    }
}

// ---------------- edge sort pre-pass (once per call) ----------------
__global__ void k_hist(const int* __restrict__ ei, int* __restrict__ counts, int E) {
    int e = blockIdx.x * 256 + threadIdx.x;
    if (e < E) atomicAdd(&counts[ei[E + e]], 1);
}

__global__ void k_scan1(const int* __restrict__ counts, int* __restrict__ locex,
                        int* __restrict__ bsum, int n) {
    __shared__ int s_wsum[16];
    const int tid = threadIdx.x;
    const int i = blockIdx.x * 1024 + tid;
    const int lane = tid & 63, wv = tid >> 6;
    int v = (i < n) ? counts[i] : 0;
    int x = v;
    #pragma unroll
    for (int off = 1; off < 64; off <<= 1) {
        int y = __shfl_up(x, off, 64);
        if (lane >= off) x += y;
    }
    if (lane == 63) s_wsum[wv] = x;
    __syncthreads();
    if (wv == 0 && lane < 16) {
        int wval = s_wsum[lane];
        int wx = wval;
        #pragma unroll
        for (int off = 1; off < 16; off <<= 1) {
            int wy = __shfl_up(wx, off, 16);
            if (lane >= off) wx += wy;
        }
        s_wsum[lane] = wx - wval;
    }
    __syncthreads();
    if (i < n) locex[i] = s_wsum[wv] + x - v;
    if (tid == 1023) bsum[blockIdx.x] = s_wsum[15] + x;
}

__global__ void k_scan2(int* __restrict__ bsum, int nb) {
    __shared__ int s_wsum[16];
    const int tid = threadIdx.x;
    const int lane = tid & 63, wv = tid >> 6;
    int v = (tid < nb) ? bsum[tid] : 0;
    int x = v;
    #pragma unroll
    for (int off = 1; off < 64; off <<= 1) {
        int y = __shfl_up(x, off, 64);
        if (lane >= off) x += y;
    }
    if (lane == 63) s_wsum[wv] = x;
    __syncthreads();
    if (wv == 0 && lane < 16) {
        int wval = s_wsum[lane];
        int wx = wval;
        #pragma unroll
        for (int off = 1; off < 16; off <<= 1) {
            int wy = __shfl_up(wx, off, 16);
            if (lane >= off) wx += wy;
        }
        s_wsum[lane] = wx - wval;
    }
    __syncthreads();
    if (tid < nb) bsum[tid] = s_wsum[wv] + x - v;
}

__global__ void k_scan3(const int* __restrict__ locex, const int* __restrict__ bsumex,
                        int* __restrict__ cursor, int* __restrict__ rowptr, int n) {
    int i = blockIdx.x * 256 + threadIdx.x;
    if (i >= n) return;
    int e = locex[i] + bsumex[i >> 10];
    cursor[i] = e;
    rowptr[i] = e;
}

__global__ void k_scatter(const int* __restrict__ ei, const float* __restrict__ pos,
                          int* __restrict__ cursor, int* __restrict__ s_src,
                          float* __restrict__ s_fid, int E) {
    int e = blockIdx.x * 256 + threadIdx.x;
    if (e >= E) return;
    int r = ei[e], c = ei[E + e];
    int p = atomicAdd(&cursor[c], 1);
    float dx = pos[3 * r + 0] - pos[3 * c + 0];
    float dy = pos[3 * r + 1] - pos[3 * c + 1];
    float dz = pos[3 * r + 2] - pos[3 * c + 2];
    float d = sqrtf(dx * dx + dy * dy + dz * dz);
    s_src[p] = r;
    s_fid[p] = fminf(d * TSCALE, (float)(K_TAB - 2) + 0.999f);
}

// ---------------- gate table build (fp16 output), ALL layers in one launch ----------------
__launch_bounds__(256)
__global__ void k_tab_all(const float* __restrict__ w1A, const float* __restrict__ b1A,
                          const float* __restrict__ w2A, const float* __restrict__ b2A,
                          ushort* __restrict__ tabA) {
    const int layer = blockIdx.x >> 8;
    const int k0 = (blockIdx.x & 255) * 32;
    const float* w1 = w1A + (size_t)layer * NGAUSS * 128;
    const float* b1 = b1A + (size_t)layer * 128;
    const float* w2 = w2A + (size_t)layer * 128 * 128;
    const float* b2 = b2A + (size_t)layer * 128;
    ushort* tab = tabA + (size_t)layer * K_TAB * 128;

    __shared__ float s_demb[32][NGAUSS];
    __shared__ float s_t1[32][128];
    const int tid = threadIdx.x;

    for (int i = tid; i < 32 * NGAUSS; i += 256) {
        int r = i / NGAUSS, g = i - r * NGAUSS;
        float d = (float)(k0 + r) * (1.0f / TSCALE);
        float t = d - g * STEP;
        s_demb[r][g] = __expf(COEFF * t * t);
    }
    __syncthreads();

    const int cg = tid & 31, rg = tid >> 5;
    const int r0 = rg << 2;
    const int c4 = cg << 2;

    float4 b1v = *(const float4*)&b1[c4];
    float4 acc[4];
    #pragma unroll
    for (int i = 0; i < 4; i++) acc[i] = b1v;
    #pragma unroll 2
    for (int k = 0; k < NGAUSS; k++) {
        float4 wv = *(const float4*)&w1[(k << 7) + c4];
        #pragma unroll
        for (int i = 0; i < 4; i++) {
            float dv = s_demb[r0 + i][k];
            acc[i].x = fmaf(dv, wv.x, acc[i].x);
            acc[i].y = fmaf(dv, wv.y, acc[i].y);
            acc[i].z = fmaf(dv, wv.z, acc[i].z);
            acc[i].w = fmaf(dv, wv.w, acc[i].w);
        }
    }
    #pragma unroll
    for (int i = 0; i < 4; i++) {
        float4 t;
        t.x = sspf(acc[i].x); t.y = sspf(acc[i].y);
        t.z = sspf(acc[i].z); t.w = sspf(acc[i].w);
        *(float4*)&s_t1[r0 + i][c4] = t;
    }
    __syncthreads();

    float4 b2v = *(const float4*)&b2[c4];
    float4 a2[4];
    #pragma unroll
    for (int i = 0; i < 4; i++) a2[i] = b2v;
    #pragma unroll 4
    for (int k = 0; k < 128; k++) {
        float4 wv = *(const float4*)&w2[(k << 7) + c4];
        #pragma unroll
        for (int i = 0; i < 4; i++) {
            float tv = s_t1[r0 + i][k];
            a2[i].x = fmaf(tv, wv.x, a2[i].x);
            a2[i].y = fmaf(tv, wv.y, a2[i].y);
            a2[i].z = fmaf(tv, wv.z, a2[i].z);
            a2[i].w = fmaf(tv, wv.w, a2[i].w);
        }
    }
    #pragma unroll
    for (int i = 0; i < 4; i++) {
        int knot = k0 + r0 + i;
        float d = (float)knot * (1.0f / TSCALE);
        float cc = 0.5f * (__cosf(d * PI_OVER_CUT) + 1.0f);
        float4 o;
        o.x = a2[i].x * cc; o.y = a2[i].y * cc;
        o.z = a2[i].z * cc; o.w = a2[i].w * cc;
        st_h4(&tab[((size_t)knot << 7) + c4], o);
    }
}

// ---------------- node-centric CSR edge kernel: masked 8-edge batches, fp16 agg ----------------
// 1 node per 32-lane group; lane owns 4 channels. No scalar tail: indices clamped,
// contributions masked. f32 running sum, fp16 partials (chain <= 4).
__launch_bounds__(256)
__global__ void k_edge_csr(const int* __restrict__ s_src, const float* __restrict__ s_fid,
                           const int* __restrict__ rowptr, const int* __restrict__ counts,
                           const ushort* __restrict__ vlin, const ushort* __restrict__ tab,
                           ushort* __restrict__ agg, int N) {
    const int tid = threadIdx.x;
    const int c4 = (tid & 31) << 2;
    const int n = blockIdx.x * 8 + (tid >> 5);
    if (n >= N) return;
    const ushort* tabc = tab + c4;
    const ushort* vlc = vlin + c4;

    const int rs = rowptr[n];
    const int re = rs + counts[n];
    float4 run = make_float4(0.f, 0.f, 0.f, 0.f);

    for (int e = rs; e < re; e += 8) {
        f16x4 T0[8], T1[8], VL[8];
        _Float16 FR[8], M[8];
        #pragma unroll
        for (int j = 0; j < 8; j++) {
            int ee = e + j;
            bool ok = ee < re;
            M[j] = ok ? (_Float16)1 : (_Float16)0;
            ee = ok ? ee : (re - 1);          // clamp: valid addr, L1-hot
            float fid = s_fid[ee];
            int i0 = (int)fid;
            FR[j] = (_Float16)(fid - (float)i0);
            const ushort* tp = tabc + ((size_t)i0 << 7);
            T0[j] = *(const f16x4*)tp;
            T1[j] = *(const f16x4*)(tp + 128);
            VL[j] = *(const f16x4*)(vlc + ((size_t)s_src[ee] << 7));
        }
        f16x4 p0 = {0, 0, 0, 0}, p1 = {0, 0, 0, 0};
        #pragma unroll
        for (int j = 0; j < 8; j += 2) {
            f16x4 w0 = (T0[j]     + FR[j]     * (T1[j]     - T0[j]))     * M[j];
            f16x4 w1 = (T0[j + 1] + FR[j + 1] * (T1[j + 1] - T0[j + 1])) * M[j + 1];
            p0 += w0 * VL[j];
            p1 += w1 * VL[j + 1];
        }
        run.x += (float)p0[0] + (float)p1[0];
        run.y += (float)p0[1] + (float)p1[1];
        run.z += (float)p0[2] + (float)p1[2];
        run.w += (float)p0[3] + (float)p1[3];
    }
    st_h4(&agg[((size_t)n << 7) + c4], run);
}

// ---------------- feature embedding ----------------
__global__ void k_fe1(const float* __restrict__ x, const float* __restrict__ w,
                      const float* __restrict__ b, float* __restrict__ h, int N) {
    int idx = blockIdx.x * 256 + threadIdx.x;
    if (idx >= N * 64) return;
    int n = idx >> 6, c = idx & 63;
    const float* xr = x + (size_t)n * 28;
    float acc = b[c];
    #pragma unroll
    for (int k = 0; k < 28; k++) acc = fmaf(xr[k], w[k * 64 + c], acc);
    h[idx] = acc;
}

__global__ void k_bnstat(const float* __restrict__ h, float* __restrict__ stats, int N) {
    __shared__ float s_s[256], s_q[256];
    int tid = threadIdx.x;
    int c = tid & 63, g = tid >> 6;
    float s = 0.f, q = 0.f;
    for (int n = blockIdx.x * 4 + g; n < N; n += gridDim.x * 4) {
        float v = h[(size_t)n * 64 + c];
        s += v; q += v * v;
    }
    s_s[tid] = s; s_q[tid] = q;
    __syncthreads();
    if (tid < 64) {
        s = s_s[tid] + s_s[tid + 64] + s_s[tid + 128] + s_s[tid + 192];
        q = s_q[tid] + s_q[tid + 64] + s_q[tid + 128] + s_q[tid + 192];
        atomicAdd(&stats[tid], s);
        atomicAdd(&stats[64 + tid], q);
    }
}

__global__ void k_bnfin(const float* __restrict__ stats, float* __restrict__ prm,
                        const float* __restrict__ gamma, const float* __restrict__ beta,
                        float invN) {
    int c = threadIdx.x;  // 64 threads
    float mu = stats[c] * invN;
    float var = stats[64 + c] * invN - mu * mu;
    float sc = gamma[c] * rsqrtf(var + 1e-5f);
    prm[c] = sc;
    prm[64 + c] = beta[c] - mu * sc;
}

// ---------------- MFMA fe2: v = relu( relu(bn(h)) @ fe_w2 + b2 ), K=64 ----------------
__launch_bounds__(256, 4)
__global__ void k_fe2(const float* __restrict__ h, const float* __restrict__ prm,
                      const ushort* __restrict__ w2T, const float* __restrict__ b2,
                      float* __restrict__ v, int N) {
    constexpr int LDP = 72;
    __shared__ _Float16 sH[64 * LDP];
    const int tid = threadIdx.x;
    const int n0 = blockIdx.x * 64;

    for (int i = tid; i < 64 * 16; i += 256) {
        int row = i >> 4, c4 = (i & 15) << 2;
        int gr = n0 + row;
        float4 hv = (gr < N) ? *(const float4*)&h[((size_t)gr << 6) + c4]
                             : make_float4(0.f, 0.f, 0.f, 0.f);
        float4 sc = *(const float4*)&prm[c4];
        float4 sh = *(const float4*)&prm[64 + c4];
        f16x4 o;
        o[0] = (_Float16)fmaxf(fmaf(hv.x, sc.x, sh.x), 0.f);
        o[1] = (_Float16)fmaxf(fmaf(hv.y, sc.y, sh.y), 0.f);
        o[2] = (_Float16)fmaxf(fmaf(hv.z, sc.z, sh.z), 0.f);
        o[3] = (_Float16)fmaxf(fmaf(hv.w, sc.w, sh.w), 0.f);
        *(f16x4*)&sH[row * LDP + c4] = o;
    }
    __syncthreads();

    const int wid = tid >> 6, lane = tid & 63;
    const int lr = lane & 15, lg = lane >> 4;
    const int kof = lg << 3;
    const int arow = wid * 16 + lr;
    const int drow0 = wid * 16 + (lg << 2);

    f16x8 a0 = *(const f16x8*)&sH[arow * LDP + kof];
    f16x8 a1 = *(const f16x8*)&sH[arow * LDP + 32 + kof];

    #pragma unroll
    for (int n = 0; n < 8; n++) {
        const ushort* bp = w2T + (((size_t)(n << 4) + lr) << 6);
        f32x4 c = {0.f, 0.f, 0.f, 0.f};
        c = MFMA16(a0, *(const f16x8*)(bp + kof), c);
        c = MFMA16(a1, *(const f16x8*)(bp + 32 + kof), c);
        int col = (n << 4) + lr;
        float bb = b2[col];
        #pragma unroll
        for (int r = 0; r < 4; r++) {
            int gr = n0 + drow0 + r;
            if (gr < N) v[((size_t)gr << 7) + col] = fmaxf(c[r] + bb, 0.f);
        }
    }
}

// ---------------- MFMA single GEMM: vlin(fp16) = v @ lin, K=128 ----------------
__launch_bounds__(256, 4)
__global__ void k_gemm_rb(const float* __restrict__ A, const ushort* __restrict__ wT,
                          ushort* __restrict__ C, int N) {
    constexpr int LDP = 136;
    __shared__ _Float16 sA[64 * LDP];
    const int tid = threadIdx.x;
    const int n0 = blockIdx.x * 64;

    for (int i = tid; i < 64 * 32; i += 256) {
        int row = i >> 5, c4 = (i & 31) << 2;
        int gr = n0 + row;
        float4 val = (gr < N) ? *(const float4*)&A[((size_t)gr << 7) + c4]
                              : make_float4(0.f, 0.f, 0.f, 0.f);
        f16x4 o;
        o[0] = (_Float16)val.x; o[1] = (_Float16)val.y;
        o[2] = (_Float16)val.z; o[3] = (_Float16)val.w;
        *(f16x4*)&sA[row * LDP + c4] = o;
    }
    __syncthreads();

    const int wid = tid >> 6, lane = tid & 63;
    const int lr = lane & 15, lg = lane >> 4;
    const int kof = lg << 3;
    const int arow = wid * 16 + lr;
    const int drow0 = wid * 16 + (lg << 2);

    f16x8 a0 = *(const f16x8*)&sA[arow * LDP + kof];
    f16x8 a1 = *(const f16x8*)&sA[arow * LDP + 32 + kof];
    f16x8 a2 = *(const f16x8*)&sA[arow * LDP + 64 + kof];
    f16x8 a3 = *(const f16x8*)&sA[arow * LDP + 96 + kof];

    #pragma unroll
    for (int n = 0; n < 8; n++) {
        const ushort* bp = wT + (((size_t)(n << 4) + lr) << 7);
        f32x4 c = {0.f, 0.f, 0.f, 0.f};
        c = MFMA16(a0, *(const f16x8*)(bp + kof), c);
        c = MFMA16(a1, *(const f16x8*)(bp + 32 + kof), c);
        c = MFMA16(a2, *(const f16x8*)(bp + 64 + kof), c);
        c = MFMA16(a3, *(const f16x8*)(bp + 96 + kof), c);
        int col = (n << 4) + lr;
        #pragma unroll
        for (int r = 0; r < 4; r++) {
            int gr = n0 + drow0 + r;
            if (gr < N) C[((size_t)gr << 7) + col] =
                __builtin_bit_cast(ushort, (_Float16)c[r]);
        }
    }
}

// ---------------- MFMA fused layer update: 3 GEMMs, 512 threads / 8 waves ----------------
__launch_bounds__(512, 4)
__global__ void k_update(const ushort* __restrict__ agg,
                         const ushort* __restrict__ w1T, const float* __restrict__ b1,
                         const ushort* __restrict__ w2T, const float* __restrict__ b2,
                         float* __restrict__ v,
                         const ushort* __restrict__ linT, ushort* __restrict__ vlin, int N) {
    constexpr int LDP = 136;
    __shared__ _Float16 sA[64 * LDP];   // 17.4 KB: agg -> t -> v_new (fp16)
    const int tid = threadIdx.x;
    const int n0 = blockIdx.x * 64;

    for (int i = tid; i < 64 * 32; i += 512) {
        int row = i >> 5, c4 = (i & 31) << 2;
        int gr = n0 + row;
        uint2 val = (gr < N) ? *(const uint2*)&agg[((size_t)gr << 7) + c4]
                             : make_uint2(0u, 0u);
        *(uint2*)&sA[row * LDP + c4] = val;   // raw fp16 copy
    }
    __syncthreads();

    const int wid = tid >> 6, lane = tid & 63;
    const int wr = wid & 3, wc = wid >> 2;
    const int lr = lane & 15, lg = lane >> 4;
    const int kof = lg << 3;
    const int arow = wr * 16 + lr;
    const int drow0 = wr * 16 + (lg << 2);
    const int cbase = wc << 6;   // 0 or 64

    f16x8 a0, a1, a2, a3;
    f32x4 acc[4];

    // ---- GEMM 1: t = ssp(agg @ W1 + b1) ----
    a0 = *(const f16x8*)&sA[arow * LDP + kof];
    a1 = *(const f16x8*)&sA[arow * LDP + 32 + kof];
    a2 = *(const f16x8*)&sA[arow * LDP + 64 + kof];
    a3 = *(const f16x8*)&sA[arow * LDP + 96 + kof];
    #pragma unroll
    for (int n = 0; n < 4; n++) {
        const ushort* bp = w1T + (((size_t)(cbase + (n << 4)) + lr) << 7);
        f32x4 c = {0.f, 0.f, 0.f, 0.f};
        c = MFMA16(a0, *(const f16x8*)(bp + kof), c);
        c = MFMA16(a1, *(const f16x8*)(bp + 32 + kof), c);
        c = MFMA16(a2, *(const f16x8*)(bp + 64 + kof), c);
        c = MFMA16(a3, *(const f16x8*)(bp + 96 + kof), c);
        acc[n] = c;
    }
    __syncthreads();
    #pragma unroll
    for (int n = 0; n < 4; n++) {
        int col = cbase + (n << 4) + lr;
        float bb = b1[col];
        #pragma unroll
        for (int r = 0; r < 4; r++)
            sA[(drow0 + r) * LDP + col] = (_Float16)sspf(acc[n][r] + bb);
    }
    __syncthreads();

    // ---- GEMM 2: v_new = t @ W2 + b2 + v_old ----
    a0 = *(const f16x8*)&sA[arow * LDP + kof];
    a1 = *(const f16x8*)&sA[arow * LDP + 32 + kof];
    a2 = *(const f16x8*)&sA[arow * LDP + 64 + kof];
    a3 = *(const f16x8*)&sA[arow * LDP + 96 + kof];
    #pragma unroll
    for (int n = 0; n < 4; n++) {
        const ushort* bp = w2T + (((size_t)(cbase + (n << 4)) + lr) << 7);
        f32x4 c = {0.f, 0.f, 0.f, 0.f};
        c = MFMA16(a0, *(const f16x8*)(bp + kof), c);
        c = MFMA16(a1, *(const f16x8*)(bp + 32 + kof), c);
        c = MFMA16(a2, *(const f16x8*)(bp + 64 + kof), c);
        c = MFMA16(a3, *(const f16x8*)(bp + 96 + kof), c);
        acc[n] = c;
    }
    __syncthreads();
    #pragma unroll
    for (int n = 0; n < 4; n++) {
        int col = cbase + (n << 4) + lr;
        float bb = b2[col];
        #pragma unroll
        for (int r = 0; r < 4; r++) {
            int gr = n0 + drow0 + r;
            float vn = 0.f;
            if (gr < N) {
                vn = acc[n][r] + bb + v[((size_t)gr << 7) + col];
                v[((size_t)gr << 7) + col] = vn;
            }
            sA[(drow0 + r) * LDP + col] = (_Float16)vn;
        }
    }
    if (!linT) return;
    __syncthreads();

    // ---- GEMM 3: vlin(fp16) = v_new @ lin ----
    a0 = *(const f16x8*)&sA[arow * LDP + kof];
    a1 = *(const f16x8*)&sA[arow * LDP + 32 + kof];
    a2 = *(const f16x8*)&sA[arow * LDP + 64 + kof];
    a3 = *(const f16x8*)&sA[arow * LDP + 96 + kof];
    #pragma unroll
    for (int n = 0; n < 4; n++) {
        const ushort* bp = linT + (((size_t)(cbase + (n << 4)) + lr) << 7);
        f32x4 c = {0.f, 0.f, 0.f, 0.f};
        c = MFMA16(a0, *(const f16x8*)(bp + kof), c);
        c = MFMA16(a1, *(const f16x8*)(bp + 32 + kof), c);
        c = MFMA16(a2, *(const f16x8*)(bp + 64 + kof), c);
        c = MFMA16(a3, *(const f16x8*)(bp + 96 + kof), c);
        int col = cbase + (n << 4) + lr;
        #pragma unroll
        for (int r = 0; r < 4; r++) {
            int gr = n0 + drow0 + r;
            if (gr < N) vlin[((size_t)gr << 7) + col] =
                __builtin_bit_cast(ushort, (_Float16)c[r]);
        }
    }
}

// ---------------- tiled fused readout ----------------
__launch_bounds__(256, 4)
__global__ void k_uout(const float* __restrict__ v, const float* __restrict__ u1w,
                       const float* __restrict__ u1b, const float* __restrict__ u2w,
                       const float* __restrict__ u2b, const int* __restrict__ batch,
                       float* __restrict__ out, int N) {
    __shared__ float sA[64 * 128];
    const int tid = threadIdx.x;
    const int n0 = blockIdx.x * 64;

    for (int i = tid; i < 64 * 32; i += 256) {
        int row = i >> 5, cq = (i & 31) << 2;
        int gr = n0 + row;
        float4 val = (gr < N) ? *(const float4*)&v[((size_t)gr << 7) + cq]
                              : make_float4(0.f, 0.f, 0.f, 0.f);
        *(float4*)&sA[row * 128 + cq] = val;
    }
    __syncthreads();

    const int cg = tid & 31, rg = tid >> 5;
    const int r0 = rg << 3;
    const int c2 = cg << 1;

    float2 acc[8];
    {
        float2 b1v = *(const float2*)&u1b[c2];
        #pragma unroll
        for (int i = 0; i < 8; i++) acc[i] = b1v;
        #pragma unroll 4
        for (int k = 0; k < 128; k++) {
            float2 wv = *(const float2*)&u1w[(k << 6) + c2];
            #pragma unroll
            for (int i = 0; i < 8; i++) {
                float a = sA[(r0 + i) * 128 + k];
                acc[i].x = fmaf(a, wv.x, acc[i].x);
                acc[i].y = fmaf(a, wv.y, acc[i].y);
            }
        }
    }
    __syncthreads();
    #pragma unroll
    for (int i = 0; i < 8; i++) {
        sA[(r0 + i) * 64 + c2 + 0] = sspf(acc[i].x);
        sA[(r0 + i) * 64 + c2 + 1] = sspf(acc[i].y);
    }
    __syncthreads();

    float acc2[8];
    {
        float bb = u2b[cg];
        #pragma unroll
        for (int i = 0; i < 8; i++) acc2[i] = bb;
        #pragma unroll 4
        for (int k = 0; k < 64; k++) {
            float wv = u2w[(k << 5) + cg];
            #pragma unroll
            for (int i = 0; i < 8; i++)
                acc2[i] = fmaf(sA[(r0 + i) * 64 + k], wv, acc2[i]);
        }
    }

    int cur = -1;
    float run = 0.f;
    #pragma unroll
    for (int i = 0; i < 8; i++) {
        int gr = n0 + r0 + i;
        int g = (gr < N) ? batch[gr] : -1;
        if (g != cur) {
            if (cur >= 0) atomicAdd(&out[(size_t)cur * 32 + cg], run);
            cur = g;
            run = 0.f;
        }
        if (g >= 0) run += acc2[i];
    }
    if (cur >= 0) atomicAdd(&out[(size_t)cur * 32 + cg], run);
}

extern "C" void kernel_launch(void* const* d_in, const int* in_sizes, int n_in,
                              void* d_out, int out_size, void* d_ws, size_t ws_size,
                              hipStream_t stream) {
    const float* x      = (const float*)d_in[0];
    const float* pos    = (const float*)d_in[1];
    const int*   batch  = (const int*)d_in[2];
    const int*   ei     = (const int*)d_in[3];
    const float* fe_w1  = (const float*)d_in[4];
    const float* fe_b1  = (const float*)d_in[5];
    const float* bn_g   = (const float*)d_in[6];
    const float* bn_b   = (const float*)d_in[7];
    const float* fe_w2  = (const float*)d_in[8];
    const float* fe_b2  = (const float*)d_in[9];
    const float* lin_w  = (const float*)d_in[10];
    const float* mlp_w1 = (const float*)d_in[11];
    const float* mlp_b1 = (const float*)d_in[12];
    const float* mlp_w2 = (const float*)d_in[13];
    const float* mlp_b2 = (const float*)d_in[14];
    const float* v1_w   = (const float*)d_in[15];
    const float* v1_b   = (const float*)d_in[16];
    const float* v2_w   = (const float*)d_in[17];
    const float* v2_b   = (const float*)d_in[18];
    const float* u1_w   = (const float*)d_in[19];
    const float* u1_b   = (const float*)d_in[20];
    const float* u2_w   = (const float*)d_in[21];
    const float* u2_b   = (const float*)d_in[22];

    const int N = in_sizes[0] / 28;
    const int E = in_sizes[3] / 2;
    const int NB1 = (N + 1023) / 1024;

    char* ws = (char*)d_ws;
    size_t o = 0;
    auto alloc = [&](size_t bytes) { void* p = ws + o; o += (bytes + 255) & ~(size_t)255; return p; };
    int*    counts = (int*)   alloc((size_t)N * 4);
    int*    cursor = (int*)   alloc((size_t)N * 4);
    int*    rowptr = (int*)   alloc((size_t)N * 4);
    int*    bsum   = (int*)   alloc((size_t)NB1 * 4);
    int*    s_src  = (int*)   alloc((size_t)E * 4);
    float*  s_fid  = (float*) alloc((size_t)E * 4);
    float*  stats  = (float*) alloc(128 * 4);
    float*  prm    = (float*) alloc(128 * 4);
    ushort* tab    = (ushort*)alloc((size_t)LAY * K_TAB * 128 * 2);  // 12 MB fp16
    float*  v      = (float*) alloc((size_t)N * 128 * 4);
    ushort* vlin   = (ushort*)alloc((size_t)N * 128 * 2);            // fp16
    ushort* agg    = (ushort*)alloc((size_t)N * 128 * 2);            // fp16
    float*  h      = (float*) alloc((size_t)N * 64 * 4);
    int*    locex  = (int*)   alloc((size_t)N * 4);
    ushort* v1T    = (ushort*)alloc((size_t)LAY * 16384 * 2);   // fp16 transposed weights
    ushort* v2T    = (ushort*)alloc((size_t)LAY * 16384 * 2);
    ushort* linT   = (ushort*)alloc((size_t)LAY * 16384 * 2);
    ushort* fe2T   = (ushort*)alloc((size_t)8192 * 2);

    // -------- weight conversion (fp16, transposed) --------
    k_cvtT128<<<LAY, 256, 0, stream>>>(v1_w, v1T);
    k_cvtT128<<<LAY, 256, 0, stream>>>(v2_w, v2T);
    k_cvtT128<<<LAY, 256, 0, stream>>>(lin_w, linT);
    k_cvtT_fe<<<1, 256, 0, stream>>>(fe_w2, fe2T);

    // -------- one-time edge sort (dst-ordered CSR) --------
    hipMemsetAsync(counts, 0, (size_t)N * 4, stream);
    k_hist<<<(E + 255) / 256, 256, 0, stream>>>(ei, counts, E);
    k_scan1<<<NB1, 1024, 0, stream>>>(counts, locex, bsum, N);
    k_scan2<<<1, 1024, 0, stream>>>(bsum, NB1);
    k_scan3<<<(N + 255) / 256, 256, 0, stream>>>(locex, bsum, cursor, rowptr, N);
    k_scatter<<<(E + 255) / 256, 256, 0, stream>>>(ei, pos, cursor, s_src, s_fid, E);

    // -------- gate tables for all layers (fp16) --------
    k_tab_all<<<LAY * 256, 256, 0, stream>>>(mlp_w1, mlp_b1, mlp_w2, mlp_b2, tab);

    // -------- feature embedding --------
    hipMemsetAsync(stats, 0, 128 * 4, stream);
    k_fe1<<<(N * 64 + 255) / 256, 256, 0, stream>>>(x, fe_w1, fe_b1, h, N);
    k_bnstat<<<256, 256, 0, stream>>>(h, stats, N);
    k_bnfin<<<1, 64, 0, stream>>>(stats, prm, bn_g, bn_b, 1.0f / (float)N);
    const int gblk = (N + 63) / 64;
    k_fe2<<<gblk, 256, 0, stream>>>(h, prm, fe2T, fe_b2, v, N);

    // vlin for layer 0
    k_gemm_rb<<<gblk, 256, 0, stream>>>(v, linT, vlin, N);

    // -------- interaction layers --------
    const int eblk = (N + 7) / 8;
    for (int l = 0; l < LAY; l++) {
        k_edge_csr<<<eblk, 256, 0, stream>>>(
            s_src, s_fid, rowptr, counts, vlin,
            tab + (size_t)l * K_TAB * 128, agg, N);
        const ushort* lin_next = (l + 1 < LAY) ? linT + (size_t)(l + 1) * 16384 : nullptr;
        k_update<<<gblk, 512, 0, stream>>>(
            agg, v1T + (size_t)l * 16384, v1_b + (size_t)l * 128,
            v2T + (size_t)l * 16384, v2_b + (size_t)l * 128,
            v, lin_next, vlin, N);
    }

    // -------- fused readout --------
    hipMemsetAsync(d_out, 0, (size_t)out_size * 4, stream);
    k_uout<<<gblk, 256, 0, stream>>>(v, u1_w, u1_b, u2_w, u2_b, batch, (float*)d_out, N);
}

// Round 13
// 940.590 us; speedup vs baseline: 1.0320x; 1.0320x over previous
//
#include <hip/hip_runtime.h>
#include <hip/hip_fp16.h>
#include <math.h>

#define DEV __device__ __forceinline__

constexpr int NGAUSS = 50;
constexpr int LAY = 6;
constexpr int K_TAB = 8192;
constexpr float DMAX = 40.0f;
constexpr float TSCALE = (float)(K_TAB - 1) / DMAX;   // fid = d * TSCALE
constexpr float STEP = 6.0f / 49.0f;
constexpr float COEFF = -0.5f / (STEP * STEP);
constexpr float LN2F = 0.69314718055994531f;
constexpr float PI_OVER_CUT = 0.52359877559829887f;  // pi/6

using f16x8 = __attribute__((ext_vector_type(8))) _Float16;
using f16x4 = __attribute__((ext_vector_type(4))) _Float16;
using f32x4 = __attribute__((ext_vector_type(4))) float;

#define MFMA16(a, b, c) __builtin_amdgcn_mfma_f32_16x16x32_f16(a, b, c, 0, 0, 0)

DEV float sspf(float x) {
    float ax = fabsf(x);
    float e = __expf(-ax);
    return fmaxf(x, 0.f) + __logf(1.f + e) - LN2F;
}

// ---- fp16 pack/unpack helpers (storage fp16, math f32) ----
DEV float4 ld_h4(const ushort* p) {          // 8B load -> 4 floats
    uint2 r = *(const uint2*)p;
    __half2 a = __builtin_bit_cast(__half2, r.x);
    __half2 b = __builtin_bit_cast(__half2, r.y);
    float2 fa = __half22float2(a), fb = __half22float2(b);
    return make_float4(fa.x, fa.y, fb.x, fb.y);
}
DEV void st_h4(ushort* p, float4 v) {        // 4 floats -> 8B store
    uint2 r;
    r.x = __builtin_bit_cast(uint, __float22half2_rn(make_float2(v.x, v.y)));
    r.y = __builtin_bit_cast(uint, __float22half2_rn(make_float2(v.z, v.w)));
    *(uint2*)p = r;
}

// ---------------- weight convert+transpose (fp32 [K][C] -> fp16 [C][K]) ----------------
__global__ void k_cvtT128(const float* __restrict__ src, ushort* __restrict__ dst) {
    const float* s = src + (size_t)blockIdx.x * 16384;
    ushort* d = dst + (size_t)blockIdx.x * 16384;
    for (int i = threadIdx.x; i < 16384; i += 256) {
        int k = i >> 7, c = i & 127;
        d[(c << 7) + k] = __builtin_bit_cast(ushort, (_Float16)s[i]);
    }
}
__global__ void k_cvtT_fe(const float* __restrict__ src, ushort* __restrict__ dst) {
    // fe_w2: [64][128] -> dst[c(128)][k(64)]
    for (int i = threadIdx.x; i < 8192; i += 256) {
        int k = i >> 7, c = i & 127;
        dst[(c << 6) + k] = __builtin_bit_cast(ushort, (_Float16)src[i]);
    }
}

// ---------------- edge sort pre-pass (once per call) ----------------
__global__ void k_hist(const int* __restrict__ ei, int* __restrict__ counts, int E) {
    int e = blockIdx.x * 256 + threadIdx.x;
    if (e < E) atomicAdd(&counts[ei[E + e]], 1);
}

__global__ void k_scan1(const int* __restrict__ counts, int* __restrict__ locex,
                        int* __restrict__ bsum, int n) {
    __shared__ int s_wsum[16];
    const int tid = threadIdx.x;
    const int i = blockIdx.x * 1024 + tid;
    const int lane = tid & 63, wv = tid >> 6;
    int v = (i < n) ? counts[i] : 0;
    int x = v;
    #pragma unroll
    for (int off = 1; off < 64; off <<= 1) {
        int y = __shfl_up(x, off, 64);
        if (lane >= off) x += y;
    }
    if (lane == 63) s_wsum[wv] = x;
    __syncthreads();
    if (wv == 0 && lane < 16) {
        int wval = s_wsum[lane];
        int wx = wval;
        #pragma unroll
        for (int off = 1; off < 16; off <<= 1) {
            int wy = __shfl_up(wx, off, 16);
            if (lane >= off) wx += wy;
        }
        s_wsum[lane] = wx - wval;
    }
    __syncthreads();
    if (i < n) locex[i] = s_wsum[wv] + x - v;
    if (tid == 1023) bsum[blockIdx.x] = s_wsum[15] + x;
}

__global__ void k_scan2(int* __restrict__ bsum, int nb) {
    __shared__ int s_wsum[16];
    const int tid = threadIdx.x;
    const int lane = tid & 63, wv = tid >> 6;
    int v = (tid < nb) ? bsum[tid] : 0;
    int x = v;
    #pragma unroll
    for (int off = 1; off < 64; off <<= 1) {
        int y = __shfl_up(x, off, 64);
        if (lane >= off) x += y;
    }
    if (lane == 63) s_wsum[wv] = x;
    __syncthreads();
    if (wv == 0 && lane < 16) {
        int wval = s_wsum[lane];
        int wx = wval;
        #pragma unroll
        for (int off = 1; off < 16; off <<= 1) {
            int wy = __shfl_up(wx, off, 16);
            if (lane >= off) wx += wy;
        }
        s_wsum[lane] = wx - wval;
    }
    __syncthreads();
    if (tid < nb) bsum[tid] = s_wsum[wv] + x - v;
}

__global__ void k_scan3(const int* __restrict__ locex, const int* __restrict__ bsumex,
                        int* __restrict__ cursor, int* __restrict__ rowptr, int n) {
    int i = blockIdx.x * 256 + threadIdx.x;
    if (i >= n) return;
    int e = locex[i] + bsumex[i >> 10];
    cursor[i] = e;
    rowptr[i] = e;
}

__global__ void k_scatter(const int* __restrict__ ei, const float* __restrict__ pos,
                          int* __restrict__ cursor, int* __restrict__ s_src,
                          float* __restrict__ s_fid, int E) {
    int e = blockIdx.x * 256 + threadIdx.x;
    if (e >= E) return;
    int r = ei[e], c = ei[E + e];
    int p = atomicAdd(&cursor[c], 1);
    float dx = pos[3 * r + 0] - pos[3 * c + 0];
    float dy = pos[3 * r + 1] - pos[3 * c + 1];
    float dz = pos[3 * r + 2] - pos[3 * c + 2];
    float d = sqrtf(dx * dx + dy * dy + dz * dz);
    s_src[p] = r;
    s_fid[p] = fminf(d * TSCALE, (float)(K_TAB - 2) + 0.999f);
}

// ---------------- gate table build (fp16 output), ALL layers in one launch ----------------
__launch_bounds__(256)
__global__ void k_tab_all(const float* __restrict__ w1A, const float* __restrict__ b1A,
                          const float* __restrict__ w2A, const float* __restrict__ b2A,
                          ushort* __restrict__ tabA) {
    const int layer = blockIdx.x >> 8;
    const int k0 = (blockIdx.x & 255) * 32;
    const float* w1 = w1A + (size_t)layer * NGAUSS * 128;
    const float* b1 = b1A + (size_t)layer * 128;
    const float* w2 = w2A + (size_t)layer * 128 * 128;
    const float* b2 = b2A + (size_t)layer * 128;
    ushort* tab = tabA + (size_t)layer * K_TAB * 128;

    __shared__ float s_demb[32][NGAUSS];
    __shared__ float s_t1[32][128];
    const int tid = threadIdx.x;

    for (int i = tid; i < 32 * NGAUSS; i += 256) {
        int r = i / NGAUSS, g = i - r * NGAUSS;
        float d = (float)(k0 + r) * (1.0f / TSCALE);
        float t = d - g * STEP;
        s_demb[r][g] = __expf(COEFF * t * t);
    }
    __syncthreads();

    const int cg = tid & 31, rg = tid >> 5;
    const int r0 = rg << 2;
    const int c4 = cg << 2;

    float4 b1v = *(const float4*)&b1[c4];
    float4 acc[4];
    #pragma unroll
    for (int i = 0; i < 4; i++) acc[i] = b1v;
    #pragma unroll 2
    for (int k = 0; k < NGAUSS; k++) {
        float4 wv = *(const float4*)&w1[(k << 7) + c4];
        #pragma unroll
        for (int i = 0; i < 4; i++) {
            float dv = s_demb[r0 + i][k];
            acc[i].x = fmaf(dv, wv.x, acc[i].x);
            acc[i].y = fmaf(dv, wv.y, acc[i].y);
            acc[i].z = fmaf(dv, wv.z, acc[i].z);
            acc[i].w = fmaf(dv, wv.w, acc[i].w);
        }
    }
    #pragma unroll
    for (int i = 0; i < 4; i++) {
        float4 t;
        t.x = sspf(acc[i].x); t.y = sspf(acc[i].y);
        t.z = sspf(acc[i].z); t.w = sspf(acc[i].w);
        *(float4*)&s_t1[r0 + i][c4] = t;
    }
    __syncthreads();

    float4 b2v = *(const float4*)&b2[c4];
    float4 a2[4];
    #pragma unroll
    for (int i = 0; i < 4; i++) a2[i] = b2v;
    #pragma unroll 4
    for (int k = 0; k < 128; k++) {
        float4 wv = *(const float4*)&w2[(k << 7) + c4];
        #pragma unroll
        for (int i = 0; i < 4; i++) {
            float tv = s_t1[r0 + i][k];
            a2[i].x = fmaf(tv, wv.x, a2[i].x);
            a2[i].y = fmaf(tv, wv.y, a2[i].y);
            a2[i].z = fmaf(tv, wv.z, a2[i].z);
            a2[i].w = fmaf(tv, wv.w, a2[i].w);
        }
    }
    #pragma unroll
    for (int i = 0; i < 4; i++) {
        int knot = k0 + r0 + i;
        float d = (float)knot * (1.0f / TSCALE);
        float cc = 0.5f * (__cosf(d * PI_OVER_CUT) + 1.0f);
        float4 o;
        o.x = a2[i].x * cc; o.y = a2[i].y * cc;
        o.z = a2[i].z * cc; o.w = a2[i].w * cc;
        st_h4(&tab[((size_t)knot << 7) + c4], o);
    }
}

// ---------------- pair-interleave the table: tab2[i][2c..2c+1] = {T[i][c], T[i+1][c]} ----------------
// one thread = (layer, knot, 4-channel group): reads 8B from rows i and i+1, writes 16B
__global__ void k_pair(const ushort* __restrict__ tab, ushort* __restrict__ tab2) {
    size_t idx = (size_t)blockIdx.x * 256 + threadIdx.x;   // LAY*K_TAB*32 total
    int cg = idx & 31;
    size_t knotg = idx >> 5;           // layer*K_TAB + knot
    int knot = (int)(knotg & (K_TAB - 1));
    const ushort* r0 = tab + (knotg << 7) + (cg << 2);
    const ushort* r1 = (knot < K_TAB - 1) ? r0 + 128 : r0;   // clamp at end
    uint2 a = *(const uint2*)r0;
    uint2 b = *(const uint2*)r1;
    // interleave halfwords: out = {a0,b0,a1,b1,a2,b2,a3,b3}
    ushort4 al = *(const ushort4*)&a;
    ushort4 bl = *(const ushort4*)&b;
    ushort out[8] = {al.x, bl.x, al.y, bl.y, al.z, bl.z, al.w, bl.w};
    *(uint4*)&tab2[(knotg << 8) + (cg << 3)] = *(const uint4*)out;
}

// ---------------- node-centric CSR edge kernel: paired-table (2 loads/edge) ----------------
// 1 node per 32-lane group; lane owns 4 channels. 8-edge batches + scalar tail.
__launch_bounds__(256)
__global__ void k_edge_csr(const int* __restrict__ s_src, const float* __restrict__ s_fid,
                           const int* __restrict__ rowptr, const int* __restrict__ counts,
                           const ushort* __restrict__ vlin, const ushort* __restrict__ tab2,
                           ushort* __restrict__ agg, int N) {
    const int tid = threadIdx.x;
    const int cg = tid & 31;
    const int n = blockIdx.x * 8 + (tid >> 5);
    if (n >= N) return;
    const ushort* tabc = tab2 + (cg << 3);   // lane's 16B slot within 512B row
    const ushort* vlc = vlin + (cg << 2);

    const int rs = rowptr[n];
    const int re = rs + counts[n];
    float4 run = make_float4(0.f, 0.f, 0.f, 0.f);
    int e = rs;
    for (; e + 8 <= re; e += 8) {
        f16x8 TP[8];
        f16x4 VL[8];
        _Float16 FR[8];
        #pragma unroll
        for (int j = 0; j < 8; j++) {
            float fid = s_fid[e + j];
            int i0 = (int)fid;
            FR[j] = (_Float16)(fid - (float)i0);
            TP[j] = *(const f16x8*)(tabc + ((size_t)i0 << 8));
            VL[j] = *(const f16x4*)(vlc + ((size_t)s_src[e + j] << 7));
        }
        f16x4 p0 = {0, 0, 0, 0}, p1 = {0, 0, 0, 0};
        #pragma unroll
        for (int j = 0; j < 8; j += 2) {
            f16x4 t0a = {TP[j][0], TP[j][2], TP[j][4], TP[j][6]};
            f16x4 t1a = {TP[j][1], TP[j][3], TP[j][5], TP[j][7]};
            f16x4 t0b = {TP[j+1][0], TP[j+1][2], TP[j+1][4], TP[j+1][6]};
            f16x4 t1b = {TP[j+1][1], TP[j+1][3], TP[j+1][5], TP[j+1][7]};
            f16x4 w0 = t0a + FR[j]     * (t1a - t0a);
            f16x4 w1 = t0b + FR[j + 1] * (t1b - t0b);
            p0 += w0 * VL[j];
            p1 += w1 * VL[j + 1];
        }
        run.x += (float)p0[0] + (float)p1[0];
        run.y += (float)p0[1] + (float)p1[1];
        run.z += (float)p0[2] + (float)p1[2];
        run.w += (float)p0[3] + (float)p1[3];
    }
    for (; e < re; e++) {
        float fid = s_fid[e];
        int i0 = (int)fid;
        _Float16 fr = (_Float16)(fid - (float)i0);
        f16x8 tp = *(const f16x8*)(tabc + ((size_t)i0 << 8));
        f16x4 vl = *(const f16x4*)(vlc + ((size_t)s_src[e] << 7));
        f16x4 t0 = {tp[0], tp[2], tp[4], tp[6]};
        f16x4 t1 = {tp[1], tp[3], tp[5], tp[7]};
        f16x4 w = t0 + fr * (t1 - t0);
        f16x4 p = w * vl;
        run.x += (float)p[0];
        run.y += (float)p[1];
        run.z += (float)p[2];
        run.w += (float)p[3];
    }
    st_h4(&agg[((size_t)n << 7) + (cg << 2)], run);
}

// ---------------- feature embedding ----------------
__global__ void k_fe1(const float* __restrict__ x, const float* __restrict__ w,
                      const float* __restrict__ b, float* __restrict__ h, int N) {
    int idx = blockIdx.x * 256 + threadIdx.x;
    if (idx >= N * 64) return;
    int n = idx >> 6, c = idx & 63;
    const float* xr = x + (size_t)n * 28;
    float acc = b[c];
    #pragma unroll
    for (int k = 0; k < 28; k++) acc = fmaf(xr[k], w[k * 64 + c], acc);
    h[idx] = acc;
}

__global__ void k_bnstat(const float* __restrict__ h, float* __restrict__ stats, int N) {
    __shared__ float s_s[256], s_q[256];
    int tid = threadIdx.x;
    int c = tid & 63, g = tid >> 6;
    float s = 0.f, q = 0.f;
    for (int n = blockIdx.x * 4 + g; n < N; n += gridDim.x * 4) {
        float v = h[(size_t)n * 64 + c];
        s += v; q += v * v;
    }
    s_s[tid] = s; s_q[tid] = q;
    __syncthreads();
    if (tid < 64) {
        s = s_s[tid] + s_s[tid + 64] + s_s[tid + 128] + s_s[tid + 192];
        q = s_q[tid] + s_q[tid + 64] + s_q[tid + 128] + s_q[tid + 192];
        atomicAdd(&stats[tid], s);
        atomicAdd(&stats[64 + tid], q);
    }
}

__global__ void k_bnfin(const float* __restrict__ stats, float* __restrict__ prm,
                        const float* __restrict__ gamma, const float* __restrict__ beta,
                        float invN) {
    int c = threadIdx.x;  // 64 threads
    float mu = stats[c] * invN;
    float var = stats[64 + c] * invN - mu * mu;
    float sc = gamma[c] * rsqrtf(var + 1e-5f);
    prm[c] = sc;
    prm[64 + c] = beta[c] - mu * sc;
}

// ---------------- MFMA fe2: v = relu( relu(bn(h)) @ fe_w2 + b2 ), K=64 ----------------
__launch_bounds__(256, 4)
__global__ void k_fe2(const float* __restrict__ h, const float* __restrict__ prm,
                      const ushort* __restrict__ w2T, const float* __restrict__ b2,
                      float* __restrict__ v, int N) {
    constexpr int LDP = 72;
    __shared__ _Float16 sH[64 * LDP];
    const int tid = threadIdx.x;
    const int n0 = blockIdx.x * 64;

    for (int i = tid; i < 64 * 16; i += 256) {
        int row = i >> 4, c4 = (i & 15) << 2;
        int gr = n0 + row;
        float4 hv = (gr < N) ? *(const float4*)&h[((size_t)gr << 6) + c4]
                             : make_float4(0.f, 0.f, 0.f, 0.f);
        float4 sc = *(const float4*)&prm[c4];
        float4 sh = *(const float4*)&prm[64 + c4];
        f16x4 o;
        o[0] = (_Float16)fmaxf(fmaf(hv.x, sc.x, sh.x), 0.f);
        o[1] = (_Float16)fmaxf(fmaf(hv.y, sc.y, sh.y), 0.f);
        o[2] = (_Float16)fmaxf(fmaf(hv.z, sc.z, sh.z), 0.f);
        o[3] = (_Float16)fmaxf(fmaf(hv.w, sc.w, sh.w), 0.f);
        *(f16x4*)&sH[row * LDP + c4] = o;
    }
    __syncthreads();

    const int wid = tid >> 6, lane = tid & 63;
    const int lr = lane & 15, lg = lane >> 4;
    const int kof = lg << 3;
    const int arow = wid * 16 + lr;
    const int drow0 = wid * 16 + (lg << 2);

    f16x8 a0 = *(const f16x8*)&sH[arow * LDP + kof];
    f16x8 a1 = *(const f16x8*)&sH[arow * LDP + 32 + kof];

    #pragma unroll
    for (int n = 0; n < 8; n++) {
        const ushort* bp = w2T + (((size_t)(n << 4) + lr) << 6);
        f32x4 c = {0.f, 0.f, 0.f, 0.f};
        c = MFMA16(a0, *(const f16x8*)(bp + kof), c);
        c = MFMA16(a1, *(const f16x8*)(bp + 32 + kof), c);
        int col = (n << 4) + lr;
        float bb = b2[col];
        #pragma unroll
        for (int r = 0; r < 4; r++) {
            int gr = n0 + drow0 + r;
            if (gr < N) v[((size_t)gr << 7) + col] = fmaxf(c[r] + bb, 0.f);
        }
    }
}

// ---------------- MFMA single GEMM: vlin(fp16) = v @ lin, K=128 ----------------
__launch_bounds__(256, 4)
__global__ void k_gemm_rb(const float* __restrict__ A, const ushort* __restrict__ wT,
                          ushort* __restrict__ C, int N) {
    constexpr int LDP = 136;
    __shared__ _Float16 sA[64 * LDP];
    const int tid = threadIdx.x;
    const int n0 = blockIdx.x * 64;

    for (int i = tid; i < 64 * 32; i += 256) {
        int row = i >> 5, c4 = (i & 31) << 2;
        int gr = n0 + row;
        float4 val = (gr < N) ? *(const float4*)&A[((size_t)gr << 7) + c4]
                              : make_float4(0.f, 0.f, 0.f, 0.f);
        f16x4 o;
        o[0] = (_Float16)val.x; o[1] = (_Float16)val.y;
        o[2] = (_Float16)val.z; o[3] = (_Float16)val.w;
        *(f16x4*)&sA[row * LDP + c4] = o;
    }
    __syncthreads();

    const int wid = tid >> 6, lane = tid & 63;
    const int lr = lane & 15, lg = lane >> 4;
    const int kof = lg << 3;
    const int arow = wid * 16 + lr;
    const int drow0 = wid * 16 + (lg << 2);

    f16x8 a0 = *(const f16x8*)&sA[arow * LDP + kof];
    f16x8 a1 = *(const f16x8*)&sA[arow * LDP + 32 + kof];
    f16x8 a2 = *(const f16x8*)&sA[arow * LDP + 64 + kof];
    f16x8 a3 = *(const f16x8*)&sA[arow * LDP + 96 + kof];

    #pragma unroll
    for (int n = 0; n < 8; n++) {
        const ushort* bp = wT + (((size_t)(n << 4) + lr) << 7);
        f32x4 c = {0.f, 0.f, 0.f, 0.f};
        c = MFMA16(a0, *(const f16x8*)(bp + kof), c);
        c = MFMA16(a1, *(const f16x8*)(bp + 32 + kof), c);
        c = MFMA16(a2, *(const f16x8*)(bp + 64 + kof), c);
        c = MFMA16(a3, *(const f16x8*)(bp + 96 + kof), c);
        int col = (n << 4) + lr;
        #pragma unroll
        for (int r = 0; r < 4; r++) {
            int gr = n0 + drow0 + r;
            if (gr < N) C[((size_t)gr << 7) + col] =
                __builtin_bit_cast(ushort, (_Float16)c[r]);
        }
    }
}

// ---------------- MFMA fused layer update: 3 GEMMs, 512 threads / 8 waves ----------------
__launch_bounds__(512, 4)
__global__ void k_update(const ushort* __restrict__ agg,
                         const ushort* __restrict__ w1T, const float* __restrict__ b1,
                         const ushort* __restrict__ w2T, const float* __restrict__ b2,
                         float* __restrict__ v,
                         const ushort* __restrict__ linT, ushort* __restrict__ vlin, int N) {
    constexpr int LDP = 136;
    __shared__ _Float16 sA[64 * LDP];   // 17.4 KB: agg -> t -> v_new (fp16)
    const int tid = threadIdx.x;
    const int n0 = blockIdx.x * 64;

    for (int i = tid; i < 64 * 32; i += 512) {
        int row = i >> 5, c4 = (i & 31) << 2;
        int gr = n0 + row;
        uint2 val = (gr < N) ? *(const uint2*)&agg[((size_t)gr << 7) + c4]
                             : make_uint2(0u, 0u);
        *(uint2*)&sA[row * LDP + c4] = val;   // raw fp16 copy
    }
    __syncthreads();

    const int wid = tid >> 6, lane = tid & 63;
    const int wr = wid & 3, wc = wid >> 2;
    const int lr = lane & 15, lg = lane >> 4;
    const int kof = lg << 3;
    const int arow = wr * 16 + lr;
    const int drow0 = wr * 16 + (lg << 2);
    const int cbase = wc << 6;   // 0 or 64

    f16x8 a0, a1, a2, a3;
    f32x4 acc[4];

    // ---- GEMM 1: t = ssp(agg @ W1 + b1) ----
    a0 = *(const f16x8*)&sA[arow * LDP + kof];
    a1 = *(const f16x8*)&sA[arow * LDP + 32 + kof];
    a2 = *(const f16x8*)&sA[arow * LDP + 64 + kof];
    a3 = *(const f16x8*)&sA[arow * LDP + 96 + kof];
    #pragma unroll
    for (int n = 0; n < 4; n++) {
        const ushort* bp = w1T + (((size_t)(cbase + (n << 4)) + lr) << 7);
        f32x4 c = {0.f, 0.f, 0.f, 0.f};
        c = MFMA16(a0, *(const f16x8*)(bp + kof), c);
        c = MFMA16(a1, *(const f16x8*)(bp + 32 + kof), c);
        c = MFMA16(a2, *(const f16x8*)(bp + 64 + kof), c);
        c = MFMA16(a3, *(const f16x8*)(bp + 96 + kof), c);
        acc[n] = c;
    }
    __syncthreads();
    #pragma unroll
    for (int n = 0; n < 4; n++) {
        int col = cbase + (n << 4) + lr;
        float bb = b1[col];
        #pragma unroll
        for (int r = 0; r < 4; r++)
            sA[(drow0 + r) * LDP + col] = (_Float16)sspf(acc[n][r] + bb);
    }
    __syncthreads();

    // ---- GEMM 2: v_new = t @ W2 + b2 + v_old ----
    a0 = *(const f16x8*)&sA[arow * LDP + kof];
    a1 = *(const f16x8*)&sA[arow * LDP + 32 + kof];
    a2 = *(const f16x8*)&sA[arow * LDP + 64 + kof];
    a3 = *(const f16x8*)&sA[arow * LDP + 96 + kof];
    #pragma unroll
    for (int n = 0; n < 4; n++) {
        const ushort* bp = w2T + (((size_t)(cbase + (n << 4)) + lr) << 7);
        f32x4 c = {0.f, 0.f, 0.f, 0.f};
        c = MFMA16(a0, *(const f16x8*)(bp + kof), c);
        c = MFMA16(a1, *(const f16x8*)(bp + 32 + kof), c);
        c = MFMA16(a2, *(const f16x8*)(bp + 64 + kof), c);
        c = MFMA16(a3, *(const f16x8*)(bp + 96 + kof), c);
        acc[n] = c;
    }
    __syncthreads();
    #pragma unroll
    for (int n = 0; n < 4; n++) {
        int col = cbase + (n << 4) + lr;
        float bb = b2[col];
        #pragma unroll
        for (int r = 0; r < 4; r++) {
            int gr = n0 + drow0 + r;
            float vn = 0.f;
            if (gr < N) {
                vn = acc[n][r] + bb + v[((size_t)gr << 7) + col];
                v[((size_t)gr << 7) + col] = vn;
            }
            sA[(drow0 + r) * LDP + col] = (_Float16)vn;
        }
    }
    if (!linT) return;
    __syncthreads();

    // ---- GEMM 3: vlin(fp16) = v_new @ lin ----
    a0 = *(const f16x8*)&sA[arow * LDP + kof];
    a1 = *(const f16x8*)&sA[arow * LDP + 32 + kof];
    a2 = *(const f16x8*)&sA[arow * LDP + 64 + kof];
    a3 = *(const f16x8*)&sA[arow * LDP + 96 + kof];
    #pragma unroll
    for (int n = 0; n < 4; n++) {
        const ushort* bp = linT + (((size_t)(cbase + (n << 4)) + lr) << 7);
        f32x4 c = {0.f, 0.f, 0.f, 0.f};
        c = MFMA16(a0, *(const f16x8*)(bp + kof), c);
        c = MFMA16(a1, *(const f16x8*)(bp + 32 + kof), c);
        c = MFMA16(a2, *(const f16x8*)(bp + 64 + kof), c);
        c = MFMA16(a3, *(const f16x8*)(bp + 96 + kof), c);
        int col = cbase + (n << 4) + lr;
        #pragma unroll
        for (int r = 0; r < 4; r++) {
            int gr = n0 + drow0 + r;
            if (gr < N) vlin[((size_t)gr << 7) + col] =
                __builtin_bit_cast(ushort, (_Float16)c[r]);
        }
    }
}

// ---------------- tiled fused readout ----------------
__launch_bounds__(256, 4)
__global__ void k_uout(const float* __restrict__ v, const float* __restrict__ u1w,
                       const float* __restrict__ u1b, const float* __restrict__ u2w,
                       const float* __restrict__ u2b, const int* __restrict__ batch,
                       float* __restrict__ out, int N) {
    __shared__ float sA[64 * 128];
    const int tid = threadIdx.x;
    const int n0 = blockIdx.x * 64;

    for (int i = tid; i < 64 * 32; i += 256) {
        int row = i >> 5, cq = (i & 31) << 2;
        int gr = n0 + row;
        float4 val = (gr < N) ? *(const float4*)&v[((size_t)gr << 7) + cq]
                              : make_float4(0.f, 0.f, 0.f, 0.f);
        *(float4*)&sA[row * 128 + cq] = val;
    }
    __syncthreads();

    const int cg = tid & 31, rg = tid >> 5;
    const int r0 = rg << 3;
    const int c2 = cg << 1;

    float2 acc[8];
    {
        float2 b1v = *(const float2*)&u1b[c2];
        #pragma unroll
        for (int i = 0; i < 8; i++) acc[i] = b1v;
        #pragma unroll 4
        for (int k = 0; k < 128; k++) {
            float2 wv = *(const float2*)&u1w[(k << 6) + c2];
            #pragma unroll
            for (int i = 0; i < 8; i++) {
                float a = sA[(r0 + i) * 128 + k];
                acc[i].x = fmaf(a, wv.x, acc[i].x);
                acc[i].y = fmaf(a, wv.y, acc[i].y);
            }
        }
    }
    __syncthreads();
    #pragma unroll
    for (int i = 0; i < 8; i++) {
        sA[(r0 + i) * 64 + c2 + 0] = sspf(acc[i].x);
        sA[(r0 + i) * 64 + c2 + 1] = sspf(acc[i].y);
    }
    __syncthreads();

    float acc2[8];
    {
        float bb = u2b[cg];
        #pragma unroll
        for (int i = 0; i < 8; i++) acc2[i] = bb;
        #pragma unroll 4
        for (int k = 0; k < 64; k++) {
            float wv = u2w[(k << 5) + cg];
            #pragma unroll
            for (int i = 0; i < 8; i++)
                acc2[i] = fmaf(sA[(r0 + i) * 64 + k], wv, acc2[i]);
        }
    }

    int cur = -1;
    float run = 0.f;
    #pragma unroll
    for (int i = 0; i < 8; i++) {
        int gr = n0 + r0 + i;
        int g = (gr < N) ? batch[gr] : -1;
        if (g != cur) {
            if (cur >= 0) atomicAdd(&out[(size_t)cur * 32 + cg], run);
            cur = g;
            run = 0.f;
        }
        if (g >= 0) run += acc2[i];
    }
    if (cur >= 0) atomicAdd(&out[(size_t)cur * 32 + cg], run);
}

extern "C" void kernel_launch(void* const* d_in, const int* in_sizes, int n_in,
                              void* d_out, int out_size, void* d_ws, size_t ws_size,
                              hipStream_t stream) {
    const float* x      = (const float*)d_in[0];
    const float* pos    = (const float*)d_in[1];
    const int*   batch  = (const int*)d_in[2];
    const int*   ei     = (const int*)d_in[3];
    const float* fe_w1  = (const float*)d_in[4];
    const float* fe_b1  = (const float*)d_in[5];
    const float* bn_g   = (const float*)d_in[6];
    const float* bn_b   = (const float*)d_in[7];
    const float* fe_w2  = (const float*)d_in[8];
    const float* fe_b2  = (const float*)d_in[9];
    const float* lin_w  = (const float*)d_in[10];
    const float* mlp_w1 = (const float*)d_in[11];
    const float* mlp_b1 = (const float*)d_in[12];
    const float* mlp_w2 = (const float*)d_in[13];
    const float* mlp_b2 = (const float*)d_in[14];
    const float* v1_w   = (const float*)d_in[15];
    const float* v1_b   = (const float*)d_in[16];
    const float* v2_w   = (const float*)d_in[17];
    const float* v2_b   = (const float*)d_in[18];
    const float* u1_w   = (const float*)d_in[19];
    const float* u1_b   = (const float*)d_in[20];
    const float* u2_w   = (const float*)d_in[21];
    const float* u2_b   = (const float*)d_in[22];

    const int N = in_sizes[0] / 28;
    const int E = in_sizes[3] / 2;
    const int NB1 = (N + 1023) / 1024;

    char* ws = (char*)d_ws;
    size_t o = 0;
    auto alloc = [&](size_t bytes) { void* p = ws + o; o += (bytes + 255) & ~(size_t)255; return p; };
    int*    counts = (int*)   alloc((size_t)N * 4);
    int*    cursor = (int*)   alloc((size_t)N * 4);
    int*    rowptr = (int*)   alloc((size_t)N * 4);
    int*    bsum   = (int*)   alloc((size_t)NB1 * 4);
    int*    s_src  = (int*)   alloc((size_t)E * 4);
    float*  s_fid  = (float*) alloc((size_t)E * 4);
    float*  stats  = (float*) alloc(128 * 4);
    float*  prm    = (float*) alloc(128 * 4);
    ushort* tab    = (ushort*)alloc((size_t)LAY * K_TAB * 128 * 2);  // 12 MB fp16
    ushort* tab2   = (ushort*)alloc((size_t)LAY * K_TAB * 256 * 2);  // 24 MB paired
    float*  v      = (float*) alloc((size_t)N * 128 * 4);
    ushort* vlin   = (ushort*)alloc((size_t)N * 128 * 2);            // fp16
    ushort* agg    = (ushort*)alloc((size_t)N * 128 * 2);            // fp16
    float*  h      = (float*) alloc((size_t)N * 64 * 4);
    int*    locex  = (int*)   alloc((size_t)N * 4);
    ushort* v1T    = (ushort*)alloc((size_t)LAY * 16384 * 2);   // fp16 transposed weights
    ushort* v2T    = (ushort*)alloc((size_t)LAY * 16384 * 2);
    ushort* linT   = (ushort*)alloc((size_t)LAY * 16384 * 2);
    ushort* fe2T   = (ushort*)alloc((size_t)8192 * 2);

    // -------- weight conversion (fp16, transposed) --------
    k_cvtT128<<<LAY, 256, 0, stream>>>(v1_w, v1T);
    k_cvtT128<<<LAY, 256, 0, stream>>>(v2_w, v2T);
    k_cvtT128<<<LAY, 256, 0, stream>>>(lin_w, linT);
    k_cvtT_fe<<<1, 256, 0, stream>>>(fe_w2, fe2T);

    // -------- one-time edge sort (dst-ordered CSR) --------
    hipMemsetAsync(counts, 0, (size_t)N * 4, stream);
    k_hist<<<(E + 255) / 256, 256, 0, stream>>>(ei, counts, E);
    k_scan1<<<NB1, 1024, 0, stream>>>(counts, locex, bsum, N);
    k_scan2<<<1, 1024, 0, stream>>>(bsum, NB1);
    k_scan3<<<(N + 255) / 256, 256, 0, stream>>>(locex, bsum, cursor, rowptr, N);
    k_scatter<<<(E + 255) / 256, 256, 0, stream>>>(ei, pos, cursor, s_src, s_fid, E);

    // -------- gate tables (fp16), then pair-interleave --------
    k_tab_all<<<LAY * 256, 256, 0, stream>>>(mlp_w1, mlp_b1, mlp_w2, mlp_b2, tab);
    k_pair<<<LAY * K_TAB * 32 / 256, 256, 0, stream>>>(tab, tab2);

    // -------- feature embedding --------
    hipMemsetAsync(stats, 0, 128 * 4, stream);
    k_fe1<<<(N * 64 + 255) / 256, 256, 0, stream>>>(x, fe_w1, fe_b1, h, N);
    k_bnstat<<<256, 256, 0, stream>>>(h, stats, N);
    k_bnfin<<<1, 64, 0, stream>>>(stats, prm, bn_g, bn_b, 1.0f / (float)N);
    const int gblk = (N + 63) / 64;
    k_fe2<<<gblk, 256, 0, stream>>>(h, prm, fe2T, fe_b2, v, N);

    // vlin for layer 0
    k_gemm_rb<<<gblk, 256, 0, stream>>>(v, linT, vlin, N);

    // -------- interaction layers --------
    const int eblk = (N + 7) / 8;
    for (int l = 0; l < LAY; l++) {
        k_edge_csr<<<eblk, 256, 0, stream>>>(
            s_src, s_fid, rowptr, counts, vlin,
            tab2 + (size_t)l * K_TAB * 256, agg, N);
        const ushort* lin_next = (l + 1 < LAY) ? linT + (size_t)(l + 1) * 16384 : nullptr;
        k_update<<<gblk, 512, 0, stream>>>(
            agg, v1T + (size_t)l * 16384, v1_b + (size_t)l * 128,
            v2T + (size_t)l * 16384, v2_b + (size_t)l * 128,
            v, lin_next, vlin, N);
    }

    // -------- fused readout --------
    hipMemsetAsync(d_out, 0, (size_t)out_size * 4, stream);
    k_uout<<<gblk, 256, 0, stream>>>(v, u1_w, u1_b, u2_w, u2_b, batch, (float*)d_out, N);
}

// Round 14
// 910.471 us; speedup vs baseline: 1.0661x; 1.0331x over previous
//
#include <hip/hip_runtime.h>
#include <hip/hip_fp16.h>
#include <math.h>

#define DEV __device__ __forceinline__

constexpr int NGAUSS = 50;
constexpr int LAY = 6;
constexpr int K_TAB = 8192;
constexpr float DMAX = 40.0f;
constexpr float TSCALE = (float)(K_TAB - 1) / DMAX;   // fid = d * TSCALE
constexpr float STEP = 6.0f / 49.0f;
constexpr float COEFF = -0.5f / (STEP * STEP);
constexpr float LN2F = 0.69314718055994531f;
constexpr float PI_OVER_CUT = 0.52359877559829887f;  // pi/6

using f16x8 = __attribute__((ext_vector_type(8))) _Float16;
using f16x4 = __attribute__((ext_vector_type(4))) _Float16;
using f32x4 = __attribute__((ext_vector_type(4))) float;

#define MFMA16(a, b, c) __builtin_amdgcn_mfma_f32_16x16x32_f16(a, b, c, 0, 0, 0)

DEV float sspf(float x) {
    float ax = fabsf(x);
    float e = __expf(-ax);
    return fmaxf(x, 0.f) + __logf(1.f + e) - LN2F;
}

// ---- fp16 pack/unpack helpers (storage fp16, math f32) ----
DEV float4 ld_h4(const ushort* p) {          // 8B load -> 4 floats
    uint2 r = *(const uint2*)p;
    __half2 a = __builtin_bit_cast(__half2, r.x);
    __half2 b = __builtin_bit_cast(__half2, r.y);
    float2 fa = __half22float2(a), fb = __half22float2(b);
    return make_float4(fa.x, fa.y, fb.x, fb.y);
}
DEV void st_h4(ushort* p, float4 v) {        // 4 floats -> 8B store
    uint2 r;
    r.x = __builtin_bit_cast(uint, __float22half2_rn(make_float2(v.x, v.y)));
    r.y = __builtin_bit_cast(uint, __float22half2_rn(make_float2(v.z, v.w)));
    *(uint2*)p = r;
}

// ---------------- weight convert+transpose (fp32 [K][C] -> fp16 [C][K]) ----------------
__global__ void k_cvtT128(const float* __restrict__ src, ushort* __restrict__ dst) {
    const float* s = src + (size_t)blockIdx.x * 16384;
    ushort* d = dst + (size_t)blockIdx.x * 16384;
    for (int i = threadIdx.x; i < 16384; i += 256) {
        int k = i >> 7, c = i & 127;
        d[(c << 7) + k] = __builtin_bit_cast(ushort, (_Float16)s[i]);
    }
}
__global__ void k_cvtT_fe(const float* __restrict__ src, ushort* __restrict__ dst) {
    // fe_w2: [64][128] -> dst[c(128)][k(64)]
    for (int i = threadIdx.x; i < 8192; i += 256) {
        int k = i >> 7, c = i & 127;
        dst[(c << 6) + k] = __builtin_bit_cast(ushort, (_Float16)src[i]);
    }
}

// ---------------- edge sort pre-pass (once per call) ----------------
__global__ void k_hist(const int* __restrict__ ei, int* __restrict__ counts, int E) {
    int e = blockIdx.x * 256 + threadIdx.x;
    if (e < E) atomicAdd(&counts[ei[E + e]], 1);
}

__global__ void k_scan1(const int* __restrict__ counts, int* __restrict__ locex,
                        int* __restrict__ bsum, int n) {
    __shared__ int s_wsum[16];
    const int tid = threadIdx.x;
    const int i = blockIdx.x * 1024 + tid;
    const int lane = tid & 63, wv = tid >> 6;
    int v = (i < n) ? counts[i] : 0;
    int x = v;
    #pragma unroll
    for (int off = 1; off < 64; off <<= 1) {
        int y = __shfl_up(x, off, 64);
        if (lane >= off) x += y;
    }
    if (lane == 63) s_wsum[wv] = x;
    __syncthreads();
    if (wv == 0 && lane < 16) {
        int wval = s_wsum[lane];
        int wx = wval;
        #pragma unroll
        for (int off = 1; off < 16; off <<= 1) {
            int wy = __shfl_up(wx, off, 16);
            if (lane >= off) wx += wy;
        }
        s_wsum[lane] = wx - wval;
    }
    __syncthreads();
    if (i < n) locex[i] = s_wsum[wv] + x - v;
    if (tid == 1023) bsum[blockIdx.x] = s_wsum[15] + x;
}

__global__ void k_scan2(int* __restrict__ bsum, int nb) {
    __shared__ int s_wsum[16];
    const int tid = threadIdx.x;
    const int lane = tid & 63, wv = tid >> 6;
    int v = (tid < nb) ? bsum[tid] : 0;
    int x = v;
    #pragma unroll
    for (int off = 1; off < 64; off <<= 1) {
        int y = __shfl_up(x, off, 64);
        if (lane >= off) x += y;
    }
    if (lane == 63) s_wsum[wv] = x;
    __syncthreads();
    if (wv == 0 && lane < 16) {
        int wval = s_wsum[lane];
        int wx = wval;
        #pragma unroll
        for (int off = 1; off < 16; off <<= 1) {
            int wy = __shfl_up(wx, off, 16);
            if (lane >= off) wx += wy;
        }
        s_wsum[lane] = wx - wval;
    }
    __syncthreads();
    if (tid < nb) bsum[tid] = s_wsum[wv] + x - v;
}

__global__ void k_scan3(const int* __restrict__ locex, const int* __restrict__ bsumex,
                        int* __restrict__ cursor, int* __restrict__ rowptr, int n) {
    int i = blockIdx.x * 256 + threadIdx.x;
    if (i >= n) return;
    int e = locex[i] + bsumex[i >> 10];
    cursor[i] = e;
    rowptr[i] = e;
}

// scatter: one 8B store per edge {src, fid}
__global__ void k_scatter(const int* __restrict__ ei, const float* __restrict__ pos,
                          int* __restrict__ cursor, uint2* __restrict__ s_ef, int E) {
    int e = blockIdx.x * 256 + threadIdx.x;
    if (e >= E) return;
    int r = ei[e], c = ei[E + e];
    int p = atomicAdd(&cursor[c], 1);
    float dx = pos[3 * r + 0] - pos[3 * c + 0];
    float dy = pos[3 * r + 1] - pos[3 * c + 1];
    float dz = pos[3 * r + 2] - pos[3 * c + 2];
    float d = sqrtf(dx * dx + dy * dy + dz * dz);
    float fid = fminf(d * TSCALE, (float)(K_TAB - 2) + 0.999f);
    s_ef[p] = make_uint2((uint)r, __builtin_bit_cast(uint, fid));
}

// ---------------- gate table build (fp16 output), ALL layers in one launch ----------------
__launch_bounds__(256)
__global__ void k_tab_all(const float* __restrict__ w1A, const float* __restrict__ b1A,
                          const float* __restrict__ w2A, const float* __restrict__ b2A,
                          ushort* __restrict__ tabA) {
    const int layer = blockIdx.x >> 8;
    const int k0 = (blockIdx.x & 255) * 32;
    const float* w1 = w1A + (size_t)layer * NGAUSS * 128;
    const float* b1 = b1A + (size_t)layer * 128;
    const float* w2 = w2A + (size_t)layer * 128 * 128;
    const float* b2 = b2A + (size_t)layer * 128;
    ushort* tab = tabA + (size_t)layer * K_TAB * 128;

    __shared__ float s_demb[32][NGAUSS];
    __shared__ float s_t1[32][128];
    const int tid = threadIdx.x;

    for (int i = tid; i < 32 * NGAUSS; i += 256) {
        int r = i / NGAUSS, g = i - r * NGAUSS;
        float d = (float)(k0 + r) * (1.0f / TSCALE);
        float t = d - g * STEP;
        s_demb[r][g] = __expf(COEFF * t * t);
    }
    __syncthreads();

    const int cg = tid & 31, rg = tid >> 5;
    const int r0 = rg << 2;
    const int c4 = cg << 2;

    float4 b1v = *(const float4*)&b1[c4];
    float4 acc[4];
    #pragma unroll
    for (int i = 0; i < 4; i++) acc[i] = b1v;
    #pragma unroll 2
    for (int k = 0; k < NGAUSS; k++) {
        float4 wv = *(const float4*)&w1[(k << 7) + c4];
        #pragma unroll
        for (int i = 0; i < 4; i++) {
            float dv = s_demb[r0 + i][k];
            acc[i].x = fmaf(dv, wv.x, acc[i].x);
            acc[i].y = fmaf(dv, wv.y, acc[i].y);
            acc[i].z = fmaf(dv, wv.z, acc[i].z);
            acc[i].w = fmaf(dv, wv.w, acc[i].w);
        }
    }
    #pragma unroll
    for (int i = 0; i < 4; i++) {
        float4 t;
        t.x = sspf(acc[i].x); t.y = sspf(acc[i].y);
        t.z = sspf(acc[i].z); t.w = sspf(acc[i].w);
        *(float4*)&s_t1[r0 + i][c4] = t;
    }
    __syncthreads();

    float4 b2v = *(const float4*)&b2[c4];
    float4 a2[4];
    #pragma unroll
    for (int i = 0; i < 4; i++) a2[i] = b2v;
    #pragma unroll 4
    for (int k = 0; k < 128; k++) {
        float4 wv = *(const float4*)&w2[(k << 7) + c4];
        #pragma unroll
        for (int i = 0; i < 4; i++) {
            float tv = s_t1[r0 + i][k];
            a2[i].x = fmaf(tv, wv.x, a2[i].x);
            a2[i].y = fmaf(tv, wv.y, a2[i].y);
            a2[i].z = fmaf(tv, wv.z, a2[i].z);
            a2[i].w = fmaf(tv, wv.w, a2[i].w);
        }
    }
    #pragma unroll
    for (int i = 0; i < 4; i++) {
        int knot = k0 + r0 + i;
        float d = (float)knot * (1.0f / TSCALE);
        float cc = 0.5f * (__cosf(d * PI_OVER_CUT) + 1.0f);
        float4 o;
        o.x = a2[i].x * cc; o.y = a2[i].y * cc;
        o.z = a2[i].z * cc; o.w = a2[i].w * cc;
        st_h4(&tab[((size_t)knot << 7) + c4], o);
    }
}

// ---------------- pair-interleave: tab2[i][2c..2c+1] = {T[i][c], T[i+1][c]} ----------------
__global__ void k_pair(const ushort* __restrict__ tab, ushort* __restrict__ tab2) {
    size_t idx = (size_t)blockIdx.x * 256 + threadIdx.x;   // LAY*K_TAB*32 total
    int cg = idx & 31;
    size_t knotg = idx >> 5;           // layer*K_TAB + knot
    int knot = (int)(knotg & (K_TAB - 1));
    const ushort* r0 = tab + (knotg << 7) + (cg << 2);
    const ushort* r1 = (knot < K_TAB - 1) ? r0 + 128 : r0;   // clamp at end
    uint2 a = *(const uint2*)r0;
    uint2 b = *(const uint2*)r1;
    ushort4 al = *(const ushort4*)&a;
    ushort4 bl = *(const ushort4*)&b;
    ushort out[8] = {al.x, bl.x, al.y, bl.y, al.z, bl.z, al.w, bl.w};
    *(uint4*)&tab2[(knotg << 8) + (cg << 3)] = *(const uint4*)out;
}

// ---------------- node-centric CSR edge kernel: 3 loads/edge ----------------
// 1 node per 32-lane group; lane owns 4 channels. 8-edge batches + scalar tail.
__launch_bounds__(256, 8)
__global__ void k_edge_csr(const uint2* __restrict__ s_ef,
                           const int* __restrict__ rowptr, const int* __restrict__ counts,
                           const ushort* __restrict__ vlin, const ushort* __restrict__ tab2,
                           ushort* __restrict__ agg, int N) {
    const int tid = threadIdx.x;
    const int cg = tid & 31;
    const int n = blockIdx.x * 8 + (tid >> 5);
    if (n >= N) return;
    const ushort* tabc = tab2 + (cg << 3);   // lane's 16B slot within 512B row
    const ushort* vlc = vlin + (cg << 2);

    const int rs = rowptr[n];
    const int re = rs + counts[n];
    float4 run = make_float4(0.f, 0.f, 0.f, 0.f);
    int e = rs;
    for (; e + 8 <= re; e += 8) {
        f16x8 TP[8];
        f16x4 VL[8];
        _Float16 FR[8];
        #pragma unroll
        for (int j = 0; j < 8; j++) {
            uint2 ef = s_ef[e + j];
            float fid = __builtin_bit_cast(float, ef.y);
            int i0 = (int)fid;
            FR[j] = (_Float16)(fid - (float)i0);
            TP[j] = *(const f16x8*)(tabc + ((size_t)i0 << 8));
            VL[j] = *(const f16x4*)(vlc + ((size_t)ef.x << 7));
        }
        f16x4 p0 = {0, 0, 0, 0}, p1 = {0, 0, 0, 0};
        #pragma unroll
        for (int j = 0; j < 8; j += 2) {
            f16x4 t0a = {TP[j][0], TP[j][2], TP[j][4], TP[j][6]};
            f16x4 t1a = {TP[j][1], TP[j][3], TP[j][5], TP[j][7]};
            f16x4 t0b = {TP[j+1][0], TP[j+1][2], TP[j+1][4], TP[j+1][6]};
            f16x4 t1b = {TP[j+1][1], TP[j+1][3], TP[j+1][5], TP[j+1][7]};
            f16x4 w0 = t0a + FR[j]     * (t1a - t0a);
            f16x4 w1 = t0b + FR[j + 1] * (t1b - t0b);
            p0 += w0 * VL[j];
            p1 += w1 * VL[j + 1];
        }
        run.x += (float)p0[0] + (float)p1[0];
        run.y += (float)p0[1] + (float)p1[1];
        run.z += (float)p0[2] + (float)p1[2];
        run.w += (float)p0[3] + (float)p1[3];
    }
    for (; e < re; e++) {
        uint2 ef = s_ef[e];
        float fid = __builtin_bit_cast(float, ef.y);
        int i0 = (int)fid;
        _Float16 fr = (_Float16)(fid - (float)i0);
        f16x8 tp = *(const f16x8*)(tabc + ((size_t)i0 << 8));
        f16x4 vl = *(const f16x4*)(vlc + ((size_t)ef.x << 7));
        f16x4 t0 = {tp[0], tp[2], tp[4], tp[6]};
        f16x4 t1 = {tp[1], tp[3], tp[5], tp[7]};
        f16x4 w = t0 + fr * (t1 - t0);
        f16x4 p = w * vl;
        run.x += (float)p[0];
        run.y += (float)p[1];
        run.z += (float)p[2];
        run.w += (float)p[3];
    }
    st_h4(&agg[((size_t)n << 7) + (cg << 2)], run);
}

// ---------------- feature embedding ----------------
__global__ void k_fe1(const float* __restrict__ x, const float* __restrict__ w,
                      const float* __restrict__ b, float* __restrict__ h, int N) {
    int idx = blockIdx.x * 256 + threadIdx.x;
    if (idx >= N * 64) return;
    int n = idx >> 6, c = idx & 63;
    const float* xr = x + (size_t)n * 28;
    float acc = b[c];
    #pragma unroll
    for (int k = 0; k < 28; k++) acc = fmaf(xr[k], w[k * 64 + c], acc);
    h[idx] = acc;
}

__global__ void k_bnstat(const float* __restrict__ h, float* __restrict__ stats, int N) {
    __shared__ float s_s[256], s_q[256];
    int tid = threadIdx.x;
    int c = tid & 63, g = tid >> 6;
    float s = 0.f, q = 0.f;
    for (int n = blockIdx.x * 4 + g; n < N; n += gridDim.x * 4) {
        float v = h[(size_t)n * 64 + c];
        s += v; q += v * v;
    }
    s_s[tid] = s; s_q[tid] = q;
    __syncthreads();
    if (tid < 64) {
        s = s_s[tid] + s_s[tid + 64] + s_s[tid + 128] + s_s[tid + 192];
        q = s_q[tid] + s_q[tid + 64] + s_q[tid + 128] + s_q[tid + 192];
        atomicAdd(&stats[tid], s);
        atomicAdd(&stats[64 + tid], q);
    }
}

__global__ void k_bnfin(const float* __restrict__ stats, float* __restrict__ prm,
                        const float* __restrict__ gamma, const float* __restrict__ beta,
                        float invN) {
    int c = threadIdx.x;  // 64 threads
    float mu = stats[c] * invN;
    float var = stats[64 + c] * invN - mu * mu;
    float sc = gamma[c] * rsqrtf(var + 1e-5f);
    prm[c] = sc;
    prm[64 + c] = beta[c] - mu * sc;
}

// ---------------- MFMA fe2: v = relu( relu(bn(h)) @ fe_w2 + b2 ), K=64 ----------------
__launch_bounds__(256, 4)
__global__ void k_fe2(const float* __restrict__ h, const float* __restrict__ prm,
                      const ushort* __restrict__ w2T, const float* __restrict__ b2,
                      float* __restrict__ v, int N) {
    constexpr int LDP = 72;
    __shared__ _Float16 sH[64 * LDP];
    const int tid = threadIdx.x;
    const int n0 = blockIdx.x * 64;

    for (int i = tid; i < 64 * 16; i += 256) {
        int row = i >> 4, c4 = (i & 15) << 2;
        int gr = n0 + row;
        float4 hv = (gr < N) ? *(const float4*)&h[((size_t)gr << 6) + c4]
                             : make_float4(0.f, 0.f, 0.f, 0.f);
        float4 sc = *(const float4*)&prm[c4];
        float4 sh = *(const float4*)&prm[64 + c4];
        f16x4 o;
        o[0] = (_Float16)fmaxf(fmaf(hv.x, sc.x, sh.x), 0.f);
        o[1] = (_Float16)fmaxf(fmaf(hv.y, sc.y, sh.y), 0.f);
        o[2] = (_Float16)fmaxf(fmaf(hv.z, sc.z, sh.z), 0.f);
        o[3] = (_Float16)fmaxf(fmaf(hv.w, sc.w, sh.w), 0.f);
        *(f16x4*)&sH[row * LDP + c4] = o;
    }
    __syncthreads();

    const int wid = tid >> 6, lane = tid & 63;
    const int lr = lane & 15, lg = lane >> 4;
    const int kof = lg << 3;
    const int arow = wid * 16 + lr;
    const int drow0 = wid * 16 + (lg << 2);

    f16x8 a0 = *(const f16x8*)&sH[arow * LDP + kof];
    f16x8 a1 = *(const f16x8*)&sH[arow * LDP + 32 + kof];

    #pragma unroll
    for (int n = 0; n < 8; n++) {
        const ushort* bp = w2T + (((size_t)(n << 4) + lr) << 6);
        f32x4 c = {0.f, 0.f, 0.f, 0.f};
        c = MFMA16(a0, *(const f16x8*)(bp + kof), c);
        c = MFMA16(a1, *(const f16x8*)(bp + 32 + kof), c);
        int col = (n << 4) + lr;
        float bb = b2[col];
        #pragma unroll
        for (int r = 0; r < 4; r++) {
            int gr = n0 + drow0 + r;
            if (gr < N) v[((size_t)gr << 7) + col] = fmaxf(c[r] + bb, 0.f);
        }
    }
}

// ---------------- MFMA single GEMM: vlin(fp16) = v @ lin, K=128 ----------------
__launch_bounds__(256, 4)
__global__ void k_gemm_rb(const float* __restrict__ A, const ushort* __restrict__ wT,
                          ushort* __restrict__ C, int N) {
    constexpr int LDP = 136;
    __shared__ _Float16 sA[64 * LDP];
    const int tid = threadIdx.x;
    const int n0 = blockIdx.x * 64;

    for (int i = tid; i < 64 * 32; i += 256) {
        int row = i >> 5, c4 = (i & 31) << 2;
        int gr = n0 + row;
        float4 val = (gr < N) ? *(const float4*)&A[((size_t)gr << 7) + c4]
                              : make_float4(0.f, 0.f, 0.f, 0.f);
        f16x4 o;
        o[0] = (_Float16)val.x; o[1] = (_Float16)val.y;
        o[2] = (_Float16)val.z; o[3] = (_Float16)val.w;
        *(f16x4*)&sA[row * LDP + c4] = o;
    }
    __syncthreads();

    const int wid = tid >> 6, lane = tid & 63;
    const int lr = lane & 15, lg = lane >> 4;
    const int kof = lg << 3;
    const int arow = wid * 16 + lr;
    const int drow0 = wid * 16 + (lg << 2);

    f16x8 a0 = *(const f16x8*)&sA[arow * LDP + kof];
    f16x8 a1 = *(const f16x8*)&sA[arow * LDP + 32 + kof];
    f16x8 a2 = *(const f16x8*)&sA[arow * LDP + 64 + kof];
    f16x8 a3 = *(const f16x8*)&sA[arow * LDP + 96 + kof];

    #pragma unroll
    for (int n = 0; n < 8; n++) {
        const ushort* bp = wT + (((size_t)(n << 4) + lr) << 7);
        f32x4 c = {0.f, 0.f, 0.f, 0.f};
        c = MFMA16(a0, *(const f16x8*)(bp + kof), c);
        c = MFMA16(a1, *(const f16x8*)(bp + 32 + kof), c);
        c = MFMA16(a2, *(const f16x8*)(bp + 64 + kof), c);
        c = MFMA16(a3, *(const f16x8*)(bp + 96 + kof), c);
        int col = (n << 4) + lr;
        #pragma unroll
        for (int r = 0; r < 4; r++) {
            int gr = n0 + drow0 + r;
            if (gr < N) C[((size_t)gr << 7) + col] =
                __builtin_bit_cast(ushort, (_Float16)c[r]);
        }
    }
}

// ---------------- MFMA fused layer update: 3 GEMMs, 512 threads / 8 waves, 4 blk/CU ----------------
__launch_bounds__(512, 8)
__global__ void k_update(const ushort* __restrict__ agg,
                         const ushort* __restrict__ w1T, const float* __restrict__ b1,
                         const ushort* __restrict__ w2T, const float* __restrict__ b2,
                         float* __restrict__ v,
                         const ushort* __restrict__ linT, ushort* __restrict__ vlin, int N) {
    constexpr int LDP = 136;
    __shared__ _Float16 sA[64 * LDP];   // 17.4 KB: agg -> t -> v_new (fp16)
    const int tid = threadIdx.x;
    const int n0 = blockIdx.x * 64;

    for (int i = tid; i < 64 * 32; i += 512) {
        int row = i >> 5, c4 = (i & 31) << 2;
        int gr = n0 + row;
        uint2 val = (gr < N) ? *(const uint2*)&agg[((size_t)gr << 7) + c4]
                             : make_uint2(0u, 0u);
        *(uint2*)&sA[row * LDP + c4] = val;   // raw fp16 copy
    }
    __syncthreads();

    const int wid = tid >> 6, lane = tid & 63;
    const int wr = wid & 3, wc = wid >> 2;
    const int lr = lane & 15, lg = lane >> 4;
    const int kof = lg << 3;
    const int arow = wr * 16 + lr;
    const int drow0 = wr * 16 + (lg << 2);
    const int cbase = wc << 6;   // 0 or 64

    f16x8 a0, a1, a2, a3;
    f32x4 acc[4];

    // ---- GEMM 1: t = ssp(agg @ W1 + b1) ----
    a0 = *(const f16x8*)&sA[arow * LDP + kof];
    a1 = *(const f16x8*)&sA[arow * LDP + 32 + kof];
    a2 = *(const f16x8*)&sA[arow * LDP + 64 + kof];
    a3 = *(const f16x8*)&sA[arow * LDP + 96 + kof];
    #pragma unroll
    for (int n = 0; n < 4; n++) {
        const ushort* bp = w1T + (((size_t)(cbase + (n << 4)) + lr) << 7);
        f32x4 c = {0.f, 0.f, 0.f, 0.f};
        c = MFMA16(a0, *(const f16x8*)(bp + kof), c);
        c = MFMA16(a1, *(const f16x8*)(bp + 32 + kof), c);
        c = MFMA16(a2, *(const f16x8*)(bp + 64 + kof), c);
        c = MFMA16(a3, *(const f16x8*)(bp + 96 + kof), c);
        acc[n] = c;
    }
    __syncthreads();
    #pragma unroll
    for (int n = 0; n < 4; n++) {
        int col = cbase + (n << 4) + lr;
        float bb = b1[col];
        #pragma unroll
        for (int r = 0; r < 4; r++)
            sA[(drow0 + r) * LDP + col] = (_Float16)sspf(acc[n][r] + bb);
    }
    __syncthreads();

    // ---- GEMM 2: v_new = t @ W2 + b2 + v_old ----
    a0 = *(const f16x8*)&sA[arow * LDP + kof];
    a1 = *(const f16x8*)&sA[arow * LDP + 32 + kof];
    a2 = *(const f16x8*)&sA[arow * LDP + 64 + kof];
    a3 = *(const f16x8*)&sA[arow * LDP + 96 + kof];
    #pragma unroll
    for (int n = 0; n < 4; n++) {
        const ushort* bp = w2T + (((size_t)(cbase + (n << 4)) + lr) << 7);
        f32x4 c = {0.f, 0.f, 0.f, 0.f};
        c = MFMA16(a0, *(const f16x8*)(bp + kof), c);
        c = MFMA16(a1, *(const f16x8*)(bp + 32 + kof), c);
        c = MFMA16(a2, *(const f16x8*)(bp + 64 + kof), c);
        c = MFMA16(a3, *(const f16x8*)(bp + 96 + kof), c);
        acc[n] = c;
    }
    __syncthreads();
    #pragma unroll
    for (int n = 0; n < 4; n++) {
        int col = cbase + (n << 4) + lr;
        float bb = b2[col];
        #pragma unroll
        for (int r = 0; r < 4; r++) {
            int gr = n0 + drow0 + r;
            float vn = 0.f;
            if (gr < N) {
                vn = acc[n][r] + bb + v[((size_t)gr << 7) + col];
                v[((size_t)gr << 7) + col] = vn;
            }
            sA[(drow0 + r) * LDP + col] = (_Float16)vn;
        }
    }
    if (!linT) return;
    __syncthreads();

    // ---- GEMM 3: vlin(fp16) = v_new @ lin ----
    a0 = *(const f16x8*)&sA[arow * LDP + kof];
    a1 = *(const f16x8*)&sA[arow * LDP + 32 + kof];
    a2 = *(const f16x8*)&sA[arow * LDP + 64 + kof];
    a3 = *(const f16x8*)&sA[arow * LDP + 96 + kof];
    #pragma unroll
    for (int n = 0; n < 4; n++) {
        const ushort* bp = linT + (((size_t)(cbase + (n << 4)) + lr) << 7);
        f32x4 c = {0.f, 0.f, 0.f, 0.f};
        c = MFMA16(a0, *(const f16x8*)(bp + kof), c);
        c = MFMA16(a1, *(const f16x8*)(bp + 32 + kof), c);
        c = MFMA16(a2, *(const f16x8*)(bp + 64 + kof), c);
        c = MFMA16(a3, *(const f16x8*)(bp + 96 + kof), c);
        int col = cbase + (n << 4) + lr;
        #pragma unroll
        for (int r = 0; r < 4; r++) {
            int gr = n0 + drow0 + r;
            if (gr < N) vlin[((size_t)gr << 7) + col] =
                __builtin_bit_cast(ushort, (_Float16)c[r]);
        }
    }
}

// ---------------- tiled fused readout ----------------
__launch_bounds__(256, 4)
__global__ void k_uout(const float* __restrict__ v, const float* __restrict__ u1w,
                       const float* __restrict__ u1b, const float* __restrict__ u2w,
                       const float* __restrict__ u2b, const int* __restrict__ batch,
                       float* __restrict__ out, int N) {
    __shared__ float sA[64 * 128];
    const int tid = threadIdx.x;
    const int n0 = blockIdx.x * 64;

    for (int i = tid; i < 64 * 32; i += 256) {
        int row = i >> 5, cq = (i & 31) << 2;
        int gr = n0 + row;
        float4 val = (gr < N) ? *(const float4*)&v[((size_t)gr << 7) + cq]
                              : make_float4(0.f, 0.f, 0.f, 0.f);
        *(float4*)&sA[row * 128 + cq] = val;
    }
    __syncthreads();

    const int cg = tid & 31, rg = tid >> 5;
    const int r0 = rg << 3;
    const int c2 = cg << 1;

    float2 acc[8];
    {
        float2 b1v = *(const float2*)&u1b[c2];
        #pragma unroll
        for (int i = 0; i < 8; i++) acc[i] = b1v;
        #pragma unroll 4
        for (int k = 0; k < 128; k++) {
            float2 wv = *(const float2*)&u1w[(k << 6) + c2];
            #pragma unroll
            for (int i = 0; i < 8; i++) {
                float a = sA[(r0 + i) * 128 + k];
                acc[i].x = fmaf(a, wv.x, acc[i].x);
                acc[i].y = fmaf(a, wv.y, acc[i].y);
            }
        }
    }
    __syncthreads();
    #pragma unroll
    for (int i = 0; i < 8; i++) {
        sA[(r0 + i) * 64 + c2 + 0] = sspf(acc[i].x);
        sA[(r0 + i) * 64 + c2 + 1] = sspf(acc[i].y);
    }
    __syncthreads();

    float acc2[8];
    {
        float bb = u2b[cg];
        #pragma unroll
        for (int i = 0; i < 8; i++) acc2[i] = bb;
        #pragma unroll 4
        for (int k = 0; k < 64; k++) {
            float wv = u2w[(k << 5) + cg];
            #pragma unroll
            for (int i = 0; i < 8; i++)
                acc2[i] = fmaf(sA[(r0 + i) * 64 + k], wv, acc2[i]);
        }
    }

    int cur = -1;
    float run = 0.f;
    #pragma unroll
    for (int i = 0; i < 8; i++) {
        int gr = n0 + r0 + i;
        int g = (gr < N) ? batch[gr] : -1;
        if (g != cur) {
            if (cur >= 0) atomicAdd(&out[(size_t)cur * 32 + cg], run);
            cur = g;
            run = 0.f;
        }
        if (g >= 0) run += acc2[i];
    }
    if (cur >= 0) atomicAdd(&out[(size_t)cur * 32 + cg], run);
}

extern "C" void kernel_launch(void* const* d_in, const int* in_sizes, int n_in,
                              void* d_out, int out_size, void* d_ws, size_t ws_size,
                              hipStream_t stream) {
    const float* x      = (const float*)d_in[0];
    const float* pos    = (const float*)d_in[1];
    const int*   batch  = (const int*)d_in[2];
    const int*   ei     = (const int*)d_in[3];
    const float* fe_w1  = (const float*)d_in[4];
    const float* fe_b1  = (const float*)d_in[5];
    const float* bn_g   = (const float*)d_in[6];
    const float* bn_b   = (const float*)d_in[7];
    const float* fe_w2  = (const float*)d_in[8];
    const float* fe_b2  = (const float*)d_in[9];
    const float* lin_w  = (const float*)d_in[10];
    const float* mlp_w1 = (const float*)d_in[11];
    const float* mlp_b1 = (const float*)d_in[12];
    const float* mlp_w2 = (const float*)d_in[13];
    const float* mlp_b2 = (const float*)d_in[14];
    const float* v1_w   = (const float*)d_in[15];
    const float* v1_b   = (const float*)d_in[16];
    const float* v2_w   = (const float*)d_in[17];
    const float* v2_b   = (const float*)d_in[18];
    const float* u1_w   = (const float*)d_in[19];
    const float* u1_b   = (const float*)d_in[20];
    const float* u2_w   = (const float*)d_in[21];
    const float* u2_b   = (const float*)d_in[22];

    const int N = in_sizes[0] / 28;
    const int E = in_sizes[3] / 2;
    const int NB1 = (N + 1023) / 1024;

    char* ws = (char*)d_ws;
    size_t o = 0;
    auto alloc = [&](size_t bytes) { void* p = ws + o; o += (bytes + 255) & ~(size_t)255; return p; };
    int*    counts = (int*)   alloc((size_t)N * 4);
    int*    cursor = (int*)   alloc((size_t)N * 4);
    int*    rowptr = (int*)   alloc((size_t)N * 4);
    int*    bsum   = (int*)   alloc((size_t)NB1 * 4);
    uint2*  s_ef   = (uint2*) alloc((size_t)E * 8);
    float*  stats  = (float*) alloc(128 * 4);
    float*  prm    = (float*) alloc(128 * 4);
    ushort* tab    = (ushort*)alloc((size_t)LAY * K_TAB * 128 * 2);  // 12 MB fp16
    ushort* tab2   = (ushort*)alloc((size_t)LAY * K_TAB * 256 * 2);  // 24 MB paired
    float*  v      = (float*) alloc((size_t)N * 128 * 4);
    ushort* vlin   = (ushort*)alloc((size_t)N * 128 * 2);            // fp16
    ushort* agg    = (ushort*)alloc((size_t)N * 128 * 2);            // fp16
    float*  h      = (float*) alloc((size_t)N * 64 * 4);
    int*    locex  = (int*)   alloc((size_t)N * 4);
    ushort* v1T    = (ushort*)alloc((size_t)LAY * 16384 * 2);   // fp16 transposed weights
    ushort* v2T    = (ushort*)alloc((size_t)LAY * 16384 * 2);
    ushort* linT   = (ushort*)alloc((size_t)LAY * 16384 * 2);
    ushort* fe2T   = (ushort*)alloc((size_t)8192 * 2);

    // -------- weight conversion (fp16, transposed) --------
    k_cvtT128<<<LAY, 256, 0, stream>>>(v1_w, v1T);
    k_cvtT128<<<LAY, 256, 0, stream>>>(v2_w, v2T);
    k_cvtT128<<<LAY, 256, 0, stream>>>(lin_w, linT);
    k_cvtT_fe<<<1, 256, 0, stream>>>(fe_w2, fe2T);

    // -------- one-time edge sort (dst-ordered CSR) --------
    hipMemsetAsync(counts, 0, (size_t)N * 4, stream);
    k_hist<<<(E + 255) / 256, 256, 0, stream>>>(ei, counts, E);
    k_scan1<<<NB1, 1024, 0, stream>>>(counts, locex, bsum, N);
    k_scan2<<<1, 1024, 0, stream>>>(bsum, NB1);
    k_scan3<<<(N + 255) / 256, 256, 0, stream>>>(locex, bsum, cursor, rowptr, N);
    k_scatter<<<(E + 255) / 256, 256, 0, stream>>>(ei, pos, cursor, s_ef, E);

    // -------- gate tables (fp16), then pair-interleave --------
    k_tab_all<<<LAY * 256, 256, 0, stream>>>(mlp_w1, mlp_b1, mlp_w2, mlp_b2, tab);
    k_pair<<<LAY * K_TAB * 32 / 256, 256, 0, stream>>>(tab, tab2);

    // -------- feature embedding --------
    hipMemsetAsync(stats, 0, 128 * 4, stream);
    k_fe1<<<(N * 64 + 255) / 256, 256, 0, stream>>>(x, fe_w1, fe_b1, h, N);
    k_bnstat<<<256, 256, 0, stream>>>(h, stats, N);
    k_bnfin<<<1, 64, 0, stream>>>(stats, prm, bn_g, bn_b, 1.0f / (float)N);
    const int gblk = (N + 63) / 64;
    k_fe2<<<gblk, 256, 0, stream>>>(h, prm, fe2T, fe_b2, v, N);

    // vlin for layer 0
    k_gemm_rb<<<gblk, 256, 0, stream>>>(v, linT, vlin, N);

    // -------- interaction layers --------
    const int eblk = (N + 7) / 8;
    for (int l = 0; l < LAY; l++) {
        k_edge_csr<<<eblk, 256, 0, stream>>>(
            s_ef, rowptr, counts, vlin,
            tab2 + (size_t)l * K_TAB * 256, agg, N);
        const ushort* lin_next = (l + 1 < LAY) ? linT + (size_t)(l + 1) * 16384 : nullptr;
        k_update<<<gblk, 512, 0, stream>>>(
            agg, v1T + (size_t)l * 16384, v1_b + (size_t)l * 128,
            v2T + (size_t)l * 16384, v2_b + (size_t)l * 128,
            v, lin_next, vlin, N);
    }

    // -------- fused readout --------
    hipMemsetAsync(d_out, 0, (size_t)out_size * 4, stream);
    k_uout<<<gblk, 256, 0, stream>>>(v, u1_w, u1_b, u2_w, u2_b, batch, (float*)d_out, N);
}

// Round 15
// 891.222 us; speedup vs baseline: 1.0892x; 1.0216x over previous
//
#include <hip/hip_runtime.h>
#include <hip/hip_fp16.h>
#include <math.h>

#define DEV __device__ __forceinline__

constexpr int NGAUSS = 50;
constexpr int LAY = 6;
constexpr int K_TAB = 8192;
constexpr float DMAX = 40.0f;
constexpr float TSCALE = (float)(K_TAB - 1) / DMAX;   // fid = d * TSCALE
constexpr float STEP = 6.0f / 49.0f;
constexpr float COEFF = -0.5f / (STEP * STEP);
constexpr float LN2F = 0.69314718055994531f;
constexpr float PI_OVER_CUT = 0.52359877559829887f;  // pi/6

using f16x8 = __attribute__((ext_vector_type(8))) _Float16;
using f16x4 = __attribute__((ext_vector_type(4))) _Float16;
using f32x4 = __attribute__((ext_vector_type(4))) float;

#define MFMA16(a, b, c) __builtin_amdgcn_mfma_f32_16x16x32_f16(a, b, c, 0, 0, 0)

DEV float sspf(float x) {
    float ax = fabsf(x);
    float e = __expf(-ax);
    return fmaxf(x, 0.f) + __logf(1.f + e) - LN2F;
}

// ---- fp16 pack/unpack helpers (storage fp16, math f32) ----
DEV float4 ld_h4(const ushort* p) {          // 8B load -> 4 floats
    uint2 r = *(const uint2*)p;
    __half2 a = __builtin_bit_cast(__half2, r.x);
    __half2 b = __builtin_bit_cast(__half2, r.y);
    float2 fa = __half22float2(a), fb = __half22float2(b);
    return make_float4(fa.x, fa.y, fb.x, fb.y);
}
DEV void st_h4(ushort* p, float4 v) {        // 4 floats -> 8B store
    uint2 r;
    r.x = __builtin_bit_cast(uint, __float22half2_rn(make_float2(v.x, v.y)));
    r.y = __builtin_bit_cast(uint, __float22half2_rn(make_float2(v.z, v.w)));
    *(uint2*)p = r;
}

// ---------------- weight convert+transpose (fp32 [K][C] -> fp16 [C][K]) ----------------
__global__ void k_cvtT128(const float* __restrict__ src, ushort* __restrict__ dst) {
    const float* s = src + (size_t)blockIdx.x * 16384;
    ushort* d = dst + (size_t)blockIdx.x * 16384;
    for (int i = threadIdx.x; i < 16384; i += 256) {
        int k = i >> 7, c = i & 127;
        d[(c << 7) + k] = __builtin_bit_cast(ushort, (_Float16)s[i]);
    }
}
__global__ void k_cvtT_fe(const float* __restrict__ src, ushort* __restrict__ dst) {
    // fe_w2: [64][128] -> dst[c(128)][k(64)]
    for (int i = threadIdx.x; i < 8192; i += 256) {
        int k = i >> 7, c = i & 127;
        dst[(c << 6) + k] = __builtin_bit_cast(ushort, (_Float16)src[i]);
    }
}

// ---------------- edge sort pre-pass (once per call) ----------------
__global__ void k_hist(const int* __restrict__ ei, int* __restrict__ counts, int E) {
    int e = blockIdx.x * 256 + threadIdx.x;
    if (e < E) atomicAdd(&counts[ei[E + e]], 1);
}

__global__ void k_scan1(const int* __restrict__ counts, int* __restrict__ locex,
                        int* __restrict__ bsum, int n) {
    __shared__ int s_wsum[16];
    const int tid = threadIdx.x;
    const int i = blockIdx.x * 1024 + tid;
    const int lane = tid & 63, wv = tid >> 6;
    int v = (i < n) ? counts[i] : 0;
    int x = v;
    #pragma unroll
    for (int off = 1; off < 64; off <<= 1) {
        int y = __shfl_up(x, off, 64);
        if (lane >= off) x += y;
    }
    if (lane == 63) s_wsum[wv] = x;
    __syncthreads();
    if (wv == 0 && lane < 16) {
        int wval = s_wsum[lane];
        int wx = wval;
        #pragma unroll
        for (int off = 1; off < 16; off <<= 1) {
            int wy = __shfl_up(wx, off, 16);
            if (lane >= off) wx += wy;
        }
        s_wsum[lane] = wx - wval;
    }
    __syncthreads();
    if (i < n) locex[i] = s_wsum[wv] + x - v;
    if (tid == 1023) bsum[blockIdx.x] = s_wsum[15] + x;
}

__global__ void k_scan2(int* __restrict__ bsum, int nb) {
    __shared__ int s_wsum[16];
    const int tid = threadIdx.x;
    const int lane = tid & 63, wv = tid >> 6;
    int v = (tid < nb) ? bsum[tid] : 0;
    int x = v;
    #pragma unroll
    for (int off = 1; off < 64; off <<= 1) {
        int y = __shfl_up(x, off, 64);
        if (lane >= off) x += y;
    }
    if (lane == 63) s_wsum[wv] = x;
    __syncthreads();
    if (wv == 0 && lane < 16) {
        int wval = s_wsum[lane];
        int wx = wval;
        #pragma unroll
        for (int off = 1; off < 16; off <<= 1) {
            int wy = __shfl_up(wx, off, 16);
            if (lane >= off) wx += wy;
        }
        s_wsum[lane] = wx - wval;
    }
    __syncthreads();
    if (tid < nb) bsum[tid] = s_wsum[wv] + x - v;
}

__global__ void k_scan3(const int* __restrict__ locex, const int* __restrict__ bsumex,
                        int* __restrict__ cursor, int* __restrict__ rowptr, int n) {
    int i = blockIdx.x * 256 + threadIdx.x;
    if (i >= n) return;
    int e = locex[i] + bsumex[i >> 10];
    cursor[i] = e;
    rowptr[i] = e;
}

// scatter: one 8B store per edge {src, fid}
__global__ void k_scatter(const int* __restrict__ ei, const float* __restrict__ pos,
                          int* __restrict__ cursor, uint2* __restrict__ s_ef, int E) {
    int e = blockIdx.x * 256 + threadIdx.x;
    if (e >= E) return;
    int r = ei[e], c = ei[E + e];
    int p = atomicAdd(&cursor[c], 1);
    float dx = pos[3 * r + 0] - pos[3 * c + 0];
    float dy = pos[3 * r + 1] - pos[3 * c + 1];
    float dz = pos[3 * r + 2] - pos[3 * c + 2];
    float d = sqrtf(dx * dx + dy * dy + dz * dz);
    float fid = fminf(d * TSCALE, (float)(K_TAB - 2) + 0.999f);
    s_ef[p] = make_uint2((uint)r, __builtin_bit_cast(uint, fid));
}

// ---------------- gate table build (fp16 output), ALL layers in one launch ----------------
__launch_bounds__(256)
__global__ void k_tab_all(const float* __restrict__ w1A, const float* __restrict__ b1A,
                          const float* __restrict__ w2A, const float* __restrict__ b2A,
                          ushort* __restrict__ tabA) {
    const int layer = blockIdx.x >> 8;
    const int k0 = (blockIdx.x & 255) * 32;
    const float* w1 = w1A + (size_t)layer * NGAUSS * 128;
    const float* b1 = b1A + (size_t)layer * 128;
    const float* w2 = w2A + (size_t)layer * 128 * 128;
    const float* b2 = b2A + (size_t)layer * 128;
    ushort* tab = tabA + (size_t)layer * K_TAB * 128;

    __shared__ float s_demb[32][NGAUSS];
    __shared__ float s_t1[32][128];
    const int tid = threadIdx.x;

    for (int i = tid; i < 32 * NGAUSS; i += 256) {
        int r = i / NGAUSS, g = i - r * NGAUSS;
        float d = (float)(k0 + r) * (1.0f / TSCALE);
        float t = d - g * STEP;
        s_demb[r][g] = __expf(COEFF * t * t);
    }
    __syncthreads();

    const int cg = tid & 31, rg = tid >> 5;
    const int r0 = rg << 2;
    const int c4 = cg << 2;

    float4 b1v = *(const float4*)&b1[c4];
    float4 acc[4];
    #pragma unroll
    for (int i = 0; i < 4; i++) acc[i] = b1v;
    #pragma unroll 2
    for (int k = 0; k < NGAUSS; k++) {
        float4 wv = *(const float4*)&w1[(k << 7) + c4];
        #pragma unroll
        for (int i = 0; i < 4; i++) {
            float dv = s_demb[r0 + i][k];
            acc[i].x = fmaf(dv, wv.x, acc[i].x);
            acc[i].y = fmaf(dv, wv.y, acc[i].y);
            acc[i].z = fmaf(dv, wv.z, acc[i].z);
            acc[i].w = fmaf(dv, wv.w, acc[i].w);
        }
    }
    #pragma unroll
    for (int i = 0; i < 4; i++) {
        float4 t;
        t.x = sspf(acc[i].x); t.y = sspf(acc[i].y);
        t.z = sspf(acc[i].z); t.w = sspf(acc[i].w);
        *(float4*)&s_t1[r0 + i][c4] = t;
    }
    __syncthreads();

    float4 b2v = *(const float4*)&b2[c4];
    float4 a2[4];
    #pragma unroll
    for (int i = 0; i < 4; i++) a2[i] = b2v;
    #pragma unroll 4
    for (int k = 0; k < 128; k++) {
        float4 wv = *(const float4*)&w2[(k << 7) + c4];
        #pragma unroll
        for (int i = 0; i < 4; i++) {
            float tv = s_t1[r0 + i][k];
            a2[i].x = fmaf(tv, wv.x, a2[i].x);
            a2[i].y = fmaf(tv, wv.y, a2[i].y);
            a2[i].z = fmaf(tv, wv.z, a2[i].z);
            a2[i].w = fmaf(tv, wv.w, a2[i].w);
        }
    }
    #pragma unroll
    for (int i = 0; i < 4; i++) {
        int knot = k0 + r0 + i;
        float d = (float)knot * (1.0f / TSCALE);
        float cc = 0.5f * (__cosf(d * PI_OVER_CUT) + 1.0f);
        float4 o;
        o.x = a2[i].x * cc; o.y = a2[i].y * cc;
        o.z = a2[i].z * cc; o.w = a2[i].w * cc;
        st_h4(&tab[((size_t)knot << 7) + c4], o);
    }
}

// ---------------- pair-interleave: tab2[i][2c..2c+1] = {T[i][c], T[i+1][c]} ----------------
__global__ void k_pair(const ushort* __restrict__ tab, ushort* __restrict__ tab2) {
    size_t idx = (size_t)blockIdx.x * 256 + threadIdx.x;   // LAY*K_TAB*32 total
    int cg = idx & 31;
    size_t knotg = idx >> 5;           // layer*K_TAB + knot
    int knot = (int)(knotg & (K_TAB - 1));
    const ushort* r0 = tab + (knotg << 7) + (cg << 2);
    const ushort* r1 = (knot < K_TAB - 1) ? r0 + 128 : r0;   // clamp at end
    uint2 a = *(const uint2*)r0;
    uint2 b = *(const uint2*)r1;
    ushort4 al = *(const ushort4*)&a;
    ushort4 bl = *(const ushort4*)&b;
    ushort out[8] = {al.x, bl.x, al.y, bl.y, al.z, bl.z, al.w, bl.w};
    *(uint4*)&tab2[(knotg << 8) + (cg << 3)] = *(const uint4*)out;
}

// ---------------- node-centric CSR edge kernel: 3 loads/edge ----------------
__launch_bounds__(256, 8)
__global__ void k_edge_csr(const uint2* __restrict__ s_ef,
                           const int* __restrict__ rowptr, const int* __restrict__ counts,
                           const ushort* __restrict__ vlin, const ushort* __restrict__ tab2,
                           ushort* __restrict__ agg, int N) {
    const int tid = threadIdx.x;
    const int cg = tid & 31;
    const int n = blockIdx.x * 8 + (tid >> 5);
    if (n >= N) return;
    const ushort* tabc = tab2 + (cg << 3);   // lane's 16B slot within 512B row
    const ushort* vlc = vlin + (cg << 2);

    const int rs = rowptr[n];
    const int re = rs + counts[n];
    float4 run = make_float4(0.f, 0.f, 0.f, 0.f);
    int e = rs;
    for (; e + 8 <= re; e += 8) {
        f16x8 TP[8];
        f16x4 VL[8];
        _Float16 FR[8];
        #pragma unroll
        for (int j = 0; j < 8; j++) {
            uint2 ef = s_ef[e + j];
            float fid = __builtin_bit_cast(float, ef.y);
            int i0 = (int)fid;
            FR[j] = (_Float16)(fid - (float)i0);
            TP[j] = *(const f16x8*)(tabc + ((size_t)i0 << 8));
            VL[j] = *(const f16x4*)(vlc + ((size_t)ef.x << 7));
        }
        f16x4 p0 = {0, 0, 0, 0}, p1 = {0, 0, 0, 0};
        #pragma unroll
        for (int j = 0; j < 8; j += 2) {
            f16x4 t0a = {TP[j][0], TP[j][2], TP[j][4], TP[j][6]};
            f16x4 t1a = {TP[j][1], TP[j][3], TP[j][5], TP[j][7]};
            f16x4 t0b = {TP[j+1][0], TP[j+1][2], TP[j+1][4], TP[j+1][6]};
            f16x4 t1b = {TP[j+1][1], TP[j+1][3], TP[j+1][5], TP[j+1][7]};
            f16x4 w0 = t0a + FR[j]     * (t1a - t0a);
            f16x4 w1 = t0b + FR[j + 1] * (t1b - t0b);
            p0 += w0 * VL[j];
            p1 += w1 * VL[j + 1];
        }
        run.x += (float)p0[0] + (float)p1[0];
        run.y += (float)p0[1] + (float)p1[1];
        run.z += (float)p0[2] + (float)p1[2];
        run.w += (float)p0[3] + (float)p1[3];
    }
    for (; e < re; e++) {
        uint2 ef = s_ef[e];
        float fid = __builtin_bit_cast(float, ef.y);
        int i0 = (int)fid;
        _Float16 fr = (_Float16)(fid - (float)i0);
        f16x8 tp = *(const f16x8*)(tabc + ((size_t)i0 << 8));
        f16x4 vl = *(const f16x4*)(vlc + ((size_t)ef.x << 7));
        f16x4 t0 = {tp[0], tp[2], tp[4], tp[6]};
        f16x4 t1 = {tp[1], tp[3], tp[5], tp[7]};
        f16x4 w = t0 + fr * (t1 - t0);
        f16x4 p = w * vl;
        run.x += (float)p[0];
        run.y += (float)p[1];
        run.z += (float)p[2];
        run.w += (float)p[3];
    }
    st_h4(&agg[((size_t)n << 7) + (cg << 2)], run);
}

// ---------------- feature embedding ----------------
__global__ void k_fe1(const float* __restrict__ x, const float* __restrict__ w,
                      const float* __restrict__ b, float* __restrict__ h, int N) {
    int idx = blockIdx.x * 256 + threadIdx.x;
    if (idx >= N * 64) return;
    int n = idx >> 6, c = idx & 63;
    const float* xr = x + (size_t)n * 28;
    float acc = b[c];
    #pragma unroll
    for (int k = 0; k < 28; k++) acc = fmaf(xr[k], w[k * 64 + c], acc);
    h[idx] = acc;
}

__global__ void k_bnstat(const float* __restrict__ h, float* __restrict__ stats, int N) {
    __shared__ float s_s[256], s_q[256];
    int tid = threadIdx.x;
    int c = tid & 63, g = tid >> 6;
    float s = 0.f, q = 0.f;
    for (int n = blockIdx.x * 4 + g; n < N; n += gridDim.x * 4) {
        float v = h[(size_t)n * 64 + c];
        s += v; q += v * v;
    }
    s_s[tid] = s; s_q[tid] = q;
    __syncthreads();
    if (tid < 64) {
        s = s_s[tid] + s_s[tid + 64] + s_s[tid + 128] + s_s[tid + 192];
        q = s_q[tid] + s_q[tid + 64] + s_q[tid + 128] + s_q[tid + 192];
        atomicAdd(&stats[tid], s);
        atomicAdd(&stats[64 + tid], q);
    }
}

__global__ void k_bnfin(const float* __restrict__ stats, float* __restrict__ prm,
                        const float* __restrict__ gamma, const float* __restrict__ beta,
                        float invN) {
    int c = threadIdx.x;  // 64 threads
    float mu = stats[c] * invN;
    float var = stats[64 + c] * invN - mu * mu;
    float sc = gamma[c] * rsqrtf(var + 1e-5f);
    prm[c] = sc;
    prm[64 + c] = beta[c] - mu * sc;
}

// ---------------- MFMA fe2: v16 = relu( relu(bn(h)) @ fe_w2 + b2 ), K=64 ----------------
__launch_bounds__(256, 4)
__global__ void k_fe2(const float* __restrict__ h, const float* __restrict__ prm,
                      const ushort* __restrict__ w2T, const float* __restrict__ b2,
                      ushort* __restrict__ v16, int N) {
    constexpr int LDP = 72;
    __shared__ _Float16 sH[64 * LDP];
    const int tid = threadIdx.x;
    const int n0 = blockIdx.x * 64;

    for (int i = tid; i < 64 * 16; i += 256) {
        int row = i >> 4, c4 = (i & 15) << 2;
        int gr = n0 + row;
        float4 hv = (gr < N) ? *(const float4*)&h[((size_t)gr << 6) + c4]
                             : make_float4(0.f, 0.f, 0.f, 0.f);
        float4 sc = *(const float4*)&prm[c4];
        float4 sh = *(const float4*)&prm[64 + c4];
        f16x4 o;
        o[0] = (_Float16)fmaxf(fmaf(hv.x, sc.x, sh.x), 0.f);
        o[1] = (_Float16)fmaxf(fmaf(hv.y, sc.y, sh.y), 0.f);
        o[2] = (_Float16)fmaxf(fmaf(hv.z, sc.z, sh.z), 0.f);
        o[3] = (_Float16)fmaxf(fmaf(hv.w, sc.w, sh.w), 0.f);
        *(f16x4*)&sH[row * LDP + c4] = o;
    }
    __syncthreads();

    const int wid = tid >> 6, lane = tid & 63;
    const int lr = lane & 15, lg = lane >> 4;
    const int kof = lg << 3;
    const int arow = wid * 16 + lr;
    const int drow0 = wid * 16 + (lg << 2);

    f16x8 a0 = *(const f16x8*)&sH[arow * LDP + kof];
    f16x8 a1 = *(const f16x8*)&sH[arow * LDP + 32 + kof];

    #pragma unroll
    for (int n = 0; n < 8; n++) {
        const ushort* bp = w2T + (((size_t)(n << 4) + lr) << 6);
        f32x4 c = {0.f, 0.f, 0.f, 0.f};
        c = MFMA16(a0, *(const f16x8*)(bp + kof), c);
        c = MFMA16(a1, *(const f16x8*)(bp + 32 + kof), c);
        int col = (n << 4) + lr;
        float bb = b2[col];
        #pragma unroll
        for (int r = 0; r < 4; r++) {
            int gr = n0 + drow0 + r;
            if (gr < N) v16[((size_t)gr << 7) + col] =
                __builtin_bit_cast(ushort, (_Float16)fmaxf(c[r] + bb, 0.f));
        }
    }
}

// ---------------- MFMA single GEMM: vlin(fp16) = v16 @ lin, K=128 ----------------
__launch_bounds__(256, 4)
__global__ void k_gemm_rb(const ushort* __restrict__ A, const ushort* __restrict__ wT,
                          ushort* __restrict__ C, int N) {
    constexpr int LDP = 136;
    __shared__ _Float16 sA[64 * LDP];
    const int tid = threadIdx.x;
    const int n0 = blockIdx.x * 64;

    for (int i = tid; i < 64 * 32; i += 256) {
        int row = i >> 5, c4 = (i & 31) << 2;
        int gr = n0 + row;
        uint2 val = (gr < N) ? *(const uint2*)&A[((size_t)gr << 7) + c4]
                             : make_uint2(0u, 0u);
        *(uint2*)&sA[row * LDP + c4] = val;
    }
    __syncthreads();

    const int wid = tid >> 6, lane = tid & 63;
    const int lr = lane & 15, lg = lane >> 4;
    const int kof = lg << 3;
    const int arow = wid * 16 + lr;
    const int drow0 = wid * 16 + (lg << 2);

    f16x8 a0 = *(const f16x8*)&sA[arow * LDP + kof];
    f16x8 a1 = *(const f16x8*)&sA[arow * LDP + 32 + kof];
    f16x8 a2 = *(const f16x8*)&sA[arow * LDP + 64 + kof];
    f16x8 a3 = *(const f16x8*)&sA[arow * LDP + 96 + kof];

    #pragma unroll
    for (int n = 0; n < 8; n++) {
        const ushort* bp = wT + (((size_t)(n << 4) + lr) << 7);
        f32x4 c = {0.f, 0.f, 0.f, 0.f};
        c = MFMA16(a0, *(const f16x8*)(bp + kof), c);
        c = MFMA16(a1, *(const f16x8*)(bp + 32 + kof), c);
        c = MFMA16(a2, *(const f16x8*)(bp + 64 + kof), c);
        c = MFMA16(a3, *(const f16x8*)(bp + 96 + kof), c);
        int col = (n << 4) + lr;
        #pragma unroll
        for (int r = 0; r < 4; r++) {
            int gr = n0 + drow0 + r;
            if (gr < N) C[((size_t)gr << 7) + col] =
                __builtin_bit_cast(ushort, (_Float16)c[r]);
        }
    }
}

// ---------------- MFMA fused layer update: coalesced LDS-roundtrip epilogues ----------------
// sA: agg -> t -> vlin-out staging; sB: v_old -> v_new. All global IO 8B/lane.
__launch_bounds__(512, 8)
__global__ void k_update(const ushort* __restrict__ agg,
                         const ushort* __restrict__ w1T, const float* __restrict__ b1,
                         const ushort* __restrict__ w2T, const float* __restrict__ b2,
                         ushort* __restrict__ v16,
                         const ushort* __restrict__ linT, ushort* __restrict__ vlin, int N) {
    constexpr int LDP = 136;
    __shared__ _Float16 sA[64 * LDP];   // 17.4 KB
    __shared__ _Float16 sB[64 * LDP];   // 17.4 KB
    const int tid = threadIdx.x;
    const int n0 = blockIdx.x * 64;

    // coalesced stage: agg -> sA, v_old -> sB
    for (int i = tid; i < 64 * 32; i += 512) {
        int row = i >> 5, c4 = (i & 31) << 2;
        int gr = n0 + row;
        uint2 a = (gr < N) ? *(const uint2*)&agg[((size_t)gr << 7) + c4] : make_uint2(0u, 0u);
        uint2 b = (gr < N) ? *(const uint2*)&v16[((size_t)gr << 7) + c4] : make_uint2(0u, 0u);
        *(uint2*)&sA[row * LDP + c4] = a;
        *(uint2*)&sB[row * LDP + c4] = b;
    }
    __syncthreads();

    const int wid = tid >> 6, lane = tid & 63;
    const int wr = wid & 3, wc = wid >> 2;
    const int lr = lane & 15, lg = lane >> 4;
    const int kof = lg << 3;
    const int arow = wr * 16 + lr;
    const int drow0 = wr * 16 + (lg << 2);
    const int cbase = wc << 6;   // 0 or 64

    f16x8 a0, a1, a2, a3;
    f32x4 acc[4];

    // ---- GEMM 1: t = ssp(agg @ W1 + b1) ----
    a0 = *(const f16x8*)&sA[arow * LDP + kof];
    a1 = *(const f16x8*)&sA[arow * LDP + 32 + kof];
    a2 = *(const f16x8*)&sA[arow * LDP + 64 + kof];
    a3 = *(const f16x8*)&sA[arow * LDP + 96 + kof];
    #pragma unroll
    for (int n = 0; n < 4; n++) {
        const ushort* bp = w1T + (((size_t)(cbase + (n << 4)) + lr) << 7);
        f32x4 c = {0.f, 0.f, 0.f, 0.f};
        c = MFMA16(a0, *(const f16x8*)(bp + kof), c);
        c = MFMA16(a1, *(const f16x8*)(bp + 32 + kof), c);
        c = MFMA16(a2, *(const f16x8*)(bp + 64 + kof), c);
        c = MFMA16(a3, *(const f16x8*)(bp + 96 + kof), c);
        acc[n] = c;
    }
    __syncthreads();   // done reading agg tile
    #pragma unroll
    for (int n = 0; n < 4; n++) {
        int col = cbase + (n << 4) + lr;
        float bb = b1[col];
        #pragma unroll
        for (int r = 0; r < 4; r++)
            sA[(drow0 + r) * LDP + col] = (_Float16)sspf(acc[n][r] + bb);
    }
    __syncthreads();

    // ---- GEMM 2: v_new = t @ W2 + b2 + v_old (residual from sB, in-place) ----
    a0 = *(const f16x8*)&sA[arow * LDP + kof];
    a1 = *(const f16x8*)&sA[arow * LDP + 32 + kof];
    a2 = *(const f16x8*)&sA[arow * LDP + 64 + kof];
    a3 = *(const f16x8*)&sA[arow * LDP + 96 + kof];
    #pragma unroll
    for (int n = 0; n < 4; n++) {
        const ushort* bp = w2T + (((size_t)(cbase + (n << 4)) + lr) << 7);
        f32x4 c = {0.f, 0.f, 0.f, 0.f};
        c = MFMA16(a0, *(const f16x8*)(bp + kof), c);
        c = MFMA16(a1, *(const f16x8*)(bp + 32 + kof), c);
        c = MFMA16(a2, *(const f16x8*)(bp + 64 + kof), c);
        c = MFMA16(a3, *(const f16x8*)(bp + 96 + kof), c);
        acc[n] = c;
    }
    #pragma unroll
    for (int n = 0; n < 4; n++) {
        int col = cbase + (n << 4) + lr;
        float bb = b2[col];
        #pragma unroll
        for (int r = 0; r < 4; r++) {
            _Float16* p = &sB[(drow0 + r) * LDP + col];
            *p = (_Float16)(acc[n][r] + bb + (float)*p);   // lane owns this slot
        }
    }
    __syncthreads();

    // coalesced store: sB -> v16
    for (int i = tid; i < 64 * 32; i += 512) {
        int row = i >> 5, c4 = (i & 31) << 2;
        int gr = n0 + row;
        if (gr < N) *(uint2*)&v16[((size_t)gr << 7) + c4] = *(const uint2*)&sB[row * LDP + c4];
    }
    if (!linT) return;

    // ---- GEMM 3: vlin = v_new @ lin (A from sB, park output in sA) ----
    a0 = *(const f16x8*)&sB[arow * LDP + kof];
    a1 = *(const f16x8*)&sB[arow * LDP + 32 + kof];
    a2 = *(const f16x8*)&sB[arow * LDP + 64 + kof];
    a3 = *(const f16x8*)&sB[arow * LDP + 96 + kof];
    #pragma unroll
    for (int n = 0; n < 4; n++) {
        const ushort* bp = linT + (((size_t)(cbase + (n << 4)) + lr) << 7);
        f32x4 c = {0.f, 0.f, 0.f, 0.f};
        c = MFMA16(a0, *(const f16x8*)(bp + kof), c);
        c = MFMA16(a1, *(const f16x8*)(bp + 32 + kof), c);
        c = MFMA16(a2, *(const f16x8*)(bp + 64 + kof), c);
        c = MFMA16(a3, *(const f16x8*)(bp + 96 + kof), c);
        acc[n] = c;
    }
    // sA's t-tile reads finished before the previous barrier -> safe to overwrite
    #pragma unroll
    for (int n = 0; n < 4; n++) {
        int col = cbase + (n << 4) + lr;
        #pragma unroll
        for (int r = 0; r < 4; r++)
            sA[(drow0 + r) * LDP + col] = (_Float16)acc[n][r];
    }
    __syncthreads();

    // coalesced store: sA -> vlin
    for (int i = tid; i < 64 * 32; i += 512) {
        int row = i >> 5, c4 = (i & 31) << 2;
        int gr = n0 + row;
        if (gr < N) *(uint2*)&vlin[((size_t)gr << 7) + c4] = *(const uint2*)&sA[row * LDP + c4];
    }
}

// ---------------- tiled fused readout (v16 input) ----------------
__launch_bounds__(256, 4)
__global__ void k_uout(const ushort* __restrict__ v16, const float* __restrict__ u1w,
                       const float* __restrict__ u1b, const float* __restrict__ u2w,
                       const float* __restrict__ u2b, const int* __restrict__ batch,
                       float* __restrict__ out, int N) {
    __shared__ float sA[64 * 128];
    const int tid = threadIdx.x;
    const int n0 = blockIdx.x * 64;

    for (int i = tid; i < 64 * 32; i += 256) {
        int row = i >> 5, cq = (i & 31) << 2;
        int gr = n0 + row;
        float4 val = make_float4(0.f, 0.f, 0.f, 0.f);
        if (gr < N) val = ld_h4(&v16[((size_t)gr << 7) + cq]);
        *(float4*)&sA[row * 128 + cq] = val;
    }
    __syncthreads();

    const int cg = tid & 31, rg = tid >> 5;
    const int r0 = rg << 3;
    const int c2 = cg << 1;

    float2 acc[8];
    {
        float2 b1v = *(const float2*)&u1b[c2];
        #pragma unroll
        for (int i = 0; i < 8; i++) acc[i] = b1v;
        #pragma unroll 4
        for (int k = 0; k < 128; k++) {
            float2 wv = *(const float2*)&u1w[(k << 6) + c2];
            #pragma unroll
            for (int i = 0; i < 8; i++) {
                float a = sA[(r0 + i) * 128 + k];
                acc[i].x = fmaf(a, wv.x, acc[i].x);
                acc[i].y = fmaf(a, wv.y, acc[i].y);
            }
        }
    }
    __syncthreads();
    #pragma unroll
    for (int i = 0; i < 8; i++) {
        sA[(r0 + i) * 64 + c2 + 0] = sspf(acc[i].x);
        sA[(r0 + i) * 64 + c2 + 1] = sspf(acc[i].y);
    }
    __syncthreads();

    float acc2[8];
    {
        float bb = u2b[cg];
        #pragma unroll
        for (int i = 0; i < 8; i++) acc2[i] = bb;
        #pragma unroll 4
        for (int k = 0; k < 64; k++) {
            float wv = u2w[(k << 5) + cg];
            #pragma unroll
            for (int i = 0; i < 8; i++)
                acc2[i] = fmaf(sA[(r0 + i) * 64 + k], wv, acc2[i]);
        }
    }

    int cur = -1;
    float run = 0.f;
    #pragma unroll
    for (int i = 0; i < 8; i++) {
        int gr = n0 + r0 + i;
        int g = (gr < N) ? batch[gr] : -1;
        if (g != cur) {
            if (cur >= 0) atomicAdd(&out[(size_t)cur * 32 + cg], run);
            cur = g;
            run = 0.f;
        }
        if (g >= 0) run += acc2[i];
    }
    if (cur >= 0) atomicAdd(&out[(size_t)cur * 32 + cg], run);
}

extern "C" void kernel_launch(void* const* d_in, const int* in_sizes, int n_in,
                              void* d_out, int out_size, void* d_ws, size_t ws_size,
                              hipStream_t stream) {
    const float* x      = (const float*)d_in[0];
    const float* pos    = (const float*)d_in[1];
    const int*   batch  = (const int*)d_in[2];
    const int*   ei     = (const int*)d_in[3];
    const float* fe_w1  = (const float*)d_in[4];
    const float* fe_b1  = (const float*)d_in[5];
    const float* bn_g   = (const float*)d_in[6];
    const float* bn_b   = (const float*)d_in[7];
    const float* fe_w2  = (const float*)d_in[8];
    const float* fe_b2  = (const float*)d_in[9];
    const float* lin_w  = (const float*)d_in[10];
    const float* mlp_w1 = (const float*)d_in[11];
    const float* mlp_b1 = (const float*)d_in[12];
    const float* mlp_w2 = (const float*)d_in[13];
    const float* mlp_b2 = (const float*)d_in[14];
    const float* v1_w   = (const float*)d_in[15];
    const float* v1_b   = (const float*)d_in[16];
    const float* v2_w   = (const float*)d_in[17];
    const float* v2_b   = (const float*)d_in[18];
    const float* u1_w   = (const float*)d_in[19];
    const float* u1_b   = (const float*)d_in[20];
    const float* u2_w   = (const float*)d_in[21];
    const float* u2_b   = (const float*)d_in[22];

    const int N = in_sizes[0] / 28;
    const int E = in_sizes[3] / 2;
    const int NB1 = (N + 1023) / 1024;

    char* ws = (char*)d_ws;
    size_t o = 0;
    auto alloc = [&](size_t bytes) { void* p = ws + o; o += (bytes + 255) & ~(size_t)255; return p; };
    int*    counts = (int*)   alloc((size_t)N * 4);
    int*    cursor = (int*)   alloc((size_t)N * 4);
    int*    rowptr = (int*)   alloc((size_t)N * 4);
    int*    bsum   = (int*)   alloc((size_t)NB1 * 4);
    uint2*  s_ef   = (uint2*) alloc((size_t)E * 8);
    float*  stats  = (float*) alloc(128 * 4);
    float*  prm    = (float*) alloc(128 * 4);
    ushort* tab    = (ushort*)alloc((size_t)LAY * K_TAB * 128 * 2);  // 12 MB fp16
    ushort* tab2   = (ushort*)alloc((size_t)LAY * K_TAB * 256 * 2);  // 24 MB paired
    ushort* v16    = (ushort*)alloc((size_t)N * 128 * 2);            // fp16 node state
    ushort* vlin   = (ushort*)alloc((size_t)N * 128 * 2);            // fp16
    ushort* agg    = (ushort*)alloc((size_t)N * 128 * 2);            // fp16
    float*  h      = (float*) alloc((size_t)N * 64 * 4);
    int*    locex  = (int*)   alloc((size_t)N * 4);
    ushort* v1T    = (ushort*)alloc((size_t)LAY * 16384 * 2);   // fp16 transposed weights
    ushort* v2T    = (ushort*)alloc((size_t)LAY * 16384 * 2);
    ushort* linT   = (ushort*)alloc((size_t)LAY * 16384 * 2);
    ushort* fe2T   = (ushort*)alloc((size_t)8192 * 2);

    // -------- weight conversion (fp16, transposed) --------
    k_cvtT128<<<LAY, 256, 0, stream>>>(v1_w, v1T);
    k_cvtT128<<<LAY, 256, 0, stream>>>(v2_w, v2T);
    k_cvtT128<<<LAY, 256, 0, stream>>>(lin_w, linT);
    k_cvtT_fe<<<1, 256, 0, stream>>>(fe_w2, fe2T);

    // -------- one-time edge sort (dst-ordered CSR) --------
    hipMemsetAsync(counts, 0, (size_t)N * 4, stream);
    k_hist<<<(E + 255) / 256, 256, 0, stream>>>(ei, counts, E);
    k_scan1<<<NB1, 1024, 0, stream>>>(counts, locex, bsum, N);
    k_scan2<<<1, 1024, 0, stream>>>(bsum, NB1);
    k_scan3<<<(N + 255) / 256, 256, 0, stream>>>(locex, bsum, cursor, rowptr, N);
    k_scatter<<<(E + 255) / 256, 256, 0, stream>>>(ei, pos, cursor, s_ef, E);

    // -------- gate tables (fp16), then pair-interleave --------
    k_tab_all<<<LAY * 256, 256, 0, stream>>>(mlp_w1, mlp_b1, mlp_w2, mlp_b2, tab);
    k_pair<<<LAY * K_TAB * 32 / 256, 256, 0, stream>>>(tab, tab2);

    // -------- feature embedding --------
    hipMemsetAsync(stats, 0, 128 * 4, stream);
    k_fe1<<<(N * 64 + 255) / 256, 256, 0, stream>>>(x, fe_w1, fe_b1, h, N);
    k_bnstat<<<256, 256, 0, stream>>>(h, stats, N);
    k_bnfin<<<1, 64, 0, stream>>>(stats, prm, bn_g, bn_b, 1.0f / (float)N);
    const int gblk = (N + 63) / 64;
    k_fe2<<<gblk, 256, 0, stream>>>(h, prm, fe2T, fe_b2, v16, N);

    // vlin for layer 0
    k_gemm_rb<<<gblk, 256, 0, stream>>>(v16, linT, vlin, N);

    // -------- interaction layers --------
    const int eblk = (N + 7) / 8;
    for (int l = 0; l < LAY; l++) {
        k_edge_csr<<<eblk, 256, 0, stream>>>(
            s_ef, rowptr, counts, vlin,
            tab2 + (size_t)l * K_TAB * 256, agg, N);
        const ushort* lin_next = (l + 1 < LAY) ? linT + (size_t)(l + 1) * 16384 : nullptr;
        k_update<<<gblk, 512, 0, stream>>>(
            agg, v1T + (size_t)l * 16384, v1_b + (size_t)l * 128,
            v2T + (size_t)l * 16384, v2_b + (size_t)l * 128,
            v16, lin_next, vlin, N);
    }

    // -------- fused readout --------
    hipMemsetAsync(d_out, 0, (size_t)out_size * 4, stream);
    k_uout<<<gblk, 256, 0, stream>>>(v16, u1_w, u1_b, u2_w, u2_b, batch, (float*)d_out, N);
}

// Round 16
// 721.744 us; speedup vs baseline: 1.3449x; 1.2348x over previous
//
#include <hip/hip_runtime.h>
#include <hip/hip_fp16.h>
#include <math.h>

#define DEV __device__ __forceinline__

constexpr int NGAUSS = 50;
constexpr int LAY = 6;
constexpr int K_TAB = 8192;
constexpr float DMAX = 40.0f;
constexpr float TSCALE = (float)(K_TAB - 1) / DMAX;   // fid = d * TSCALE
constexpr float STEP = 6.0f / 49.0f;
constexpr float COEFF = -0.5f / (STEP * STEP);
constexpr float LN2F = 0.69314718055994531f;
constexpr float PI_OVER_CUT = 0.52359877559829887f;  // pi/6

using f16x8 = __attribute__((ext_vector_type(8))) _Float16;
using f16x4 = __attribute__((ext_vector_type(4))) _Float16;
using f32x4 = __attribute__((ext_vector_type(4))) float;

#define MFMA16(a, b, c) __builtin_amdgcn_mfma_f32_16x16x32_f16(a, b, c, 0, 0, 0)

DEV float sspf(float x) {
    float ax = fabsf(x);
    float e = __expf(-ax);
    return fmaxf(x, 0.f) + __logf(1.f + e) - LN2F;
}

// ---- fp16 pack/unpack helpers (storage fp16, math f32) ----
DEV float4 ld_h4(const ushort* p) {          // 8B load -> 4 floats
    uint2 r = *(const uint2*)p;
    __half2 a = __builtin_bit_cast(__half2, r.x);
    __half2 b = __builtin_bit_cast(__half2, r.y);
    float2 fa = __half22float2(a), fb = __half22float2(b);
    return make_float4(fa.x, fa.y, fb.x, fb.y);
}
DEV void st_h4(ushort* p, float4 v) {        // 4 floats -> 8B store
    uint2 r;
    r.x = __builtin_bit_cast(uint, __float22half2_rn(make_float2(v.x, v.y)));
    r.y = __builtin_bit_cast(uint, __float22half2_rn(make_float2(v.z, v.w)));
    *(uint2*)p = r;
}

// ---------------- weight convert+transpose (fp32 [K][C] -> fp16 [C][K]) ----------------
__global__ void k_cvtT128(const float* __restrict__ src, ushort* __restrict__ dst) {
    const float* s = src + (size_t)blockIdx.x * 16384;
    ushort* d = dst + (size_t)blockIdx.x * 16384;
    for (int i = threadIdx.x; i < 16384; i += 256) {
        int k = i >> 7, c = i & 127;
        d[(c << 7) + k] = __builtin_bit_cast(ushort, (_Float16)s[i]);
    }
}
__global__ void k_cvtT_fe(const float* __restrict__ src, ushort* __restrict__ dst) {
    // fe_w2: [64][128] -> dst[c(128)][k(64)]
    for (int i = threadIdx.x; i < 8192; i += 256) {
        int k = i >> 7, c = i & 127;
        dst[(c << 6) + k] = __builtin_bit_cast(ushort, (_Float16)src[i]);
    }
}

// ---------------- edge sort pre-pass (once per call) ----------------
__global__ void k_hist(const int* __restrict__ ei, int* __restrict__ counts, int E) {
    int e = blockIdx.x * 256 + threadIdx.x;
    if (e < E) atomicAdd(&counts[ei[E + e]], 1);
}

__global__ void k_scan1(const int* __restrict__ counts, int* __restrict__ locex,
                        int* __restrict__ bsum, int n) {
    __shared__ int s_wsum[16];
    const int tid = threadIdx.x;
    const int i = blockIdx.x * 1024 + tid;
    const int lane = tid & 63, wv = tid >> 6;
    int v = (i < n) ? counts[i] : 0;
    int x = v;
    #pragma unroll
    for (int off = 1; off < 64; off <<= 1) {
        int y = __shfl_up(x, off, 64);
        if (lane >= off) x += y;
    }
    if (lane == 63) s_wsum[wv] = x;
    __syncthreads();
    if (wv == 0 && lane < 16) {
        int wval = s_wsum[lane];
        int wx = wval;
        #pragma unroll
        for (int off = 1; off < 16; off <<= 1) {
            int wy = __shfl_up(wx, off, 16);
            if (lane >= off) wx += wy;
        }
        s_wsum[lane] = wx - wval;
    }
    __syncthreads();
    if (i < n) locex[i] = s_wsum[wv] + x - v;
    if (tid == 1023) bsum[blockIdx.x] = s_wsum[15] + x;
}

__global__ void k_scan2(int* __restrict__ bsum, int nb) {
    __shared__ int s_wsum[16];
    const int tid = threadIdx.x;
    const int lane = tid & 63, wv = tid >> 6;
    int v = (tid < nb) ? bsum[tid] : 0;
    int x = v;
    #pragma unroll
    for (int off = 1; off < 64; off <<= 1) {
        int y = __shfl_up(x, off, 64);
        if (lane >= off) x += y;
    }
    if (lane == 63) s_wsum[wv] = x;
    __syncthreads();
    if (wv == 0 && lane < 16) {
        int wval = s_wsum[lane];
        int wx = wval;
        #pragma unroll
        for (int off = 1; off < 16; off <<= 1) {
            int wy = __shfl_up(wx, off, 16);
            if (lane >= off) wx += wy;
        }
        s_wsum[lane] = wx - wval;
    }
    __syncthreads();
    if (tid < nb) bsum[tid] = s_wsum[wv] + x - v;
}

__global__ void k_scan3(const int* __restrict__ locex, const int* __restrict__ bsumex,
                        int* __restrict__ cursor, int* __restrict__ rowptr, int n) {
    int i = blockIdx.x * 256 + threadIdx.x;
    if (i >= n) return;
    int e = locex[i] + bsumex[i >> 10];
    cursor[i] = e;
    rowptr[i] = e;
}

// scatter: one 8B store per edge {src, fid}
__global__ void k_scatter(const int* __restrict__ ei, const float* __restrict__ pos,
                          int* __restrict__ cursor, uint2* __restrict__ s_ef, int E) {
    int e = blockIdx.x * 256 + threadIdx.x;
    if (e >= E) return;
    int r = ei[e], c = ei[E + e];
    int p = atomicAdd(&cursor[c], 1);
    float dx = pos[3 * r + 0] - pos[3 * c + 0];
    float dy = pos[3 * r + 1] - pos[3 * c + 1];
    float dz = pos[3 * r + 2] - pos[3 * c + 2];
    float d = sqrtf(dx * dx + dy * dy + dz * dz);
    float fid = fminf(d * TSCALE, (float)(K_TAB - 2) + 0.999f);
    s_ef[p] = make_uint2((uint)r, __builtin_bit_cast(uint, fid));
}

// ---------------- gate table build (fp16 output), ALL layers in one launch ----------------
__launch_bounds__(256)
__global__ void k_tab_all(const float* __restrict__ w1A, const float* __restrict__ b1A,
                          const float* __restrict__ w2A, const float* __restrict__ b2A,
                          ushort* __restrict__ tabA) {
    const int layer = blockIdx.x >> 8;
    const int k0 = (blockIdx.x & 255) * 32;
    const float* w1 = w1A + (size_t)layer * NGAUSS * 128;
    const float* b1 = b1A + (size_t)layer * 128;
    const float* w2 = w2A + (size_t)layer * 128 * 128;
    const float* b2 = b2A + (size_t)layer * 128;
    ushort* tab = tabA + (size_t)layer * K_TAB * 128;

    __shared__ float s_demb[32][NGAUSS];
    __shared__ float s_t1[32][128];
    const int tid = threadIdx.x;

    for (int i = tid; i < 32 * NGAUSS; i += 256) {
        int r = i / NGAUSS, g = i - r * NGAUSS;
        float d = (float)(k0 + r) * (1.0f / TSCALE);
        float t = d - g * STEP;
        s_demb[r][g] = __expf(COEFF * t * t);
    }
    __syncthreads();

    const int cg = tid & 31, rg = tid >> 5;
    const int r0 = rg << 2;
    const int c4 = cg << 2;

    float4 b1v = *(const float4*)&b1[c4];
    float4 acc[4];
    #pragma unroll
    for (int i = 0; i < 4; i++) acc[i] = b1v;
    #pragma unroll 2
    for (int k = 0; k < NGAUSS; k++) {
        float4 wv = *(const float4*)&w1[(k << 7) + c4];
        #pragma unroll
        for (int i = 0; i < 4; i++) {
            float dv = s_demb[r0 + i][k];
            acc[i].x = fmaf(dv, wv.x, acc[i].x);
            acc[i].y = fmaf(dv, wv.y, acc[i].y);
            acc[i].z = fmaf(dv, wv.z, acc[i].z);
            acc[i].w = fmaf(dv, wv.w, acc[i].w);
        }
    }
    #pragma unroll
    for (int i = 0; i < 4; i++) {
        float4 t;
        t.x = sspf(acc[i].x); t.y = sspf(acc[i].y);
        t.z = sspf(acc[i].z); t.w = sspf(acc[i].w);
        *(float4*)&s_t1[r0 + i][c4] = t;
    }
    __syncthreads();

    float4 b2v = *(const float4*)&b2[c4];
    float4 a2[4];
    #pragma unroll
    for (int i = 0; i < 4; i++) a2[i] = b2v;
    #pragma unroll 4
    for (int k = 0; k < 128; k++) {
        float4 wv = *(const float4*)&w2[(k << 7) + c4];
        #pragma unroll
        for (int i = 0; i < 4; i++) {
            float tv = s_t1[r0 + i][k];
            a2[i].x = fmaf(tv, wv.x, a2[i].x);
            a2[i].y = fmaf(tv, wv.y, a2[i].y);
            a2[i].z = fmaf(tv, wv.z, a2[i].z);
            a2[i].w = fmaf(tv, wv.w, a2[i].w);
        }
    }
    #pragma unroll
    for (int i = 0; i < 4; i++) {
        int knot = k0 + r0 + i;
        float d = (float)knot * (1.0f / TSCALE);
        float cc = 0.5f * (__cosf(d * PI_OVER_CUT) + 1.0f);
        float4 o;
        o.x = a2[i].x * cc; o.y = a2[i].y * cc;
        o.z = a2[i].z * cc; o.w = a2[i].w * cc;
        st_h4(&tab[((size_t)knot << 7) + c4], o);
    }
}

// ---------------- pair-interleave: tab2[i][2c..2c+1] = {T[i][c], T[i+1][c]} ----------------
__global__ void k_pair(const ushort* __restrict__ tab, ushort* __restrict__ tab2) {
    size_t idx = (size_t)blockIdx.x * 256 + threadIdx.x;   // LAY*K_TAB*32 total
    int cg = idx & 31;
    size_t knotg = idx >> 5;           // layer*K_TAB + knot
    int knot = (int)(knotg & (K_TAB - 1));
    const ushort* r0 = tab + (knotg << 7) + (cg << 2);
    const ushort* r1 = (knot < K_TAB - 1) ? r0 + 128 : r0;   // clamp at end
    uint2 a = *(const uint2*)r0;
    uint2 b = *(const uint2*)r1;
    ushort4 al = *(const ushort4*)&a;
    ushort4 bl = *(const ushort4*)&b;
    ushort out[8] = {al.x, bl.x, al.y, bl.y, al.z, bl.z, al.w, bl.w};
    *(uint4*)&tab2[(knotg << 8) + (cg << 3)] = *(const uint4*)out;
}

// ---------------- node-centric CSR edge kernel: 3 loads/edge ----------------
__launch_bounds__(256, 8)
__global__ void k_edge_csr(const uint2* __restrict__ s_ef,
                           const int* __restrict__ rowptr, const int* __restrict__ counts,
                           const ushort* __restrict__ vlin, const ushort* __restrict__ tab2,
                           ushort* __restrict__ agg, int N) {
    const int tid = threadIdx.x;
    const int cg = tid & 31;
    const int n = blockIdx.x * 8 + (tid >> 5);
    if (n >= N) return;
    const ushort* tabc = tab2 + (cg << 3);   // lane's 16B slot within 512B row
    const ushort* vlc = vlin + (cg << 2);

    const int rs = rowptr[n];
    const int re = rs + counts[n];
    float4 run = make_float4(0.f, 0.f, 0.f, 0.f);
    int e = rs;
    for (; e + 8 <= re; e += 8) {
        f16x8 TP[8];
        f16x4 VL[8];
        _Float16 FR[8];
        #pragma unroll
        for (int j = 0; j < 8; j++) {
            uint2 ef = s_ef[e + j];
            float fid = __builtin_bit_cast(float, ef.y);
            int i0 = (int)fid;
            FR[j] = (_Float16)(fid - (float)i0);
            TP[j] = *(const f16x8*)(tabc + ((size_t)i0 << 8));
            VL[j] = *(const f16x4*)(vlc + ((size_t)ef.x << 7));
        }
        f16x4 p0 = {0, 0, 0, 0}, p1 = {0, 0, 0, 0};
        #pragma unroll
        for (int j = 0; j < 8; j += 2) {
            f16x4 t0a = {TP[j][0], TP[j][2], TP[j][4], TP[j][6]};
            f16x4 t1a = {TP[j][1], TP[j][3], TP[j][5], TP[j][7]};
            f16x4 t0b = {TP[j+1][0], TP[j+1][2], TP[j+1][4], TP[j+1][6]};
            f16x4 t1b = {TP[j+1][1], TP[j+1][3], TP[j+1][5], TP[j+1][7]};
            f16x4 w0 = t0a + FR[j]     * (t1a - t0a);
            f16x4 w1 = t0b + FR[j + 1] * (t1b - t0b);
            p0 += w0 * VL[j];
            p1 += w1 * VL[j + 1];
        }
        run.x += (float)p0[0] + (float)p1[0];
        run.y += (float)p0[1] + (float)p1[1];
        run.z += (float)p0[2] + (float)p1[2];
        run.w += (float)p0[3] + (float)p1[3];
    }
    for (; e < re; e++) {
        uint2 ef = s_ef[e];
        float fid = __builtin_bit_cast(float, ef.y);
        int i0 = (int)fid;
        _Float16 fr = (_Float16)(fid - (float)i0);
        f16x8 tp = *(const f16x8*)(tabc + ((size_t)i0 << 8));
        f16x4 vl = *(const f16x4*)(vlc + ((size_t)ef.x << 7));
        f16x4 t0 = {tp[0], tp[2], tp[4], tp[6]};
        f16x4 t1 = {tp[1], tp[3], tp[5], tp[7]};
        f16x4 w = t0 + fr * (t1 - t0);
        f16x4 p = w * vl;
        run.x += (float)p[0];
        run.y += (float)p[1];
        run.z += (float)p[2];
        run.w += (float)p[3];
    }
    st_h4(&agg[((size_t)n << 7) + (cg << 2)], run);
}

// ---------------- feature embedding ----------------
__global__ void k_fe1(const float* __restrict__ x, const float* __restrict__ w,
                      const float* __restrict__ b, float* __restrict__ h, int N) {
    int idx = blockIdx.x * 256 + threadIdx.x;
    if (idx >= N * 64) return;
    int n = idx >> 6, c = idx & 63;
    const float* xr = x + (size_t)n * 28;
    float acc = b[c];
    #pragma unroll
    for (int k = 0; k < 28; k++) acc = fmaf(xr[k], w[k * 64 + c], acc);
    h[idx] = acc;
}

__global__ void k_bnstat(const float* __restrict__ h, float* __restrict__ stats, int N) {
    __shared__ float s_s[256], s_q[256];
    int tid = threadIdx.x;
    int c = tid & 63, g = tid >> 6;
    float s = 0.f, q = 0.f;
    for (int n = blockIdx.x * 4 + g; n < N; n += gridDim.x * 4) {
        float v = h[(size_t)n * 64 + c];
        s += v; q += v * v;
    }
    s_s[tid] = s; s_q[tid] = q;
    __syncthreads();
    if (tid < 64) {
        s = s_s[tid] + s_s[tid + 64] + s_s[tid + 128] + s_s[tid + 192];
        q = s_q[tid] + s_q[tid + 64] + s_q[tid + 128] + s_q[tid + 192];
        atomicAdd(&stats[tid], s);
        atomicAdd(&stats[64 + tid], q);
    }
}

__global__ void k_bnfin(const float* __restrict__ stats, float* __restrict__ prm,
                        const float* __restrict__ gamma, const float* __restrict__ beta,
                        float invN) {
    int c = threadIdx.x;  // 64 threads
    float mu = stats[c] * invN;
    float var = stats[64 + c] * invN - mu * mu;
    float sc = gamma[c] * rsqrtf(var + 1e-5f);
    prm[c] = sc;
    prm[64 + c] = beta[c] - mu * sc;
}

// ---------------- MFMA fe2: v16 = relu( relu(bn(h)) @ fe_w2 + b2 ), K=64 ----------------
__launch_bounds__(256, 4)
__global__ void k_fe2(const float* __restrict__ h, const float* __restrict__ prm,
                      const ushort* __restrict__ w2T, const float* __restrict__ b2,
                      ushort* __restrict__ v16, int N) {
    constexpr int LDP = 72;
    __shared__ _Float16 sH[64 * LDP];
    const int tid = threadIdx.x;
    const int n0 = blockIdx.x * 64;

    for (int i = tid; i < 64 * 16; i += 256) {
        int row = i >> 4, c4 = (i & 15) << 2;
        int gr = n0 + row;
        float4 hv = (gr < N) ? *(const float4*)&h[((size_t)gr << 6) + c4]
                             : make_float4(0.f, 0.f, 0.f, 0.f);
        float4 sc = *(const float4*)&prm[c4];
        float4 sh = *(const float4*)&prm[64 + c4];
        f16x4 o;
        o[0] = (_Float16)fmaxf(fmaf(hv.x, sc.x, sh.x), 0.f);
        o[1] = (_Float16)fmaxf(fmaf(hv.y, sc.y, sh.y), 0.f);
        o[2] = (_Float16)fmaxf(fmaf(hv.z, sc.z, sh.z), 0.f);
        o[3] = (_Float16)fmaxf(fmaf(hv.w, sc.w, sh.w), 0.f);
        *(f16x4*)&sH[row * LDP + c4] = o;
    }
    __syncthreads();

    const int wid = tid >> 6, lane = tid & 63;
    const int lr = lane & 15, lg = lane >> 4;
    const int kof = lg << 3;
    const int arow = wid * 16 + lr;
    const int drow0 = wid * 16 + (lg << 2);

    f16x8 a0 = *(const f16x8*)&sH[arow * LDP + kof];
    f16x8 a1 = *(const f16x8*)&sH[arow * LDP + 32 + kof];

    #pragma unroll
    for (int n = 0; n < 8; n++) {
        const ushort* bp = w2T + (((size_t)(n << 4) + lr) << 6);
        f32x4 c = {0.f, 0.f, 0.f, 0.f};
        c = MFMA16(a0, *(const f16x8*)(bp + kof), c);
        c = MFMA16(a1, *(const f16x8*)(bp + 32 + kof), c);
        int col = (n << 4) + lr;
        float bb = b2[col];
        #pragma unroll
        for (int r = 0; r < 4; r++) {
            int gr = n0 + drow0 + r;
            if (gr < N) v16[((size_t)gr << 7) + col] =
                __builtin_bit_cast(ushort, (_Float16)fmaxf(c[r] + bb, 0.f));
        }
    }
}

// ---------------- MFMA single GEMM: vlin(fp16) = v16 @ lin, K=128 ----------------
__launch_bounds__(256, 4)
__global__ void k_gemm_rb(const ushort* __restrict__ A, const ushort* __restrict__ wT,
                          ushort* __restrict__ C, int N) {
    constexpr int LDP = 136;
    __shared__ _Float16 sA[64 * LDP];
    const int tid = threadIdx.x;
    const int n0 = blockIdx.x * 64;

    for (int i = tid; i < 64 * 32; i += 256) {
        int row = i >> 5, c4 = (i & 31) << 2;
        int gr = n0 + row;
        uint2 val = (gr < N) ? *(const uint2*)&A[((size_t)gr << 7) + c4]
                             : make_uint2(0u, 0u);
        *(uint2*)&sA[row * LDP + c4] = val;
    }
    __syncthreads();

    const int wid = tid >> 6, lane = tid & 63;
    const int lr = lane & 15, lg = lane >> 4;
    const int kof = lg << 3;
    const int arow = wid * 16 + lr;
    const int drow0 = wid * 16 + (lg << 2);

    f16x8 a0 = *(const f16x8*)&sA[arow * LDP + kof];
    f16x8 a1 = *(const f16x8*)&sA[arow * LDP + 32 + kof];
    f16x8 a2 = *(const f16x8*)&sA[arow * LDP + 64 + kof];
    f16x8 a3 = *(const f16x8*)&sA[arow * LDP + 96 + kof];

    #pragma unroll
    for (int n = 0; n < 8; n++) {
        const ushort* bp = wT + (((size_t)(n << 4) + lr) << 7);
        f32x4 c = {0.f, 0.f, 0.f, 0.f};
        c = MFMA16(a0, *(const f16x8*)(bp + kof), c);
        c = MFMA16(a1, *(const f16x8*)(bp + 32 + kof), c);
        c = MFMA16(a2, *(const f16x8*)(bp + 64 + kof), c);
        c = MFMA16(a3, *(const f16x8*)(bp + 96 + kof), c);
        int col = (n << 4) + lr;
        #pragma unroll
        for (int r = 0; r < 4; r++) {
            int gr = n0 + drow0 + r;
            if (gr < N) C[((size_t)gr << 7) + col] =
                __builtin_bit_cast(ushort, (_Float16)c[r]);
        }
    }
}

// ---------------- MFMA fused layer update: 1 wave per 16-col block (no redundant B loads) ----------------
__launch_bounds__(512, 8)
__global__ void k_update(const ushort* __restrict__ agg,
                         const ushort* __restrict__ w1T, const float* __restrict__ b1,
                         const ushort* __restrict__ w2T, const float* __restrict__ b2,
                         ushort* __restrict__ v16,
                         const ushort* __restrict__ linT, ushort* __restrict__ vlin, int N) {
    constexpr int LDP = 136;
    __shared__ _Float16 sA[64 * LDP];   // 17.4 KB
    __shared__ _Float16 sB[64 * LDP];   // 17.4 KB
    const int tid = threadIdx.x;
    const int n0 = blockIdx.x * 64;

    // coalesced stage: agg -> sA, v_old -> sB
    for (int i = tid; i < 64 * 32; i += 512) {
        int row = i >> 5, c4 = (i & 31) << 2;
        int gr = n0 + row;
        uint2 a = (gr < N) ? *(const uint2*)&agg[((size_t)gr << 7) + c4] : make_uint2(0u, 0u);
        uint2 b = (gr < N) ? *(const uint2*)&v16[((size_t)gr << 7) + c4] : make_uint2(0u, 0u);
        *(uint2*)&sA[row * LDP + c4] = a;
        *(uint2*)&sB[row * LDP + c4] = b;
    }
    __syncthreads();

    const int wid = tid >> 6, lane = tid & 63;
    const int lr = lane & 15, lg = lane >> 4;
    const int kof = lg << 3;
    const int col = (wid << 4) + lr;   // wave owns cols wid*16..wid*16+15
    const int dr0 = lg << 2;

    f32x4 acc[4];

    // ---- GEMM 1: t = ssp(agg @ W1 + b1) ----
    {
        const ushort* bp = w1T + ((size_t)col << 7);
        f16x8 B0 = *(const f16x8*)(bp + kof);
        f16x8 B1 = *(const f16x8*)(bp + 32 + kof);
        f16x8 B2 = *(const f16x8*)(bp + 64 + kof);
        f16x8 B3 = *(const f16x8*)(bp + 96 + kof);
        #pragma unroll
        for (int rb = 0; rb < 4; rb++) {
            const _Float16* ap = &sA[((rb << 4) + lr) * LDP + kof];
            f32x4 c = {0.f, 0.f, 0.f, 0.f};
            c = MFMA16(*(const f16x8*)ap, B0, c);
            c = MFMA16(*(const f16x8*)(ap + 32), B1, c);
            c = MFMA16(*(const f16x8*)(ap + 64), B2, c);
            c = MFMA16(*(const f16x8*)(ap + 96), B3, c);
            acc[rb] = c;
        }
    }
    __syncthreads();   // done reading agg tile
    {
        float bb = b1[col];
        #pragma unroll
        for (int rb = 0; rb < 4; rb++) {
            #pragma unroll
            for (int r = 0; r < 4; r++)
                sA[((rb << 4) + dr0 + r) * LDP + col] = (_Float16)sspf(acc[rb][r] + bb);
        }
    }
    __syncthreads();

    // ---- GEMM 2: v_new = t @ W2 + b2 + v_old (residual from sB, in-place) ----
    {
        const ushort* bp = w2T + ((size_t)col << 7);
        f16x8 B0 = *(const f16x8*)(bp + kof);
        f16x8 B1 = *(const f16x8*)(bp + 32 + kof);
        f16x8 B2 = *(const f16x8*)(bp + 64 + kof);
        f16x8 B3 = *(const f16x8*)(bp + 96 + kof);
        #pragma unroll
        for (int rb = 0; rb < 4; rb++) {
            const _Float16* ap = &sA[((rb << 4) + lr) * LDP + kof];
            f32x4 c = {0.f, 0.f, 0.f, 0.f};
            c = MFMA16(*(const f16x8*)ap, B0, c);
            c = MFMA16(*(const f16x8*)(ap + 32), B1, c);
            c = MFMA16(*(const f16x8*)(ap + 64), B2, c);
            c = MFMA16(*(const f16x8*)(ap + 96), B3, c);
            acc[rb] = c;
        }
    }
    {
        float bb = b2[col];
        #pragma unroll
        for (int rb = 0; rb < 4; rb++) {
            #pragma unroll
            for (int r = 0; r < 4; r++) {
                _Float16* p = &sB[((rb << 4) + dr0 + r) * LDP + col];
                *p = (_Float16)(acc[rb][r] + bb + (float)*p);   // lane owns this slot
            }
        }
    }
    __syncthreads();

    // coalesced store: sB -> v16
    for (int i = tid; i < 64 * 32; i += 512) {
        int row = i >> 5, c4 = (i & 31) << 2;
        int gr = n0 + row;
        if (gr < N) *(uint2*)&v16[((size_t)gr << 7) + c4] = *(const uint2*)&sB[row * LDP + c4];
    }
    if (!linT) return;

    // ---- GEMM 3: vlin = v_new @ lin (A from sB, park output in sA) ----
    {
        const ushort* bp = linT + ((size_t)col << 7);
        f16x8 B0 = *(const f16x8*)(bp + kof);
        f16x8 B1 = *(const f16x8*)(bp + 32 + kof);
        f16x8 B2 = *(const f16x8*)(bp + 64 + kof);
        f16x8 B3 = *(const f16x8*)(bp + 96 + kof);
        #pragma unroll
        for (int rb = 0; rb < 4; rb++) {
            const _Float16* ap = &sB[((rb << 4) + lr) * LDP + kof];
            f32x4 c = {0.f, 0.f, 0.f, 0.f};
            c = MFMA16(*(const f16x8*)ap, B0, c);
            c = MFMA16(*(const f16x8*)(ap + 32), B1, c);
            c = MFMA16(*(const f16x8*)(ap + 64), B2, c);
            c = MFMA16(*(const f16x8*)(ap + 96), B3, c);
            acc[rb] = c;
        }
    }
    // sA's t-tile reads finished before the last barrier -> safe to overwrite
    #pragma unroll
    for (int rb = 0; rb < 4; rb++) {
        #pragma unroll
        for (int r = 0; r < 4; r++)
            sA[((rb << 4) + dr0 + r) * LDP + col] = (_Float16)acc[rb][r];
    }
    __syncthreads();

    // coalesced store: sA -> vlin
    for (int i = tid; i < 64 * 32; i += 512) {
        int row = i >> 5, c4 = (i & 31) << 2;
        int gr = n0 + row;
        if (gr < N) *(uint2*)&vlin[((size_t)gr << 7) + c4] = *(const uint2*)&sA[row * LDP + c4];
    }
}

// ---------------- tiled fused readout (v16 input) ----------------
__launch_bounds__(256, 4)
__global__ void k_uout(const ushort* __restrict__ v16, const float* __restrict__ u1w,
                       const float* __restrict__ u1b, const float* __restrict__ u2w,
                       const float* __restrict__ u2b, const int* __restrict__ batch,
                       float* __restrict__ out, int N) {
    __shared__ float sA[64 * 128];
    const int tid = threadIdx.x;
    const int n0 = blockIdx.x * 64;

    for (int i = tid; i < 64 * 32; i += 256) {
        int row = i >> 5, cq = (i & 31) << 2;
        int gr = n0 + row;
        float4 val = make_float4(0.f, 0.f, 0.f, 0.f);
        if (gr < N) val = ld_h4(&v16[((size_t)gr << 7) + cq]);
        *(float4*)&sA[row * 128 + cq] = val;
    }
    __syncthreads();

    const int cg = tid & 31, rg = tid >> 5;
    const int r0 = rg << 3;
    const int c2 = cg << 1;

    float2 acc[8];
    {
        float2 b1v = *(const float2*)&u1b[c2];
        #pragma unroll
        for (int i = 0; i < 8; i++) acc[i] = b1v;
        #pragma unroll 4
        for (int k = 0; k < 128; k++) {
            float2 wv = *(const float2*)&u1w[(k << 6) + c2];
            #pragma unroll
            for (int i = 0; i < 8; i++) {
                float a = sA[(r0 + i) * 128 + k];
                acc[i].x = fmaf(a, wv.x, acc[i].x);
                acc[i].y = fmaf(a, wv.y, acc[i].y);
            }
        }
    }
    __syncthreads();
    #pragma unroll
    for (int i = 0; i < 8; i++) {
        sA[(r0 + i) * 64 + c2 + 0] = sspf(acc[i].x);
        sA[(r0 + i) * 64 + c2 + 1] = sspf(acc[i].y);
    }
    __syncthreads();

    float acc2[8];
    {
        float bb = u2b[cg];
        #pragma unroll
        for (int i = 0; i < 8; i++) acc2[i] = bb;
        #pragma unroll 4
        for (int k = 0; k < 64; k++) {
            float wv = u2w[(k << 5) + cg];
            #pragma unroll
            for (int i = 0; i < 8; i++)
                acc2[i] = fmaf(sA[(r0 + i) * 64 + k], wv, acc2[i]);
        }
    }

    int cur = -1;
    float run = 0.f;
    #pragma unroll
    for (int i = 0; i < 8; i++) {
        int gr = n0 + r0 + i;
        int g = (gr < N) ? batch[gr] : -1;
        if (g != cur) {
            if (cur >= 0) atomicAdd(&out[(size_t)cur * 32 + cg], run);
            cur = g;
            run = 0.f;
        }
        if (g >= 0) run += acc2[i];
    }
    if (cur >= 0) atomicAdd(&out[(size_t)cur * 32 + cg], run);
}

extern "C" void kernel_launch(void* const* d_in, const int* in_sizes, int n_in,
                              void* d_out, int out_size, void* d_ws, size_t ws_size,
                              hipStream_t stream) {
    const float* x      = (const float*)d_in[0];
    const float* pos    = (const float*)d_in[1];
    const int*   batch  = (const int*)d_in[2];
    const int*   ei     = (const int*)d_in[3];
    const float* fe_w1  = (const float*)d_in[4];
    const float* fe_b1  = (const float*)d_in[5];
    const float* bn_g   = (const float*)d_in[6];
    const float* bn_b   = (const float*)d_in[7];
    const float* fe_w2  = (const float*)d_in[8];
    const float* fe_b2  = (const float*)d_in[9];
    const float* lin_w  = (const float*)d_in[10];
    const float* mlp_w1 = (const float*)d_in[11];
    const float* mlp_b1 = (const float*)d_in[12];
    const float* mlp_w2 = (const float*)d_in[13];
    const float* mlp_b2 = (const float*)d_in[14];
    const float* v1_w   = (const float*)d_in[15];
    const float* v1_b   = (const float*)d_in[16];
    const float* v2_w   = (const float*)d_in[17];
    const float* v2_b   = (const float*)d_in[18];
    const float* u1_w   = (const float*)d_in[19];
    const float* u1_b   = (const float*)d_in[20];
    const float* u2_w   = (const float*)d_in[21];
    const float* u2_b   = (const float*)d_in[22];

    const int N = in_sizes[0] / 28;
    const int E = in_sizes[3] / 2;
    const int NB1 = (N + 1023) / 1024;

    char* ws = (char*)d_ws;
    size_t o = 0;
    auto alloc = [&](size_t bytes) { void* p = ws + o; o += (bytes + 255) & ~(size_t)255; return p; };
    int*    counts = (int*)   alloc((size_t)N * 4);
    int*    cursor = (int*)   alloc((size_t)N * 4);
    int*    rowptr = (int*)   alloc((size_t)N * 4);
    int*    bsum   = (int*)   alloc((size_t)NB1 * 4);
    uint2*  s_ef   = (uint2*) alloc((size_t)E * 8);
    float*  stats  = (float*) alloc(128 * 4);
    float*  prm    = (float*) alloc(128 * 4);
    ushort* tab    = (ushort*)alloc((size_t)LAY * K_TAB * 128 * 2);  // 12 MB fp16
    ushort* tab2   = (ushort*)alloc((size_t)LAY * K_TAB * 256 * 2);  // 24 MB paired
    ushort* v16    = (ushort*)alloc((size_t)N * 128 * 2);            // fp16 node state
    ushort* vlin   = (ushort*)alloc((size_t)N * 128 * 2);            // fp16
    ushort* agg    = (ushort*)alloc((size_t)N * 128 * 2);            // fp16
    float*  h      = (float*) alloc((size_t)N * 64 * 4);
    int*    locex  = (int*)   alloc((size_t)N * 4);
    ushort* v1T    = (ushort*)alloc((size_t)LAY * 16384 * 2);   // fp16 transposed weights
    ushort* v2T    = (ushort*)alloc((size_t)LAY * 16384 * 2);
    ushort* linT   = (ushort*)alloc((size_t)LAY * 16384 * 2);
    ushort* fe2T   = (ushort*)alloc((size_t)8192 * 2);

    // -------- weight conversion (fp16, transposed) --------
    k_cvtT128<<<LAY, 256, 0, stream>>>(v1_w, v1T);
    k_cvtT128<<<LAY, 256, 0, stream>>>(v2_w, v2T);
    k_cvtT128<<<LAY, 256, 0, stream>>>(lin_w, linT);
    k_cvtT_fe<<<1, 256, 0, stream>>>(fe_w2, fe2T);

    // -------- one-time edge sort (dst-ordered CSR) --------
    hipMemsetAsync(counts, 0, (size_t)N * 4, stream);
    k_hist<<<(E + 255) / 256, 256, 0, stream>>>(ei, counts, E);
    k_scan1<<<NB1, 1024, 0, stream>>>(counts, locex, bsum, N);
    k_scan2<<<1, 1024, 0, stream>>>(bsum, NB1);
    k_scan3<<<(N + 255) / 256, 256, 0, stream>>>(locex, bsum, cursor, rowptr, N);
    k_scatter<<<(E + 255) / 256, 256, 0, stream>>>(ei, pos, cursor, s_ef, E);

    // -------- gate tables (fp16), then pair-interleave --------
    k_tab_all<<<LAY * 256, 256, 0, stream>>>(mlp_w1, mlp_b1, mlp_w2, mlp_b2, tab);
    k_pair<<<LAY * K_TAB * 32 / 256, 256, 0, stream>>>(tab, tab2);

    // -------- feature embedding --------
    hipMemsetAsync(stats, 0, 128 * 4, stream);
    k_fe1<<<(N * 64 + 255) / 256, 256, 0, stream>>>(x, fe_w1, fe_b1, h, N);
    k_bnstat<<<256, 256, 0, stream>>>(h, stats, N);
    k_bnfin<<<1, 64, 0, stream>>>(stats, prm, bn_g, bn_b, 1.0f / (float)N);
    const int gblk = (N + 63) / 64;
    k_fe2<<<gblk, 256, 0, stream>>>(h, prm, fe2T, fe_b2, v16, N);

    // vlin for layer 0
    k_gemm_rb<<<gblk, 256, 0, stream>>>(v16, linT, vlin, N);

    // -------- interaction layers --------
    const int eblk = (N + 7) / 8;
    for (int l = 0; l < LAY; l++) {
        k_edge_csr<<<eblk, 256, 0, stream>>>(
            s_ef, rowptr, counts, vlin,
            tab2 + (size_t)l * K_TAB * 256, agg, N);
        const ushort* lin_next = (l + 1 < LAY) ? linT + (size_t)(l + 1) * 16384 : nullptr;
        k_update<<<gblk, 512, 0, stream>>>(
            agg, v1T + (size_t)l * 16384, v1_b + (size_t)l * 128,
            v2T + (size_t)l * 16384, v2_b + (size_t)l * 128,
            v16, lin_next, vlin, N);
    }

    // -------- fused readout --------
    hipMemsetAsync(d_out, 0, (size_t)out_size * 4, stream);
    k_uout<<<gblk, 256, 0, stream>>>(v16, u1_w, u1_b, u2_w, u2_b, batch, (float*)d_out, N);
}

// Round 17
// 654.269 us; speedup vs baseline: 1.4836x; 1.1031x over previous
//
#include <hip/hip_runtime.h>
#include <hip/hip_fp16.h>
#include <math.h>

#define DEV __device__ __forceinline__

constexpr int NGAUSS = 50;
constexpr int LAY = 6;
constexpr int K_TAB = 16384;                           // nearest-neighbor table
constexpr float DMAX = 40.0f;
constexpr float TSCALE = (float)(K_TAB - 1) / DMAX;    // knot = round(d * TSCALE)
constexpr float STEP = 6.0f / 49.0f;
constexpr float COEFF = -0.5f / (STEP * STEP);
constexpr float LN2F = 0.69314718055994531f;
constexpr float PI_OVER_CUT = 0.52359877559829887f;    // pi/6

using f16x8 = __attribute__((ext_vector_type(8))) _Float16;
using f16x4 = __attribute__((ext_vector_type(4))) _Float16;
using f32x4 = __attribute__((ext_vector_type(4))) float;
using f32x8 = __attribute__((ext_vector_type(8))) float;

#define MFMA16(a, b, c) __builtin_amdgcn_mfma_f32_16x16x32_f16(a, b, c, 0, 0, 0)

DEV float sspf(float x) {
    float ax = fabsf(x);
    float e = __expf(-ax);
    return fmaxf(x, 0.f) + __logf(1.f + e) - LN2F;
}

// ---- fp16 pack/unpack helpers (storage fp16, math f32) ----
DEV float4 ld_h4(const ushort* p) {          // 8B load -> 4 floats
    uint2 r = *(const uint2*)p;
    __half2 a = __builtin_bit_cast(__half2, r.x);
    __half2 b = __builtin_bit_cast(__half2, r.y);
    float2 fa = __half22float2(a), fb = __half22float2(b);
    return make_float4(fa.x, fa.y, fb.x, fb.y);
}
DEV void st_h4(ushort* p, float4 v) {        // 4 floats -> 8B store
    uint2 r;
    r.x = __builtin_bit_cast(uint, __float22half2_rn(make_float2(v.x, v.y)));
    r.y = __builtin_bit_cast(uint, __float22half2_rn(make_float2(v.z, v.w)));
    *(uint2*)p = r;
}

// ---------------- weight convert+transpose (fp32 [K][C] -> fp16 [C][K]) ----------------
__global__ void k_cvtT128(const float* __restrict__ src, ushort* __restrict__ dst) {
    const float* s = src + (size_t)blockIdx.x * 16384;
    ushort* d = dst + (size_t)blockIdx.x * 16384;
    for (int i = threadIdx.x; i < 16384; i += 256) {
        int k = i >> 7, c = i & 127;
        d[(c << 7) + k] = __builtin_bit_cast(ushort, (_Float16)s[i]);
    }
}
__global__ void k_cvtT_fe(const float* __restrict__ src, ushort* __restrict__ dst) {
    // fe_w2: [64][128] -> dst[c(128)][k(64)]
    for (int i = threadIdx.x; i < 8192; i += 256) {
        int k = i >> 7, c = i & 127;
        dst[(c << 6) + k] = __builtin_bit_cast(ushort, (_Float16)src[i]);
    }
}

// ---------------- edge sort pre-pass (once per call) ----------------
__global__ void k_hist(const int* __restrict__ ei, int* __restrict__ counts, int E) {
    int e = blockIdx.x * 256 + threadIdx.x;
    if (e < E) atomicAdd(&counts[ei[E + e]], 1);
}

__global__ void k_scan1(const int* __restrict__ counts, int* __restrict__ locex,
                        int* __restrict__ bsum, int n) {
    __shared__ int s_wsum[16];
    const int tid = threadIdx.x;
    const int i = blockIdx.x * 1024 + tid;
    const int lane = tid & 63, wv = tid >> 6;
    int v = (i < n) ? counts[i] : 0;
    int x = v;
    #pragma unroll
    for (int off = 1; off < 64; off <<= 1) {
        int y = __shfl_up(x, off, 64);
        if (lane >= off) x += y;
    }
    if (lane == 63) s_wsum[wv] = x;
    __syncthreads();
    if (wv == 0 && lane < 16) {
        int wval = s_wsum[lane];
        int wx = wval;
        #pragma unroll
        for (int off = 1; off < 16; off <<= 1) {
            int wy = __shfl_up(wx, off, 16);
            if (lane >= off) wx += wy;
        }
        s_wsum[lane] = wx - wval;
    }
    __syncthreads();
    if (i < n) locex[i] = s_wsum[wv] + x - v;
    if (tid == 1023) bsum[blockIdx.x] = s_wsum[15] + x;
}

__global__ void k_scan2(int* __restrict__ bsum, int nb) {
    __shared__ int s_wsum[16];
    const int tid = threadIdx.x;
    const int lane = tid & 63, wv = tid >> 6;
    int v = (tid < nb) ? bsum[tid] : 0;
    int x = v;
    #pragma unroll
    for (int off = 1; off < 64; off <<= 1) {
        int y = __shfl_up(x, off, 64);
        if (lane >= off) x += y;
    }
    if (lane == 63) s_wsum[wv] = x;
    __syncthreads();
    if (wv == 0 && lane < 16) {
        int wval = s_wsum[lane];
        int wx = wval;
        #pragma unroll
        for (int off = 1; off < 16; off <<= 1) {
            int wy = __shfl_up(wx, off, 16);
            if (lane >= off) wx += wy;
        }
        s_wsum[lane] = wx - wval;
    }
    __syncthreads();
    if (tid < nb) bsum[tid] = s_wsum[wv] + x - v;
}

__global__ void k_scan3(const int* __restrict__ locex, const int* __restrict__ bsumex,
                        int* __restrict__ cursor, int* __restrict__ rowptr, int n) {
    int i = blockIdx.x * 256 + threadIdx.x;
    if (i >= n) return;
    int e = locex[i] + bsumex[i >> 10];
    cursor[i] = e;
    rowptr[i] = e;
}

// scatter: one 4B store per edge, packed {src(16b) | knot(14b)<<16}
// NOTE: requires N < 65536 (N = 50000 here) and K_TAB <= 65536.
__global__ void k_scatter(const int* __restrict__ ei, const float* __restrict__ pos,
                          int* __restrict__ cursor, uint* __restrict__ s_ef, int E) {
    int e = blockIdx.x * 256 + threadIdx.x;
    if (e >= E) return;
    int r = ei[e], c = ei[E + e];
    int p = atomicAdd(&cursor[c], 1);
    float dx = pos[3 * r + 0] - pos[3 * c + 0];
    float dy = pos[3 * r + 1] - pos[3 * c + 1];
    float dz = pos[3 * r + 2] - pos[3 * c + 2];
    float d = sqrtf(dx * dx + dy * dy + dz * dz);
    int i0 = (int)(d * TSCALE + 0.5f);
    if (i0 > K_TAB - 1) i0 = K_TAB - 1;
    s_ef[p] = (uint)r | ((uint)i0 << 16);
}

// ---------------- gate table build (fp16 output), ALL layers in one launch ----------------
// 32 knots per block; grid = LAY * (K_TAB/32)
__launch_bounds__(256)
__global__ void k_tab_all(const float* __restrict__ w1A, const float* __restrict__ b1A,
                          const float* __restrict__ w2A, const float* __restrict__ b2A,
                          ushort* __restrict__ tabA) {
    const int layer = blockIdx.x / (K_TAB / 32);
    const int k0 = (blockIdx.x % (K_TAB / 32)) * 32;
    const float* w1 = w1A + (size_t)layer * NGAUSS * 128;
    const float* b1 = b1A + (size_t)layer * 128;
    const float* w2 = w2A + (size_t)layer * 128 * 128;
    const float* b2 = b2A + (size_t)layer * 128;
    ushort* tab = tabA + (size_t)layer * K_TAB * 128;

    __shared__ float s_demb[32][NGAUSS];
    __shared__ float s_t1[32][128];
    const int tid = threadIdx.x;

    for (int i = tid; i < 32 * NGAUSS; i += 256) {
        int r = i / NGAUSS, g = i - r * NGAUSS;
        float d = (float)(k0 + r) * (1.0f / TSCALE);
        float t = d - g * STEP;
        s_demb[r][g] = __expf(COEFF * t * t);
    }
    __syncthreads();

    const int cg = tid & 31, rg = tid >> 5;
    const int r0 = rg << 2;
    const int c4 = cg << 2;

    float4 b1v = *(const float4*)&b1[c4];
    float4 acc[4];
    #pragma unroll
    for (int i = 0; i < 4; i++) acc[i] = b1v;
    #pragma unroll 2
    for (int k = 0; k < NGAUSS; k++) {
        float4 wv = *(const float4*)&w1[(k << 7) + c4];
        #pragma unroll
        for (int i = 0; i < 4; i++) {
            float dv = s_demb[r0 + i][k];
            acc[i].x = fmaf(dv, wv.x, acc[i].x);
            acc[i].y = fmaf(dv, wv.y, acc[i].y);
            acc[i].z = fmaf(dv, wv.z, acc[i].z);
            acc[i].w = fmaf(dv, wv.w, acc[i].w);
        }
    }
    #pragma unroll
    for (int i = 0; i < 4; i++) {
        float4 t;
        t.x = sspf(acc[i].x); t.y = sspf(acc[i].y);
        t.z = sspf(acc[i].z); t.w = sspf(acc[i].w);
        *(float4*)&s_t1[r0 + i][c4] = t;
    }
    __syncthreads();

    float4 b2v = *(const float4*)&b2[c4];
    float4 a2[4];
    #pragma unroll
    for (int i = 0; i < 4; i++) a2[i] = b2v;
    #pragma unroll 4
    for (int k = 0; k < 128; k++) {
        float4 wv = *(const float4*)&w2[(k << 7) + c4];
        #pragma unroll
        for (int i = 0; i < 4; i++) {
            float tv = s_t1[r0 + i][k];
            a2[i].x = fmaf(tv, wv.x, a2[i].x);
            a2[i].y = fmaf(tv, wv.y, a2[i].y);
            a2[i].z = fmaf(tv, wv.z, a2[i].z);
            a2[i].w = fmaf(tv, wv.w, a2[i].w);
        }
    }
    #pragma unroll
    for (int i = 0; i < 4; i++) {
        int knot = k0 + r0 + i;
        float d = (float)knot * (1.0f / TSCALE);
        float cc = 0.5f * (__cosf(d * PI_OVER_CUT) + 1.0f);
        float4 o;
        o.x = a2[i].x * cc; o.y = a2[i].y * cc;
        o.z = a2[i].z * cc; o.w = a2[i].w * cc;
        st_h4(&tab[((size_t)knot << 7) + c4], o);
    }
}

// ---------------- node-centric CSR edge kernel: NN table, 16 lanes/edge, 2 edges in flight ----------------
// 32-lane group owns node n; half h = edge parity, lane covers 8 channels (f16x8).
__launch_bounds__(256, 8)
__global__ void k_edge_csr(const uint* __restrict__ s_ef,
                           const int* __restrict__ rowptr, const int* __restrict__ counts,
                           const ushort* __restrict__ vlin, const ushort* __restrict__ tab,
                           ushort* __restrict__ agg, int N) {
    const int tid = threadIdx.x;
    const int l32 = tid & 31;
    const int h = l32 >> 4;          // 0/1: which parity of edges this lane handles
    const int lc = l32 & 15;         // channel octet: channels 8lc..8lc+7
    const int n = blockIdx.x * 8 + (tid >> 5);
    if (n >= N) return;
    const ushort* tabc = tab + (lc << 3);
    const ushort* vlc  = vlin + (lc << 3);

    const int rs = rowptr[n];
    const int re = rs + counts[n];
    f32x8 acc = {0.f, 0.f, 0.f, 0.f, 0.f, 0.f, 0.f, 0.f};

    int e = rs + h;
    // main loop: 4 edges of this parity per iter (8 edges per group-iter)
    for (; e + 6 < re; e += 8) {
        f16x8 TP[4], VL[4];
        #pragma unroll
        for (int j = 0; j < 4; j++) {
            uint pk = s_ef[e + 2 * j];
            TP[j] = *(const f16x8*)(tabc + ((size_t)(pk >> 16) << 7));
            VL[j] = *(const f16x8*)(vlc + ((size_t)(pk & 0xFFFFu) << 7));
        }
        f16x8 p0 = TP[0] * VL[0];
        p0 += TP[1] * VL[1];
        f16x8 p1 = TP[2] * VL[2];
        p1 += TP[3] * VL[3];
        acc += __builtin_convertvector(p0, f32x8);
        acc += __builtin_convertvector(p1, f32x8);
    }
    // tail: one edge of this parity at a time
    for (; e < re; e += 2) {
        uint pk = s_ef[e];
        f16x8 tp = *(const f16x8*)(tabc + ((size_t)(pk >> 16) << 7));
        f16x8 vl = *(const f16x8*)(vlc + ((size_t)(pk & 0xFFFFu) << 7));
        acc += __builtin_convertvector(tp * vl, f32x8);
    }
    // combine parity halves (lane i <-> lane i^16)
    #pragma unroll
    for (int i = 0; i < 8; i++) acc[i] += __shfl_xor(acc[i], 16);
    if (h == 0) {
        f16x8 o;
        #pragma unroll
        for (int i = 0; i < 8; i++) o[i] = (_Float16)acc[i];
        *(f16x8*)&agg[((size_t)n << 7) + (lc << 3)] = o;
    }
}

// ---------------- feature embedding ----------------
__global__ void k_fe1(const float* __restrict__ x, const float* __restrict__ w,
                      const float* __restrict__ b, float* __restrict__ h, int N) {
    int idx = blockIdx.x * 256 + threadIdx.x;
    if (idx >= N * 64) return;
    int n = idx >> 6, c = idx & 63;
    const float* xr = x + (size_t)n * 28;
    float acc = b[c];
    #pragma unroll
    for (int k = 0; k < 28; k++) acc = fmaf(xr[k], w[k * 64 + c], acc);
    h[idx] = acc;
}

__global__ void k_bnstat(const float* __restrict__ h, float* __restrict__ stats, int N) {
    __shared__ float s_s[256], s_q[256];
    int tid = threadIdx.x;
    int c = tid & 63, g = tid >> 6;
    float s = 0.f, q = 0.f;
    for (int n = blockIdx.x * 4 + g; n < N; n += gridDim.x * 4) {
        float v = h[(size_t)n * 64 + c];
        s += v; q += v * v;
    }
    s_s[tid] = s; s_q[tid] = q;
    __syncthreads();
    if (tid < 64) {
        s = s_s[tid] + s_s[tid + 64] + s_s[tid + 128] + s_s[tid + 192];
        q = s_q[tid] + s_q[tid + 64] + s_q[tid + 128] + s_q[tid + 192];
        atomicAdd(&stats[tid], s);
        atomicAdd(&stats[64 + tid], q);
    }
}

__global__ void k_bnfin(const float* __restrict__ stats, float* __restrict__ prm,
                        const float* __restrict__ gamma, const float* __restrict__ beta,
                        float invN) {
    int c = threadIdx.x;  // 64 threads
    float mu = stats[c] * invN;
    float var = stats[64 + c] * invN - mu * mu;
    float sc = gamma[c] * rsqrtf(var + 1e-5f);
    prm[c] = sc;
    prm[64 + c] = beta[c] - mu * sc;
}

// ---------------- MFMA fe2: v16 = relu( relu(bn(h)) @ fe_w2 + b2 ), K=64 ----------------
__launch_bounds__(256, 4)
__global__ void k_fe2(const float* __restrict__ h, const float* __restrict__ prm,
                      const ushort* __restrict__ w2T, const float* __restrict__ b2,
                      ushort* __restrict__ v16, int N) {
    constexpr int LDP = 72;
    __shared__ _Float16 sH[64 * LDP];
    const int tid = threadIdx.x;
    const int n0 = blockIdx.x * 64;

    for (int i = tid; i < 64 * 16; i += 256) {
        int row = i >> 4, c4 = (i & 15) << 2;
        int gr = n0 + row;
        float4 hv = (gr < N) ? *(const float4*)&h[((size_t)gr << 6) + c4]
                             : make_float4(0.f, 0.f, 0.f, 0.f);
        float4 sc = *(const float4*)&prm[c4];
        float4 sh = *(const float4*)&prm[64 + c4];
        f16x4 o;
        o[0] = (_Float16)fmaxf(fmaf(hv.x, sc.x, sh.x), 0.f);
        o[1] = (_Float16)fmaxf(fmaf(hv.y, sc.y, sh.y), 0.f);
        o[2] = (_Float16)fmaxf(fmaf(hv.z, sc.z, sh.z), 0.f);
        o[3] = (_Float16)fmaxf(fmaf(hv.w, sc.w, sh.w), 0.f);
        *(f16x4*)&sH[row * LDP + c4] = o;
    }
    __syncthreads();

    const int wid = tid >> 6, lane = tid & 63;
    const int lr = lane & 15, lg = lane >> 4;
    const int kof = lg << 3;
    const int arow = wid * 16 + lr;
    const int drow0 = wid * 16 + (lg << 2);

    f16x8 a0 = *(const f16x8*)&sH[arow * LDP + kof];
    f16x8 a1 = *(const f16x8*)&sH[arow * LDP + 32 + kof];

    #pragma unroll
    for (int n = 0; n < 8; n++) {
        const ushort* bp = w2T + (((size_t)(n << 4) + lr) << 6);
        f32x4 c = {0.f, 0.f, 0.f, 0.f};
        c = MFMA16(a0, *(const f16x8*)(bp + kof), c);
        c = MFMA16(a1, *(const f16x8*)(bp + 32 + kof), c);
        int col = (n << 4) + lr;
        float bb = b2[col];
        #pragma unroll
        for (int r = 0; r < 4; r++) {
            int gr = n0 + drow0 + r;
            if (gr < N) v16[((size_t)gr << 7) + col] =
                __builtin_bit_cast(ushort, (_Float16)fmaxf(c[r] + bb, 0.f));
        }
    }
}

// ---------------- MFMA single GEMM: vlin(fp16) = v16 @ lin, K=128 ----------------
__launch_bounds__(256, 4)
__global__ void k_gemm_rb(const ushort* __restrict__ A, const ushort* __restrict__ wT,
                          ushort* __restrict__ C, int N) {
    constexpr int LDP = 136;
    __shared__ _Float16 sA[64 * LDP];
    const int tid = threadIdx.x;
    const int n0 = blockIdx.x * 64;

    for (int i = tid; i < 64 * 32; i += 256) {
        int row = i >> 5, c4 = (i & 31) << 2;
        int gr = n0 + row;
        uint2 val = (gr < N) ? *(const uint2*)&A[((size_t)gr << 7) + c4]
                             : make_uint2(0u, 0u);
        *(uint2*)&sA[row * LDP + c4] = val;
    }
    __syncthreads();

    const int wid = tid >> 6, lane = tid & 63;
    const int lr = lane & 15, lg = lane >> 4;
    const int kof = lg << 3;
    const int arow = wid * 16 + lr;
    const int drow0 = wid * 16 + (lg << 2);

    f16x8 a0 = *(const f16x8*)&sA[arow * LDP + kof];
    f16x8 a1 = *(const f16x8*)&sA[arow * LDP + 32 + kof];
    f16x8 a2 = *(const f16x8*)&sA[arow * LDP + 64 + kof];
    f16x8 a3 = *(const f16x8*)&sA[arow * LDP + 96 + kof];

    #pragma unroll
    for (int n = 0; n < 8; n++) {
        const ushort* bp = wT + (((size_t)(n << 4) + lr) << 7);
        f32x4 c = {0.f, 0.f, 0.f, 0.f};
        c = MFMA16(a0, *(const f16x8*)(bp + kof), c);
        c = MFMA16(a1, *(const f16x8*)(bp + 32 + kof), c);
        c = MFMA16(a2, *(const f16x8*)(bp + 64 + kof), c);
        c = MFMA16(a3, *(const f16x8*)(bp + 96 + kof), c);
        int col = (n << 4) + lr;
        #pragma unroll
        for (int r = 0; r < 4; r++) {
            int gr = n0 + drow0 + r;
            if (gr < N) C[((size_t)gr << 7) + col] =
                __builtin_bit_cast(ushort, (_Float16)c[r]);
        }
    }
}

// ---------------- MFMA fused layer update: 1 wave per 16-col block (no redundant B loads) ----------------
__launch_bounds__(512, 8)
__global__ void k_update(const ushort* __restrict__ agg,
                         const ushort* __restrict__ w1T, const float* __restrict__ b1,
                         const ushort* __restrict__ w2T, const float* __restrict__ b2,
                         ushort* __restrict__ v16,
                         const ushort* __restrict__ linT, ushort* __restrict__ vlin, int N) {
    constexpr int LDP = 136;
    __shared__ _Float16 sA[64 * LDP];   // 17.4 KB
    __shared__ _Float16 sB[64 * LDP];   // 17.4 KB
    const int tid = threadIdx.x;
    const int n0 = blockIdx.x * 64;

    // coalesced stage: agg -> sA, v_old -> sB
    for (int i = tid; i < 64 * 32; i += 512) {
        int row = i >> 5, c4 = (i & 31) << 2;
        int gr = n0 + row;
        uint2 a = (gr < N) ? *(const uint2*)&agg[((size_t)gr << 7) + c4] : make_uint2(0u, 0u);
        uint2 b = (gr < N) ? *(const uint2*)&v16[((size_t)gr << 7) + c4] : make_uint2(0u, 0u);
        *(uint2*)&sA[row * LDP + c4] = a;
        *(uint2*)&sB[row * LDP + c4] = b;
    }
    __syncthreads();

    const int wid = tid >> 6, lane = tid & 63;
    const int lr = lane & 15, lg = lane >> 4;
    const int kof = lg << 3;
    const int col = (wid << 4) + lr;   // wave owns cols wid*16..wid*16+15
    const int dr0 = lg << 2;

    f32x4 acc[4];

    // ---- GEMM 1: t = ssp(agg @ W1 + b1) ----
    {
        const ushort* bp = w1T + ((size_t)col << 7);
        f16x8 B0 = *(const f16x8*)(bp + kof);
        f16x8 B1 = *(const f16x8*)(bp + 32 + kof);
        f16x8 B2 = *(const f16x8*)(bp + 64 + kof);
        f16x8 B3 = *(const f16x8*)(bp + 96 + kof);
        #pragma unroll
        for (int rb = 0; rb < 4; rb++) {
            const _Float16* ap = &sA[((rb << 4) + lr) * LDP + kof];
            f32x4 c = {0.f, 0.f, 0.f, 0.f};
            c = MFMA16(*(const f16x8*)ap, B0, c);
            c = MFMA16(*(const f16x8*)(ap + 32), B1, c);
            c = MFMA16(*(const f16x8*)(ap + 64), B2, c);
            c = MFMA16(*(const f16x8*)(ap + 96), B3, c);
            acc[rb] = c;
        }
    }
    __syncthreads();   // done reading agg tile
    {
        float bb = b1[col];
        #pragma unroll
        for (int rb = 0; rb < 4; rb++) {
            #pragma unroll
            for (int r = 0; r < 4; r++)
                sA[((rb << 4) + dr0 + r) * LDP + col] = (_Float16)sspf(acc[rb][r] + bb);
        }
    }
    __syncthreads();

    // ---- GEMM 2: v_new = t @ W2 + b2 + v_old (residual from sB, in-place) ----
    {
        const ushort* bp = w2T + ((size_t)col << 7);
        f16x8 B0 = *(const f16x8*)(bp + kof);
        f16x8 B1 = *(const f16x8*)(bp + 32 + kof);
        f16x8 B2 = *(const f16x8*)(bp + 64 + kof);
        f16x8 B3 = *(const f16x8*)(bp + 96 + kof);
        #pragma unroll
        for (int rb = 0; rb < 4; rb++) {
            const _Float16* ap = &sA[((rb << 4) + lr) * LDP + kof];
            f32x4 c = {0.f, 0.f, 0.f, 0.f};
            c = MFMA16(*(const f16x8*)ap, B0, c);
            c = MFMA16(*(const f16x8*)(ap + 32), B1, c);
            c = MFMA16(*(const f16x8*)(ap + 64), B2, c);
            c = MFMA16(*(const f16x8*)(ap + 96), B3, c);
            acc[rb] = c;
        }
    }
    {
        float bb = b2[col];
        #pragma unroll
        for (int rb = 0; rb < 4; rb++) {
            #pragma unroll
            for (int r = 0; r < 4; r++) {
                _Float16* p = &sB[((rb << 4) + dr0 + r) * LDP + col];
                *p = (_Float16)(acc[rb][r] + bb + (float)*p);   // lane owns this slot
            }
        }
    }
    __syncthreads();

    // coalesced store: sB -> v16
    for (int i = tid; i < 64 * 32; i += 512) {
        int row = i >> 5, c4 = (i & 31) << 2;
        int gr = n0 + row;
        if (gr < N) *(uint2*)&v16[((size_t)gr << 7) + c4] = *(const uint2*)&sB[row * LDP + c4];
    }
    if (!linT) return;

    // ---- GEMM 3: vlin = v_new @ lin (A from sB, park output in sA) ----
    {
        const ushort* bp = linT + ((size_t)col << 7);
        f16x8 B0 = *(const f16x8*)(bp + kof);
        f16x8 B1 = *(const f16x8*)(bp + 32 + kof);
        f16x8 B2 = *(const f16x8*)(bp + 64 + kof);
        f16x8 B3 = *(const f16x8*)(bp + 96 + kof);
        #pragma unroll
        for (int rb = 0; rb < 4; rb++) {
            const _Float16* ap = &sB[((rb << 4) + lr) * LDP + kof];
            f32x4 c = {0.f, 0.f, 0.f, 0.f};
            c = MFMA16(*(const f16x8*)ap, B0, c);
            c = MFMA16(*(const f16x8*)(ap + 32), B1, c);
            c = MFMA16(*(const f16x8*)(ap + 64), B2, c);
            c = MFMA16(*(const f16x8*)(ap + 96), B3, c);
            acc[rb] = c;
        }
    }
    // sA's t-tile reads finished before the last barrier -> safe to overwrite
    #pragma unroll
    for (int rb = 0; rb < 4; rb++) {
        #pragma unroll
        for (int r = 0; r < 4; r++)
            sA[((rb << 4) + dr0 + r) * LDP + col] = (_Float16)acc[rb][r];
    }
    __syncthreads();

    // coalesced store: sA -> vlin
    for (int i = tid; i < 64 * 32; i += 512) {
        int row = i >> 5, c4 = (i & 31) << 2;
        int gr = n0 + row;
        if (gr < N) *(uint2*)&vlin[((size_t)gr << 7) + c4] = *(const uint2*)&sA[row * LDP + c4];
    }
}

// ---------------- tiled fused readout (v16 input) ----------------
__launch_bounds__(256, 4)
__global__ void k_uout(const ushort* __restrict__ v16, const float* __restrict__ u1w,
                       const float* __restrict__ u1b, const float* __restrict__ u2w,
                       const float* __restrict__ u2b, const int* __restrict__ batch,
                       float* __restrict__ out, int N) {
    __shared__ float sA[64 * 128];
    const int tid = threadIdx.x;
    const int n0 = blockIdx.x * 64;

    for (int i = tid; i < 64 * 32; i += 256) {
        int row = i >> 5, cq = (i & 31) << 2;
        int gr = n0 + row;
        float4 val = make_float4(0.f, 0.f, 0.f, 0.f);
        if (gr < N) val = ld_h4(&v16[((size_t)gr << 7) + cq]);
        *(float4*)&sA[row * 128 + cq] = val;
    }
    __syncthreads();

    const int cg = tid & 31, rg = tid >> 5;
    const int r0 = rg << 3;
    const int c2 = cg << 1;

    float2 acc[8];
    {
        float2 b1v = *(const float2*)&u1b[c2];
        #pragma unroll
        for (int i = 0; i < 8; i++) acc[i] = b1v;
        #pragma unroll 4
        for (int k = 0; k < 128; k++) {
            float2 wv = *(const float2*)&u1w[(k << 6) + c2];
            #pragma unroll
            for (int i = 0; i < 8; i++) {
                float a = sA[(r0 + i) * 128 + k];
                acc[i].x = fmaf(a, wv.x, acc[i].x);
                acc[i].y = fmaf(a, wv.y, acc[i].y);
            }
        }
    }
    __syncthreads();
    #pragma unroll
    for (int i = 0; i < 8; i++) {
        sA[(r0 + i) * 64 + c2 + 0] = sspf(acc[i].x);
        sA[(r0 + i) * 64 + c2 + 1] = sspf(acc[i].y);
    }
    __syncthreads();

    float acc2[8];
    {
        float bb = u2b[cg];
        #pragma unroll
        for (int i = 0; i < 8; i++) acc2[i] = bb;
        #pragma unroll 4
        for (int k = 0; k < 64; k++) {
            float wv = u2w[(k << 5) + cg];
            #pragma unroll
            for (int i = 0; i < 8; i++)
                acc2[i] = fmaf(sA[(r0 + i) * 64 + k], wv, acc2[i]);
        }
    }

    int cur = -1;
    float run = 0.f;
    #pragma unroll
    for (int i = 0; i < 8; i++) {
        int gr = n0 + r0 + i;
        int g = (gr < N) ? batch[gr] : -1;
        if (g != cur) {
            if (cur >= 0) atomicAdd(&out[(size_t)cur * 32 + cg], run);
            cur = g;
            run = 0.f;
        }
        if (g >= 0) run += acc2[i];
    }
    if (cur >= 0) atomicAdd(&out[(size_t)cur * 32 + cg], run);
}

extern "C" void kernel_launch(void* const* d_in, const int* in_sizes, int n_in,
                              void* d_out, int out_size, void* d_ws, size_t ws_size,
                              hipStream_t stream) {
    const float* x      = (const float*)d_in[0];
    const float* pos    = (const float*)d_in[1];
    const int*   batch  = (const int*)d_in[2];
    const int*   ei     = (const int*)d_in[3];
    const float* fe_w1  = (const float*)d_in[4];
    const float* fe_b1  = (const float*)d_in[5];
    const float* bn_g   = (const float*)d_in[6];
    const float* bn_b   = (const float*)d_in[7];
    const float* fe_w2  = (const float*)d_in[8];
    const float* fe_b2  = (const float*)d_in[9];
    const float* lin_w  = (const float*)d_in[10];
    const float* mlp_w1 = (const float*)d_in[11];
    const float* mlp_b1 = (const float*)d_in[12];
    const float* mlp_w2 = (const float*)d_in[13];
    const float* mlp_b2 = (const float*)d_in[14];
    const float* v1_w   = (const float*)d_in[15];
    const float* v1_b   = (const float*)d_in[16];
    const float* v2_w   = (const float*)d_in[17];
    const float* v2_b   = (const float*)d_in[18];
    const float* u1_w   = (const float*)d_in[19];
    const float* u1_b   = (const float*)d_in[20];
    const float* u2_w   = (const float*)d_in[21];
    const float* u2_b   = (const float*)d_in[22];

    const int N = in_sizes[0] / 28;
    const int E = in_sizes[3] / 2;
    const int NB1 = (N + 1023) / 1024;

    char* ws = (char*)d_ws;
    size_t o = 0;
    auto alloc = [&](size_t bytes) { void* p = ws + o; o += (bytes + 255) & ~(size_t)255; return p; };
    int*    counts = (int*)   alloc((size_t)N * 4);
    int*    cursor = (int*)   alloc((size_t)N * 4);
    int*    rowptr = (int*)   alloc((size_t)N * 4);
    int*    bsum   = (int*)   alloc((size_t)NB1 * 4);
    uint*   s_ef   = (uint*)  alloc((size_t)E * 4);
    float*  stats  = (float*) alloc(128 * 4);
    float*  prm    = (float*) alloc(128 * 4);
    ushort* tab    = (ushort*)alloc((size_t)LAY * K_TAB * 128 * 2);  // 25 MB fp16 (NN)
    ushort* v16    = (ushort*)alloc((size_t)N * 128 * 2);            // fp16 node state
    ushort* vlin   = (ushort*)alloc((size_t)N * 128 * 2);            // fp16
    ushort* agg    = (ushort*)alloc((size_t)N * 128 * 2);            // fp16
    float*  h      = (float*) alloc((size_t)N * 64 * 4);
    int*    locex  = (int*)   alloc((size_t)N * 4);
    ushort* v1T    = (ushort*)alloc((size_t)LAY * 16384 * 2);   // fp16 transposed weights
    ushort* v2T    = (ushort*)alloc((size_t)LAY * 16384 * 2);
    ushort* linT   = (ushort*)alloc((size_t)LAY * 16384 * 2);
    ushort* fe2T   = (ushort*)alloc((size_t)8192 * 2);

    // -------- weight conversion (fp16, transposed) --------
    k_cvtT128<<<LAY, 256, 0, stream>>>(v1_w, v1T);
    k_cvtT128<<<LAY, 256, 0, stream>>>(v2_w, v2T);
    k_cvtT128<<<LAY, 256, 0, stream>>>(lin_w, linT);
    k_cvtT_fe<<<1, 256, 0, stream>>>(fe_w2, fe2T);

    // -------- one-time edge sort (dst-ordered CSR) --------
    hipMemsetAsync(counts, 0, (size_t)N * 4, stream);
    k_hist<<<(E + 255) / 256, 256, 0, stream>>>(ei, counts, E);
    k_scan1<<<NB1, 1024, 0, stream>>>(counts, locex, bsum, N);
    k_scan2<<<1, 1024, 0, stream>>>(bsum, NB1);
    k_scan3<<<(N + 255) / 256, 256, 0, stream>>>(locex, bsum, cursor, rowptr, N);
    k_scatter<<<(E + 255) / 256, 256, 0, stream>>>(ei, pos, cursor, s_ef, E);

    // -------- gate tables (fp16, nearest-neighbor, 16384 knots) --------
    k_tab_all<<<LAY * (K_TAB / 32), 256, 0, stream>>>(mlp_w1, mlp_b1, mlp_w2, mlp_b2, tab);

    // -------- feature embedding --------
    hipMemsetAsync(stats, 0, 128 * 4, stream);
    k_fe1<<<(N * 64 + 255) / 256, 256, 0, stream>>>(x, fe_w1, fe_b1, h, N);
    k_bnstat<<<256, 256, 0, stream>>>(h, stats, N);
    k_bnfin<<<1, 64, 0, stream>>>(stats, prm, bn_g, bn_b, 1.0f / (float)N);
    const int gblk = (N + 63) / 64;
    k_fe2<<<gblk, 256, 0, stream>>>(h, prm, fe2T, fe_b2, v16, N);

    // vlin for layer 0
    k_gemm_rb<<<gblk, 256, 0, stream>>>(v16, linT, vlin, N);

    // -------- interaction layers --------
    const int eblk = (N + 7) / 8;
    for (int l = 0; l < LAY; l++) {
        k_edge_csr<<<eblk, 256, 0, stream>>>(
            s_ef, rowptr, counts, vlin,
            tab + (size_t)l * K_TAB * 128, agg, N);
        const ushort* lin_next = (l + 1 < LAY) ? linT + (size_t)(l + 1) * 16384 : nullptr;
        k_update<<<gblk, 512, 0, stream>>>(
            agg, v1T + (size_t)l * 16384, v1_b + (size_t)l * 128,
            v2T + (size_t)l * 16384, v2_b + (size_t)l * 128,
            v16, lin_next, vlin, N);
    }

    // -------- fused readout --------
    hipMemsetAsync(d_out, 0, (size_t)out_size * 4, stream);
    k_uout<<<gblk, 256, 0, stream>>>(v16, u1_w, u1_b, u2_w, u2_b, batch, (float*)d_out, N);
}

// Round 18
// 638.875 us; speedup vs baseline: 1.5194x; 1.0241x over previous
//
#include <hip/hip_runtime.h>
#include <hip/hip_fp16.h>
#include <math.h>

#define DEV __device__ __forceinline__

constexpr int NGAUSS = 50;
constexpr int LAY = 6;
constexpr int K_TAB = 16384;                           // nearest-neighbor table
constexpr float DMAX = 40.0f;
constexpr float TSCALE = (float)(K_TAB - 1) / DMAX;    // knot = round(d * TSCALE)
constexpr float STEP = 6.0f / 49.0f;
constexpr float COEFF = -0.5f / (STEP * STEP);
constexpr float LN2F = 0.69314718055994531f;
constexpr float PI_OVER_CUT = 0.52359877559829887f;    // pi/6

using f16x8 = __attribute__((ext_vector_type(8))) _Float16;
using f16x4 = __attribute__((ext_vector_type(4))) _Float16;
using f32x4 = __attribute__((ext_vector_type(4))) float;
using f32x8 = __attribute__((ext_vector_type(8))) float;

#define MFMA16(a, b, c) __builtin_amdgcn_mfma_f32_16x16x32_f16(a, b, c, 0, 0, 0)

DEV float sspf(float x) {
    float ax = fabsf(x);
    float e = __expf(-ax);
    return fmaxf(x, 0.f) + __logf(1.f + e) - LN2F;
}

// ---- fp16 pack/unpack helpers (storage fp16, math f32) ----
DEV float4 ld_h4(const ushort* p) {          // 8B load -> 4 floats
    uint2 r = *(const uint2*)p;
    __half2 a = __builtin_bit_cast(__half2, r.x);
    __half2 b = __builtin_bit_cast(__half2, r.y);
    float2 fa = __half22float2(a), fb = __half22float2(b);
    return make_float4(fa.x, fa.y, fb.x, fb.y);
}
DEV void st_h4(ushort* p, float4 v) {        // 4 floats -> 8B store
    uint2 r;
    r.x = __builtin_bit_cast(uint, __float22half2_rn(make_float2(v.x, v.y)));
    r.y = __builtin_bit_cast(uint, __float22half2_rn(make_float2(v.z, v.w)));
    *(uint2*)p = r;
}

// ---------------- weight convert+transpose (fp32 [K][C] -> fp16 [C][K]) ----------------
__global__ void k_cvtT128(const float* __restrict__ src, ushort* __restrict__ dst) {
    const float* s = src + (size_t)blockIdx.x * 16384;
    ushort* d = dst + (size_t)blockIdx.x * 16384;
    for (int i = threadIdx.x; i < 16384; i += 256) {
        int k = i >> 7, c = i & 127;
        d[(c << 7) + k] = __builtin_bit_cast(ushort, (_Float16)s[i]);
    }
}
__global__ void k_cvtT_fe(const float* __restrict__ src, ushort* __restrict__ dst) {
    // fe_w2: [64][128] -> dst[c(128)][k(64)]
    for (int i = threadIdx.x; i < 8192; i += 256) {
        int k = i >> 7, c = i & 127;
        dst[(c << 6) + k] = __builtin_bit_cast(ushort, (_Float16)src[i]);
    }
}

// ---------------- edge sort pre-pass (once per call) ----------------
__global__ void k_hist(const int* __restrict__ ei, int* __restrict__ counts, int E) {
    int e = blockIdx.x * 256 + threadIdx.x;
    if (e < E) atomicAdd(&counts[ei[E + e]], 1);
}

__global__ void k_scan1(const int* __restrict__ counts, int* __restrict__ locex,
                        int* __restrict__ bsum, int n) {
    __shared__ int s_wsum[16];
    const int tid = threadIdx.x;
    const int i = blockIdx.x * 1024 + tid;
    const int lane = tid & 63, wv = tid >> 6;
    int v = (i < n) ? counts[i] : 0;
    int x = v;
    #pragma unroll
    for (int off = 1; off < 64; off <<= 1) {
        int y = __shfl_up(x, off, 64);
        if (lane >= off) x += y;
    }
    if (lane == 63) s_wsum[wv] = x;
    __syncthreads();
    if (wv == 0 && lane < 16) {
        int wval = s_wsum[lane];
        int wx = wval;
        #pragma unroll
        for (int off = 1; off < 16; off <<= 1) {
            int wy = __shfl_up(wx, off, 16);
            if (lane >= off) wx += wy;
        }
        s_wsum[lane] = wx - wval;
    }
    __syncthreads();
    if (i < n) locex[i] = s_wsum[wv] + x - v;
    if (tid == 1023) bsum[blockIdx.x] = s_wsum[15] + x;
}

__global__ void k_scan2(int* __restrict__ bsum, int nb) {
    __shared__ int s_wsum[16];
    const int tid = threadIdx.x;
    const int lane = tid & 63, wv = tid >> 6;
    int v = (tid < nb) ? bsum[tid] : 0;
    int x = v;
    #pragma unroll
    for (int off = 1; off < 64; off <<= 1) {
        int y = __shfl_up(x, off, 64);
        if (lane >= off) x += y;
    }
    if (lane == 63) s_wsum[wv] = x;
    __syncthreads();
    if (wv == 0 && lane < 16) {
        int wval = s_wsum[lane];
        int wx = wval;
        #pragma unroll
        for (int off = 1; off < 16; off <<= 1) {
            int wy = __shfl_up(wx, off, 16);
            if (lane >= off) wx += wy;
        }
        s_wsum[lane] = wx - wval;
    }
    __syncthreads();
    if (tid < nb) bsum[tid] = s_wsum[wv] + x - v;
}

__global__ void k_scan3(const int* __restrict__ locex, const int* __restrict__ bsumex,
                        int* __restrict__ cursor, int* __restrict__ rowptr, int n) {
    int i = blockIdx.x * 256 + threadIdx.x;
    if (i >= n) return;
    int e = locex[i] + bsumex[i >> 10];
    cursor[i] = e;
    rowptr[i] = e;
}

// scatter: one 4B store per edge, packed {src(16b) | knot(14b)<<16}
// NOTE: requires N < 65536 (N = 50000 here) and K_TAB <= 65536.
__global__ void k_scatter(const int* __restrict__ ei, const float* __restrict__ pos,
                          int* __restrict__ cursor, uint* __restrict__ s_ef, int E) {
    int e = blockIdx.x * 256 + threadIdx.x;
    if (e >= E) return;
    int r = ei[e], c = ei[E + e];
    int p = atomicAdd(&cursor[c], 1);
    float dx = pos[3 * r + 0] - pos[3 * c + 0];
    float dy = pos[3 * r + 1] - pos[3 * c + 1];
    float dz = pos[3 * r + 2] - pos[3 * c + 2];
    float d = sqrtf(dx * dx + dy * dy + dz * dz);
    int i0 = (int)(d * TSCALE + 0.5f);
    if (i0 > K_TAB - 1) i0 = K_TAB - 1;
    s_ef[p] = (uint)r | ((uint)i0 << 16);
}

// ---------------- gate table build: fp32 GEMM1 + MFMA GEMM2 ----------------
// 32 knots per block; grid = LAY * (K_TAB/32)
__launch_bounds__(256)
__global__ void k_tab_all(const float* __restrict__ w1A, const float* __restrict__ b1A,
                          const ushort* __restrict__ w2TA, const float* __restrict__ b2A,
                          ushort* __restrict__ tabA) {
    const int layer = blockIdx.x / (K_TAB / 32);
    const int k0 = (blockIdx.x % (K_TAB / 32)) * 32;
    const float* w1 = w1A + (size_t)layer * NGAUSS * 128;
    const float* b1 = b1A + (size_t)layer * 128;
    const ushort* w2T = w2TA + (size_t)layer * 16384;
    const float* b2 = b2A + (size_t)layer * 128;
    ushort* tab = tabA + (size_t)layer * K_TAB * 128;

    constexpr int LDP = 136;
    __shared__ float s_demb[32][NGAUSS];     // 6.4 KB
    __shared__ _Float16 sT[32 * LDP];        // 8.7 KB
    const int tid = threadIdx.x;

    for (int i = tid; i < 32 * NGAUSS; i += 256) {
        int r = i / NGAUSS, g = i - r * NGAUSS;
        float d = (float)(k0 + r) * (1.0f / TSCALE);
        float t = d - g * STEP;
        s_demb[r][g] = __expf(COEFF * t * t);
    }
    __syncthreads();

    // GEMM1 (fp32): t1 = ssp(demb @ w1 + b1), store fp16 to sT
    {
        const int cg = tid & 31, rg = tid >> 5;
        const int r0 = rg << 2;
        const int c4 = cg << 2;
        float4 b1v = *(const float4*)&b1[c4];
        float4 acc[4];
        #pragma unroll
        for (int i = 0; i < 4; i++) acc[i] = b1v;
        #pragma unroll 2
        for (int k = 0; k < NGAUSS; k++) {
            float4 wv = *(const float4*)&w1[(k << 7) + c4];
            #pragma unroll
            for (int i = 0; i < 4; i++) {
                float dv = s_demb[r0 + i][k];
                acc[i].x = fmaf(dv, wv.x, acc[i].x);
                acc[i].y = fmaf(dv, wv.y, acc[i].y);
                acc[i].z = fmaf(dv, wv.z, acc[i].z);
                acc[i].w = fmaf(dv, wv.w, acc[i].w);
            }
        }
        #pragma unroll
        for (int i = 0; i < 4; i++) {
            f16x4 t;
            t[0] = (_Float16)sspf(acc[i].x);
            t[1] = (_Float16)sspf(acc[i].y);
            t[2] = (_Float16)sspf(acc[i].z);
            t[3] = (_Float16)sspf(acc[i].w);
            *(f16x4*)&sT[(r0 + i) * LDP + c4] = t;
        }
    }
    __syncthreads();

    // GEMM2 (MFMA): W = t1 @ w2 + b2, x cosC -> tab (fp16)
    // 4 waves: wave owns col-tiles {2w, 2w+1}; row-tiles rt in {0,1}
    const int wid = tid >> 6, lane = tid & 63;
    const int lr = lane & 15, lg = lane >> 4;
    const int kof = lg << 3;

    #pragma unroll
    for (int cb = 0; cb < 2; cb++) {
        const int col = ((2 * wid + cb) << 4) + lr;
        const ushort* bp = w2T + ((size_t)col << 7);
        f16x8 B0 = *(const f16x8*)(bp + kof);
        f16x8 B1 = *(const f16x8*)(bp + 32 + kof);
        f16x8 B2 = *(const f16x8*)(bp + 64 + kof);
        f16x8 B3 = *(const f16x8*)(bp + 96 + kof);
        float bb = b2[col];
        #pragma unroll
        for (int rt = 0; rt < 2; rt++) {
            const _Float16* ap = &sT[((rt << 4) + lr) * LDP + kof];
            f32x4 c = {0.f, 0.f, 0.f, 0.f};
            c = MFMA16(*(const f16x8*)ap, B0, c);
            c = MFMA16(*(const f16x8*)(ap + 32), B1, c);
            c = MFMA16(*(const f16x8*)(ap + 64), B2, c);
            c = MFMA16(*(const f16x8*)(ap + 96), B3, c);
            #pragma unroll
            for (int r = 0; r < 4; r++) {
                int knot = k0 + (rt << 4) + (lg << 2) + r;
                float d = (float)knot * (1.0f / TSCALE);
                float cc = 0.5f * (__cosf(d * PI_OVER_CUT) + 1.0f);
                tab[((size_t)knot << 7) + col] =
                    __builtin_bit_cast(ushort, (_Float16)((c[r] + bb) * cc));
            }
        }
    }
}

// ---------------- node-centric CSR edge kernel: NN table, 16 lanes/edge, 2 edges in flight ----------------
__launch_bounds__(256, 8)
__global__ void k_edge_csr(const uint* __restrict__ s_ef,
                           const int* __restrict__ rowptr, const int* __restrict__ counts,
                           const ushort* __restrict__ vlin, const ushort* __restrict__ tab,
                           ushort* __restrict__ agg, int N) {
    const int tid = threadIdx.x;
    const int l32 = tid & 31;
    const int h = l32 >> 4;          // 0/1: edge parity this lane handles
    const int lc = l32 & 15;         // channel octet: channels 8lc..8lc+7
    const int n = blockIdx.x * 8 + (tid >> 5);
    if (n >= N) return;
    const ushort* tabc = tab + (lc << 3);
    const ushort* vlc  = vlin + (lc << 3);

    const int rs = rowptr[n];
    const int re = rs + counts[n];
    f32x8 acc = {0.f, 0.f, 0.f, 0.f, 0.f, 0.f, 0.f, 0.f};

    int e = rs + h;
    for (; e + 6 < re; e += 8) {
        f16x8 TP[4], VL[4];
        #pragma unroll
        for (int j = 0; j < 4; j++) {
            uint pk = s_ef[e + 2 * j];
            TP[j] = *(const f16x8*)(tabc + ((size_t)(pk >> 16) << 7));
            VL[j] = *(const f16x8*)(vlc + ((size_t)(pk & 0xFFFFu) << 7));
        }
        f16x8 p0 = TP[0] * VL[0];
        p0 += TP[1] * VL[1];
        f16x8 p1 = TP[2] * VL[2];
        p1 += TP[3] * VL[3];
        acc += __builtin_convertvector(p0, f32x8);
        acc += __builtin_convertvector(p1, f32x8);
    }
    for (; e < re; e += 2) {
        uint pk = s_ef[e];
        f16x8 tp = *(const f16x8*)(tabc + ((size_t)(pk >> 16) << 7));
        f16x8 vl = *(const f16x8*)(vlc + ((size_t)(pk & 0xFFFFu) << 7));
        acc += __builtin_convertvector(tp * vl, f32x8);
    }
    #pragma unroll
    for (int i = 0; i < 8; i++) acc[i] += __shfl_xor(acc[i], 16);
    if (h == 0) {
        f16x8 o;
        #pragma unroll
        for (int i = 0; i < 8; i++) o[i] = (_Float16)acc[i];
        *(f16x8*)&agg[((size_t)n << 7) + (lc << 3)] = o;
    }
}

// ---------------- feature embedding ----------------
__global__ void k_fe1(const float* __restrict__ x, const float* __restrict__ w,
                      const float* __restrict__ b, float* __restrict__ h, int N) {
    int idx = blockIdx.x * 256 + threadIdx.x;
    if (idx >= N * 64) return;
    int n = idx >> 6, c = idx & 63;
    const float* xr = x + (size_t)n * 28;
    float acc = b[c];
    #pragma unroll
    for (int k = 0; k < 28; k++) acc = fmaf(xr[k], w[k * 64 + c], acc);
    h[idx] = acc;
}

__global__ void k_bnstat(const float* __restrict__ h, float* __restrict__ stats, int N) {
    __shared__ float s_s[256], s_q[256];
    int tid = threadIdx.x;
    int c = tid & 63, g = tid >> 6;
    float s = 0.f, q = 0.f;
    for (int n = blockIdx.x * 4 + g; n < N; n += gridDim.x * 4) {
        float v = h[(size_t)n * 64 + c];
        s += v; q += v * v;
    }
    s_s[tid] = s; s_q[tid] = q;
    __syncthreads();
    if (tid < 64) {
        s = s_s[tid] + s_s[tid + 64] + s_s[tid + 128] + s_s[tid + 192];
        q = s_q[tid] + s_q[tid + 64] + s_q[tid + 128] + s_q[tid + 192];
        atomicAdd(&stats[tid], s);
        atomicAdd(&stats[64 + tid], q);
    }
}

__global__ void k_bnfin(const float* __restrict__ stats, float* __restrict__ prm,
                        const float* __restrict__ gamma, const float* __restrict__ beta,
                        float invN) {
    int c = threadIdx.x;  // 64 threads
    float mu = stats[c] * invN;
    float var = stats[64 + c] * invN - mu * mu;
    float sc = gamma[c] * rsqrtf(var + 1e-5f);
    prm[c] = sc;
    prm[64 + c] = beta[c] - mu * sc;
}

// ---------------- MFMA fe2: v16 = relu( relu(bn(h)) @ fe_w2 + b2 ), K=64 ----------------
__launch_bounds__(256, 4)
__global__ void k_fe2(const float* __restrict__ h, const float* __restrict__ prm,
                      const ushort* __restrict__ w2T, const float* __restrict__ b2,
                      ushort* __restrict__ v16, int N) {
    constexpr int LDP = 72;
    __shared__ _Float16 sH[64 * LDP];
    const int tid = threadIdx.x;
    const int n0 = blockIdx.x * 64;

    for (int i = tid; i < 64 * 16; i += 256) {
        int row = i >> 4, c4 = (i & 15) << 2;
        int gr = n0 + row;
        float4 hv = (gr < N) ? *(const float4*)&h[((size_t)gr << 6) + c4]
                             : make_float4(0.f, 0.f, 0.f, 0.f);
        float4 sc = *(const float4*)&prm[c4];
        float4 sh = *(const float4*)&prm[64 + c4];
        f16x4 o;
        o[0] = (_Float16)fmaxf(fmaf(hv.x, sc.x, sh.x), 0.f);
        o[1] = (_Float16)fmaxf(fmaf(hv.y, sc.y, sh.y), 0.f);
        o[2] = (_Float16)fmaxf(fmaf(hv.z, sc.z, sh.z), 0.f);
        o[3] = (_Float16)fmaxf(fmaf(hv.w, sc.w, sh.w), 0.f);
        *(f16x4*)&sH[row * LDP + c4] = o;
    }
    __syncthreads();

    const int wid = tid >> 6, lane = tid & 63;
    const int lr = lane & 15, lg = lane >> 4;
    const int kof = lg << 3;
    const int arow = wid * 16 + lr;
    const int drow0 = wid * 16 + (lg << 2);

    f16x8 a0 = *(const f16x8*)&sH[arow * LDP + kof];
    f16x8 a1 = *(const f16x8*)&sH[arow * LDP + 32 + kof];

    #pragma unroll
    for (int n = 0; n < 8; n++) {
        const ushort* bp = w2T + (((size_t)(n << 4) + lr) << 6);
        f32x4 c = {0.f, 0.f, 0.f, 0.f};
        c = MFMA16(a0, *(const f16x8*)(bp + kof), c);
        c = MFMA16(a1, *(const f16x8*)(bp + 32 + kof), c);
        int col = (n << 4) + lr;
        float bb = b2[col];
        #pragma unroll
        for (int r = 0; r < 4; r++) {
            int gr = n0 + drow0 + r;
            if (gr < N) v16[((size_t)gr << 7) + col] =
                __builtin_bit_cast(ushort, (_Float16)fmaxf(c[r] + bb, 0.f));
        }
    }
}

// ---------------- MFMA single GEMM: vlin(fp16) = v16 @ lin, K=128 ----------------
__launch_bounds__(256, 4)
__global__ void k_gemm_rb(const ushort* __restrict__ A, const ushort* __restrict__ wT,
                          ushort* __restrict__ C, int N) {
    constexpr int LDP = 136;
    __shared__ _Float16 sA[64 * LDP];
    const int tid = threadIdx.x;
    const int n0 = blockIdx.x * 64;

    for (int i = tid; i < 64 * 32; i += 256) {
        int row = i >> 5, c4 = (i & 31) << 2;
        int gr = n0 + row;
        uint2 val = (gr < N) ? *(const uint2*)&A[((size_t)gr << 7) + c4]
                             : make_uint2(0u, 0u);
        *(uint2*)&sA[row * LDP + c4] = val;
    }
    __syncthreads();

    const int wid = tid >> 6, lane = tid & 63;
    const int lr = lane & 15, lg = lane >> 4;
    const int kof = lg << 3;
    const int arow = wid * 16 + lr;
    const int drow0 = wid * 16 + (lg << 2);

    f16x8 a0 = *(const f16x8*)&sA[arow * LDP + kof];
    f16x8 a1 = *(const f16x8*)&sA[arow * LDP + 32 + kof];
    f16x8 a2 = *(const f16x8*)&sA[arow * LDP + 64 + kof];
    f16x8 a3 = *(const f16x8*)&sA[arow * LDP + 96 + kof];

    #pragma unroll
    for (int n = 0; n < 8; n++) {
        const ushort* bp = wT + (((size_t)(n << 4) + lr) << 7);
        f32x4 c = {0.f, 0.f, 0.f, 0.f};
        c = MFMA16(a0, *(const f16x8*)(bp + kof), c);
        c = MFMA16(a1, *(const f16x8*)(bp + 32 + kof), c);
        c = MFMA16(a2, *(const f16x8*)(bp + 64 + kof), c);
        c = MFMA16(a3, *(const f16x8*)(bp + 96 + kof), c);
        int col = (n << 4) + lr;
        #pragma unroll
        for (int r = 0; r < 4; r++) {
            int gr = n0 + drow0 + r;
            if (gr < N) C[((size_t)gr << 7) + col] =
                __builtin_bit_cast(ushort, (_Float16)c[r]);
        }
    }
}

// ---------------- MFMA fused layer update: 1 wave per 16-col block ----------------
__launch_bounds__(512, 8)
__global__ void k_update(const ushort* __restrict__ agg,
                         const ushort* __restrict__ w1T, const float* __restrict__ b1,
                         const ushort* __restrict__ w2T, const float* __restrict__ b2,
                         ushort* __restrict__ v16,
                         const ushort* __restrict__ linT, ushort* __restrict__ vlin, int N) {
    constexpr int LDP = 136;
    __shared__ _Float16 sA[64 * LDP];   // 17.4 KB
    __shared__ _Float16 sB[64 * LDP];   // 17.4 KB
    const int tid = threadIdx.x;
    const int n0 = blockIdx.x * 64;

    for (int i = tid; i < 64 * 32; i += 512) {
        int row = i >> 5, c4 = (i & 31) << 2;
        int gr = n0 + row;
        uint2 a = (gr < N) ? *(const uint2*)&agg[((size_t)gr << 7) + c4] : make_uint2(0u, 0u);
        uint2 b = (gr < N) ? *(const uint2*)&v16[((size_t)gr << 7) + c4] : make_uint2(0u, 0u);
        *(uint2*)&sA[row * LDP + c4] = a;
        *(uint2*)&sB[row * LDP + c4] = b;
    }
    __syncthreads();

    const int wid = tid >> 6, lane = tid & 63;
    const int lr = lane & 15, lg = lane >> 4;
    const int kof = lg << 3;
    const int col = (wid << 4) + lr;
    const int dr0 = lg << 2;

    f32x4 acc[4];

    // ---- GEMM 1: t = ssp(agg @ W1 + b1) ----
    {
        const ushort* bp = w1T + ((size_t)col << 7);
        f16x8 B0 = *(const f16x8*)(bp + kof);
        f16x8 B1 = *(const f16x8*)(bp + 32 + kof);
        f16x8 B2 = *(const f16x8*)(bp + 64 + kof);
        f16x8 B3 = *(const f16x8*)(bp + 96 + kof);
        #pragma unroll
        for (int rb = 0; rb < 4; rb++) {
            const _Float16* ap = &sA[((rb << 4) + lr) * LDP + kof];
            f32x4 c = {0.f, 0.f, 0.f, 0.f};
            c = MFMA16(*(const f16x8*)ap, B0, c);
            c = MFMA16(*(const f16x8*)(ap + 32), B1, c);
            c = MFMA16(*(const f16x8*)(ap + 64), B2, c);
            c = MFMA16(*(const f16x8*)(ap + 96), B3, c);
            acc[rb] = c;
        }
    }
    __syncthreads();
    {
        float bb = b1[col];
        #pragma unroll
        for (int rb = 0; rb < 4; rb++) {
            #pragma unroll
            for (int r = 0; r < 4; r++)
                sA[((rb << 4) + dr0 + r) * LDP + col] = (_Float16)sspf(acc[rb][r] + bb);
        }
    }
    __syncthreads();

    // ---- GEMM 2: v_new = t @ W2 + b2 + v_old ----
    {
        const ushort* bp = w2T + ((size_t)col << 7);
        f16x8 B0 = *(const f16x8*)(bp + kof);
        f16x8 B1 = *(const f16x8*)(bp + 32 + kof);
        f16x8 B2 = *(const f16x8*)(bp + 64 + kof);
        f16x8 B3 = *(const f16x8*)(bp + 96 + kof);
        #pragma unroll
        for (int rb = 0; rb < 4; rb++) {
            const _Float16* ap = &sA[((rb << 4) + lr) * LDP + kof];
            f32x4 c = {0.f, 0.f, 0.f, 0.f};
            c = MFMA16(*(const f16x8*)ap, B0, c);
            c = MFMA16(*(const f16x8*)(ap + 32), B1, c);
            c = MFMA16(*(const f16x8*)(ap + 64), B2, c);
            c = MFMA16(*(const f16x8*)(ap + 96), B3, c);
            acc[rb] = c;
        }
    }
    {
        float bb = b2[col];
        #pragma unroll
        for (int rb = 0; rb < 4; rb++) {
            #pragma unroll
            for (int r = 0; r < 4; r++) {
                _Float16* p = &sB[((rb << 4) + dr0 + r) * LDP + col];
                *p = (_Float16)(acc[rb][r] + bb + (float)*p);
            }
        }
    }
    __syncthreads();

    for (int i = tid; i < 64 * 32; i += 512) {
        int row = i >> 5, c4 = (i & 31) << 2;
        int gr = n0 + row;
        if (gr < N) *(uint2*)&v16[((size_t)gr << 7) + c4] = *(const uint2*)&sB[row * LDP + c4];
    }
    if (!linT) return;

    // ---- GEMM 3: vlin = v_new @ lin ----
    {
        const ushort* bp = linT + ((size_t)col << 7);
        f16x8 B0 = *(const f16x8*)(bp + kof);
        f16x8 B1 = *(const f16x8*)(bp + 32 + kof);
        f16x8 B2 = *(const f16x8*)(bp + 64 + kof);
        f16x8 B3 = *(const f16x8*)(bp + 96 + kof);
        #pragma unroll
        for (int rb = 0; rb < 4; rb++) {
            const _Float16* ap = &sB[((rb << 4) + lr) * LDP + kof];
            f32x4 c = {0.f, 0.f, 0.f, 0.f};
            c = MFMA16(*(const f16x8*)ap, B0, c);
            c = MFMA16(*(const f16x8*)(ap + 32), B1, c);
            c = MFMA16(*(const f16x8*)(ap + 64), B2, c);
            c = MFMA16(*(const f16x8*)(ap + 96), B3, c);
            acc[rb] = c;
        }
    }
    #pragma unroll
    for (int rb = 0; rb < 4; rb++) {
        #pragma unroll
        for (int r = 0; r < 4; r++)
            sA[((rb << 4) + dr0 + r) * LDP + col] = (_Float16)acc[rb][r];
    }
    __syncthreads();

    for (int i = tid; i < 64 * 32; i += 512) {
        int row = i >> 5, c4 = (i & 31) << 2;
        int gr = n0 + row;
        if (gr < N) *(uint2*)&vlin[((size_t)gr << 7) + c4] = *(const uint2*)&sA[row * LDP + c4];
    }
}

// ---------------- tiled fused readout (v16 input) ----------------
__launch_bounds__(256, 4)
__global__ void k_uout(const ushort* __restrict__ v16, const float* __restrict__ u1w,
                       const float* __restrict__ u1b, const float* __restrict__ u2w,
                       const float* __restrict__ u2b, const int* __restrict__ batch,
                       float* __restrict__ out, int N) {
    __shared__ float sA[64 * 128];
    const int tid = threadIdx.x;
    const int n0 = blockIdx.x * 64;

    for (int i = tid; i < 64 * 32; i += 256) {
        int row = i >> 5, cq = (i & 31) << 2;
        int gr = n0 + row;
        float4 val = make_float4(0.f, 0.f, 0.f, 0.f);
        if (gr < N) val = ld_h4(&v16[((size_t)gr << 7) + cq]);
        *(float4*)&sA[row * 128 + cq] = val;
    }
    __syncthreads();

    const int cg = tid & 31, rg = tid >> 5;
    const int r0 = rg << 3;
    const int c2 = cg << 1;

    float2 acc[8];
    {
        float2 b1v = *(const float2*)&u1b[c2];
        #pragma unroll
        for (int i = 0; i < 8; i++) acc[i] = b1v;
        #pragma unroll 4
        for (int k = 0; k < 128; k++) {
            float2 wv = *(const float2*)&u1w[(k << 6) + c2];
            #pragma unroll
            for (int i = 0; i < 8; i++) {
                float a = sA[(r0 + i) * 128 + k];
                acc[i].x = fmaf(a, wv.x, acc[i].x);
                acc[i].y = fmaf(a, wv.y, acc[i].y);
            }
        }
    }
    __syncthreads();
    #pragma unroll
    for (int i = 0; i < 8; i++) {
        sA[(r0 + i) * 64 + c2 + 0] = sspf(acc[i].x);
        sA[(r0 + i) * 64 + c2 + 1] = sspf(acc[i].y);
    }
    __syncthreads();

    float acc2[8];
    {
        float bb = u2b[cg];
        #pragma unroll
        for (int i = 0; i < 8; i++) acc2[i] = bb;
        #pragma unroll 4
        for (int k = 0; k < 64; k++) {
            float wv = u2w[(k << 5) + cg];
            #pragma unroll
            for (int i = 0; i < 8; i++)
                acc2[i] = fmaf(sA[(r0 + i) * 64 + k], wv, acc2[i]);
        }
    }

    int cur = -1;
    float run = 0.f;
    #pragma unroll
    for (int i = 0; i < 8; i++) {
        int gr = n0 + r0 + i;
        int g = (gr < N) ? batch[gr] : -1;
        if (g != cur) {
            if (cur >= 0) atomicAdd(&out[(size_t)cur * 32 + cg], run);
            cur = g;
            run = 0.f;
        }
        if (g >= 0) run += acc2[i];
    }
    if (cur >= 0) atomicAdd(&out[(size_t)cur * 32 + cg], run);
}

extern "C" void kernel_launch(void* const* d_in, const int* in_sizes, int n_in,
                              void* d_out, int out_size, void* d_ws, size_t ws_size,
                              hipStream_t stream) {
    const float* x      = (const float*)d_in[0];
    const float* pos    = (const float*)d_in[1];
    const int*   batch  = (const int*)d_in[2];
    const int*   ei     = (const int*)d_in[3];
    const float* fe_w1  = (const float*)d_in[4];
    const float* fe_b1  = (const float*)d_in[5];
    const float* bn_g   = (const float*)d_in[6];
    const float* bn_b   = (const float*)d_in[7];
    const float* fe_w2  = (const float*)d_in[8];
    const float* fe_b2  = (const float*)d_in[9];
    const float* lin_w  = (const float*)d_in[10];
    const float* mlp_w1 = (const float*)d_in[11];
    const float* mlp_b1 = (const float*)d_in[12];
    const float* mlp_w2 = (const float*)d_in[13];
    const float* mlp_b2 = (const float*)d_in[14];
    const float* v1_w   = (const float*)d_in[15];
    const float* v1_b   = (const float*)d_in[16];
    const float* v2_w   = (const float*)d_in[17];
    const float* v2_b   = (const float*)d_in[18];
    const float* u1_w   = (const float*)d_in[19];
    const float* u1_b   = (const float*)d_in[20];
    const float* u2_w   = (const float*)d_in[21];
    const float* u2_b   = (const float*)d_in[22];

    const int N = in_sizes[0] / 28;
    const int E = in_sizes[3] / 2;
    const int NB1 = (N + 1023) / 1024;

    char* ws = (char*)d_ws;
    size_t o = 0;
    auto alloc = [&](size_t bytes) { void* p = ws + o; o += (bytes + 255) & ~(size_t)255; return p; };
    int*    counts = (int*)   alloc((size_t)N * 4);
    int*    cursor = (int*)   alloc((size_t)N * 4);
    int*    rowptr = (int*)   alloc((size_t)N * 4);
    int*    bsum   = (int*)   alloc((size_t)NB1 * 4);
    uint*   s_ef   = (uint*)  alloc((size_t)E * 4);
    float*  stats  = (float*) alloc(128 * 4);
    float*  prm    = (float*) alloc(128 * 4);
    ushort* tab    = (ushort*)alloc((size_t)LAY * K_TAB * 128 * 2);  // 25 MB fp16 (NN)
    ushort* v16    = (ushort*)alloc((size_t)N * 128 * 2);            // fp16 node state
    ushort* vlin   = (ushort*)alloc((size_t)N * 128 * 2);            // fp16
    ushort* agg    = (ushort*)alloc((size_t)N * 128 * 2);            // fp16
    float*  h      = (float*) alloc((size_t)N * 64 * 4);
    int*    locex  = (int*)   alloc((size_t)N * 4);
    ushort* v1T    = (ushort*)alloc((size_t)LAY * 16384 * 2);   // fp16 transposed weights
    ushort* v2T    = (ushort*)alloc((size_t)LAY * 16384 * 2);
    ushort* linT   = (ushort*)alloc((size_t)LAY * 16384 * 2);
    ushort* mw2T   = (ushort*)alloc((size_t)LAY * 16384 * 2);   // mlp_w2 fp16 [c][k]
    ushort* fe2T   = (ushort*)alloc((size_t)8192 * 2);

    // -------- weight conversion (fp16, transposed) --------
    k_cvtT128<<<LAY, 256, 0, stream>>>(v1_w, v1T);
    k_cvtT128<<<LAY, 256, 0, stream>>>(v2_w, v2T);
    k_cvtT128<<<LAY, 256, 0, stream>>>(lin_w, linT);
    k_cvtT128<<<LAY, 256, 0, stream>>>(mlp_w2, mw2T);
    k_cvtT_fe<<<1, 256, 0, stream>>>(fe_w2, fe2T);

    // -------- one-time edge sort (dst-ordered CSR) --------
    hipMemsetAsync(counts, 0, (size_t)N * 4, stream);
    k_hist<<<(E + 255) / 256, 256, 0, stream>>>(ei, counts, E);
    k_scan1<<<NB1, 1024, 0, stream>>>(counts, locex, bsum, N);
    k_scan2<<<1, 1024, 0, stream>>>(bsum, NB1);
    k_scan3<<<(N + 255) / 256, 256, 0, stream>>>(locex, bsum, cursor, rowptr, N);
    k_scatter<<<(E + 255) / 256, 256, 0, stream>>>(ei, pos, cursor, s_ef, E);

    // -------- gate tables (fp16, nearest-neighbor, MFMA GEMM2) --------
    k_tab_all<<<LAY * (K_TAB / 32), 256, 0, stream>>>(mlp_w1, mlp_b1, mw2T, mlp_b2, tab);

    // -------- feature embedding --------
    hipMemsetAsync(stats, 0, 128 * 4, stream);
    k_fe1<<<(N * 64 + 255) / 256, 256, 0, stream>>>(x, fe_w1, fe_b1, h, N);
    k_bnstat<<<256, 256, 0, stream>>>(h, stats, N);
    k_bnfin<<<1, 64, 0, stream>>>(stats, prm, bn_g, bn_b, 1.0f / (float)N);
    const int gblk = (N + 63) / 64;
    k_fe2<<<gblk, 256, 0, stream>>>(h, prm, fe2T, fe_b2, v16, N);

    // vlin for layer 0
    k_gemm_rb<<<gblk, 256, 0, stream>>>(v16, linT, vlin, N);

    // -------- interaction layers --------
    const int eblk = (N + 7) / 8;
    for (int l = 0; l < LAY; l++) {
        k_edge_csr<<<eblk, 256, 0, stream>>>(
            s_ef, rowptr, counts, vlin,
            tab + (size_t)l * K_TAB * 128, agg, N);
        const ushort* lin_next = (l + 1 < LAY) ? linT + (size_t)(l + 1) * 16384 : nullptr;
        k_update<<<gblk, 512, 0, stream>>>(
            agg, v1T + (size_t)l * 16384, v1_b + (size_t)l * 128,
            v2T + (size_t)l * 16384, v2_b + (size_t)l * 128,
            v16, lin_next, vlin, N);
    }

    // -------- fused readout --------
    hipMemsetAsync(d_out, 0, (size_t)out_size * 4, stream);
    k_uout<<<gblk, 256, 0, stream>>>(v16, u1_w, u1_b, u2_w, u2_b, batch, (float*)d_out, N);
}

// Round 19
// 601.448 us; speedup vs baseline: 1.6139x; 1.0622x over previous
//
#include <hip/hip_runtime.h>
#include <hip/hip_fp16.h>
#include <math.h>

#define DEV __device__ __forceinline__

constexpr int NGAUSS = 50;
constexpr int LAY = 6;
constexpr int K_TAB = 8192;                            // nearest-neighbor table
constexpr float DMAX = 40.0f;
constexpr float TSCALE = (float)(K_TAB - 1) / DMAX;    // knot = round(d * TSCALE)
constexpr float STEP = 6.0f / 49.0f;
constexpr float COEFF = -0.5f / (STEP * STEP);
constexpr float LN2F = 0.69314718055994531f;
constexpr float PI_OVER_CUT = 0.52359877559829887f;    // pi/6

using f16x8 = __attribute__((ext_vector_type(8))) _Float16;
using f16x4 = __attribute__((ext_vector_type(4))) _Float16;
using f32x4 = __attribute__((ext_vector_type(4))) float;
using f32x8 = __attribute__((ext_vector_type(8))) float;

#define MFMA16(a, b, c) __builtin_amdgcn_mfma_f32_16x16x32_f16(a, b, c, 0, 0, 0)

DEV float sspf(float x) {
    float ax = fabsf(x);
    float e = __expf(-ax);
    return fmaxf(x, 0.f) + __logf(1.f + e) - LN2F;
}

// ---- fp16 pack/unpack helpers (storage fp16, math f32) ----
DEV float4 ld_h4(const ushort* p) {          // 8B load -> 4 floats
    uint2 r = *(const uint2*)p;
    __half2 a = __builtin_bit_cast(__half2, r.x);
    __half2 b = __builtin_bit_cast(__half2, r.y);
    float2 fa = __half22float2(a), fb = __half22float2(b);
    return make_float4(fa.x, fa.y, fb.x, fb.y);
}

// ---------------- weight convert+transpose (fp32 [K][C] -> fp16 [C][K]) ----------------
__global__ void k_cvtT128(const float* __restrict__ src, ushort* __restrict__ dst) {
    const float* s = src + (size_t)blockIdx.x * 16384;
    ushort* d = dst + (size_t)blockIdx.x * 16384;
    for (int i = threadIdx.x; i < 16384; i += 256) {
        int k = i >> 7, c = i & 127;
        d[(c << 7) + k] = __builtin_bit_cast(ushort, (_Float16)s[i]);
    }
}
__global__ void k_cvtT_fe(const float* __restrict__ src, ushort* __restrict__ dst) {
    // fe_w2: [64][128] -> dst[c(128)][k(64)]
    for (int i = threadIdx.x; i < 8192; i += 256) {
        int k = i >> 7, c = i & 127;
        dst[(c << 6) + k] = __builtin_bit_cast(ushort, (_Float16)src[i]);
    }
}
__global__ void k_cvtT_w1(const float* __restrict__ src, ushort* __restrict__ dst) {
    // mlp_w1: [50][128] -> dst[c(128)][k(64)], zero-padded k>=50
    const float* s = src + (size_t)blockIdx.x * (NGAUSS * 128);
    ushort* d = dst + (size_t)blockIdx.x * (128 * 64);
    for (int i = threadIdx.x; i < 128 * 64; i += 256) {
        int c = i >> 6, k = i & 63;
        float v = (k < NGAUSS) ? s[k * 128 + c] : 0.f;
        d[(c << 6) + k] = __builtin_bit_cast(ushort, (_Float16)v);
    }
}

// ---------------- edge sort pre-pass (once per call) ----------------
__global__ void k_hist(const int* __restrict__ ei, int* __restrict__ counts, int E) {
    int e = blockIdx.x * 256 + threadIdx.x;
    if (e < E) atomicAdd(&counts[ei[E + e]], 1);
}

__global__ void k_scan1(const int* __restrict__ counts, int* __restrict__ locex,
                        int* __restrict__ bsum, int n) {
    __shared__ int s_wsum[16];
    const int tid = threadIdx.x;
    const int i = blockIdx.x * 1024 + tid;
    const int lane = tid & 63, wv = tid >> 6;
    int v = (i < n) ? counts[i] : 0;
    int x = v;
    #pragma unroll
    for (int off = 1; off < 64; off <<= 1) {
        int y = __shfl_up(x, off, 64);
        if (lane >= off) x += y;
    }
    if (lane == 63) s_wsum[wv] = x;
    __syncthreads();
    if (wv == 0 && lane < 16) {
        int wval = s_wsum[lane];
        int wx = wval;
        #pragma unroll
        for (int off = 1; off < 16; off <<= 1) {
            int wy = __shfl_up(wx, off, 16);
            if (lane >= off) wx += wy;
        }
        s_wsum[lane] = wx - wval;
    }
    __syncthreads();
    if (i < n) locex[i] = s_wsum[wv] + x - v;
    if (tid == 1023) bsum[blockIdx.x] = s_wsum[15] + x;
}

__global__ void k_scan2(int* __restrict__ bsum, int nb) {
    __shared__ int s_wsum[16];
    const int tid = threadIdx.x;
    const int lane = tid & 63, wv = tid >> 6;
    int v = (tid < nb) ? bsum[tid] : 0;
    int x = v;
    #pragma unroll
    for (int off = 1; off < 64; off <<= 1) {
        int y = __shfl_up(x, off, 64);
        if (lane >= off) x += y;
    }
    if (lane == 63) s_wsum[wv] = x;
    __syncthreads();
    if (wv == 0 && lane < 16) {
        int wval = s_wsum[lane];
        int wx = wval;
        #pragma unroll
        for (int off = 1; off < 16; off <<= 1) {
            int wy = __shfl_up(wx, off, 16);
            if (lane >= off) wx += wy;
        }
        s_wsum[lane] = wx - wval;
    }
    __syncthreads();
    if (tid < nb) bsum[tid] = s_wsum[wv] + x - v;
}

__global__ void k_scan3(const int* __restrict__ locex, const int* __restrict__ bsumex,
                        int* __restrict__ cursor, int* __restrict__ rowptr, int n) {
    int i = blockIdx.x * 256 + threadIdx.x;
    if (i >= n) return;
    int e = locex[i] + bsumex[i >> 10];
    cursor[i] = e;
    rowptr[i] = e;
}

// scatter: one 4B store per edge, packed {src(16b) | knot(13b)<<16}
__global__ void k_scatter(const int* __restrict__ ei, const float* __restrict__ pos,
                          int* __restrict__ cursor, uint* __restrict__ s_ef, int E) {
    int e = blockIdx.x * 256 + threadIdx.x;
    if (e >= E) return;
    int r = ei[e], c = ei[E + e];
    int p = atomicAdd(&cursor[c], 1);
    float dx = pos[3 * r + 0] - pos[3 * c + 0];
    float dy = pos[3 * r + 1] - pos[3 * c + 1];
    float dz = pos[3 * r + 2] - pos[3 * c + 2];
    float d = sqrtf(dx * dx + dy * dy + dz * dz);
    int i0 = (int)(d * TSCALE + 0.5f);
    if (i0 > K_TAB - 1) i0 = K_TAB - 1;
    s_ef[p] = (uint)r | ((uint)i0 << 16);
}

// ---------------- gate table build: all-MFMA ----------------
// 32 knots per block; grid = LAY * (K_TAB/32)
__launch_bounds__(256)
__global__ void k_tab_all(const ushort* __restrict__ w1TA, const float* __restrict__ b1A,
                          const ushort* __restrict__ w2TA, const float* __restrict__ b2A,
                          ushort* __restrict__ tabA) {
    const int layer = blockIdx.x / (K_TAB / 32);
    const int k0 = (blockIdx.x % (K_TAB / 32)) * 32;
    const ushort* w1T = w1TA + (size_t)layer * 8192;    // [128][64] fp16
    const float* b1 = b1A + (size_t)layer * 128;
    const ushort* w2T = w2TA + (size_t)layer * 16384;   // [128][128] fp16
    const float* b2 = b2A + (size_t)layer * 128;
    ushort* tab = tabA + (size_t)layer * K_TAB * 128;

    constexpr int LDD = 72;
    constexpr int LDP = 136;
    __shared__ _Float16 sD[32 * LDD];   // demb fp16, K padded to 64 (4.5 KB)
    __shared__ _Float16 sT[32 * LDP];   // t1 fp16 (8.7 KB)
    __shared__ float s_cc[32];
    const int tid = threadIdx.x;

    // stage: demb fp16 (zero-padded) + per-knot cosC
    for (int i = tid; i < 32 * 64; i += 256) {
        int r = i >> 6, g = i & 63;
        float val = 0.f;
        if (g < NGAUSS) {
            float d = (float)(k0 + r) * (1.0f / TSCALE);
            float t = d - g * STEP;
            val = __expf(COEFF * t * t);
        }
        sD[r * LDD + g] = (_Float16)val;
    }
    if (tid < 32) {
        float d = (float)(k0 + tid) * (1.0f / TSCALE);
        s_cc[tid] = 0.5f * (__cosf(d * PI_OVER_CUT) + 1.0f);
    }
    __syncthreads();

    const int wid = tid >> 6, lane = tid & 63;
    const int lr = lane & 15, lg = lane >> 4;
    const int kof = lg << 3;

    // GEMM1 (MFMA, K=64): t1 = ssp(demb @ w1 + b1) -> sT
    #pragma unroll
    for (int cb = 0; cb < 2; cb++) {
        const int col = ((2 * wid + cb) << 4) + lr;
        const ushort* bp = w1T + ((size_t)col << 6);
        f16x8 B0 = *(const f16x8*)(bp + kof);
        f16x8 B1 = *(const f16x8*)(bp + 32 + kof);
        float bb = b1[col];
        #pragma unroll
        for (int rt = 0; rt < 2; rt++) {
            const _Float16* ap = &sD[((rt << 4) + lr) * LDD + kof];
            f32x4 c = {0.f, 0.f, 0.f, 0.f};
            c = MFMA16(*(const f16x8*)ap, B0, c);
            c = MFMA16(*(const f16x8*)(ap + 32), B1, c);
            #pragma unroll
            for (int r = 0; r < 4; r++)
                sT[((rt << 4) + (lg << 2) + r) * LDP + col] = (_Float16)sspf(c[r] + bb);
        }
    }
    __syncthreads();

    // GEMM2 (MFMA, K=128): W = (t1 @ w2 + b2) * cosC -> tab
    #pragma unroll
    for (int cb = 0; cb < 2; cb++) {
        const int col = ((2 * wid + cb) << 4) + lr;
        const ushort* bp = w2T + ((size_t)col << 7);
        f16x8 B0 = *(const f16x8*)(bp + kof);
        f16x8 B1 = *(const f16x8*)(bp + 32 + kof);
        f16x8 B2 = *(const f16x8*)(bp + 64 + kof);
        f16x8 B3 = *(const f16x8*)(bp + 96 + kof);
        float bb = b2[col];
        #pragma unroll
        for (int rt = 0; rt < 2; rt++) {
            const _Float16* ap = &sT[((rt << 4) + lr) * LDP + kof];
            f32x4 c = {0.f, 0.f, 0.f, 0.f};
            c = MFMA16(*(const f16x8*)ap, B0, c);
            c = MFMA16(*(const f16x8*)(ap + 32), B1, c);
            c = MFMA16(*(const f16x8*)(ap + 64), B2, c);
            c = MFMA16(*(const f16x8*)(ap + 96), B3, c);
            #pragma unroll
            for (int r = 0; r < 4; r++) {
                int kr = (rt << 4) + (lg << 2) + r;
                tab[((size_t)(k0 + kr) << 7) + col] =
                    __builtin_bit_cast(ushort, (_Float16)((c[r] + bb) * s_cc[kr]));
            }
        }
    }
}

// ---------------- node-centric CSR edge kernel: NN table, 16 lanes/edge, 2 edges in flight ----------------
__launch_bounds__(256, 8)
__global__ void k_edge_csr(const uint* __restrict__ s_ef,
                           const int* __restrict__ rowptr, const int* __restrict__ counts,
                           const ushort* __restrict__ vlin, const ushort* __restrict__ tab,
                           ushort* __restrict__ agg, int N) {
    const int tid = threadIdx.x;
    const int l32 = tid & 31;
    const int h = l32 >> 4;          // 0/1: edge parity this lane handles
    const int lc = l32 & 15;         // channel octet: channels 8lc..8lc+7
    const int n = blockIdx.x * 8 + (tid >> 5);
    if (n >= N) return;
    const ushort* tabc = tab + (lc << 3);
    const ushort* vlc  = vlin + (lc << 3);

    const int rs = rowptr[n];
    const int re = rs + counts[n];
    f32x8 acc = {0.f, 0.f, 0.f, 0.f, 0.f, 0.f, 0.f, 0.f};

    int e = rs + h;
    for (; e + 6 < re; e += 8) {
        f16x8 TP[4], VL[4];
        #pragma unroll
        for (int j = 0; j < 4; j++) {
            uint pk = s_ef[e + 2 * j];
            TP[j] = *(const f16x8*)(tabc + ((size_t)(pk >> 16) << 7));
            VL[j] = *(const f16x8*)(vlc + ((size_t)(pk & 0xFFFFu) << 7));
        }
        f16x8 p0 = TP[0] * VL[0];
        p0 += TP[1] * VL[1];
        f16x8 p1 = TP[2] * VL[2];
        p1 += TP[3] * VL[3];
        acc += __builtin_convertvector(p0, f32x8);
        acc += __builtin_convertvector(p1, f32x8);
    }
    for (; e < re; e += 2) {
        uint pk = s_ef[e];
        f16x8 tp = *(const f16x8*)(tabc + ((size_t)(pk >> 16) << 7));
        f16x8 vl = *(const f16x8*)(vlc + ((size_t)(pk & 0xFFFFu) << 7));
        acc += __builtin_convertvector(tp * vl, f32x8);
    }
    #pragma unroll
    for (int i = 0; i < 8; i++) acc[i] += __shfl_xor(acc[i], 16);
    if (h == 0) {
        f16x8 o;
        #pragma unroll
        for (int i = 0; i < 8; i++) o[i] = (_Float16)acc[i];
        *(f16x8*)&agg[((size_t)n << 7) + (lc << 3)] = o;
    }
}

// ---------------- feature embedding ----------------
__global__ void k_fe1(const float* __restrict__ x, const float* __restrict__ w,
                      const float* __restrict__ b, float* __restrict__ h, int N) {
    int idx = blockIdx.x * 256 + threadIdx.x;
    if (idx >= N * 64) return;
    int n = idx >> 6, c = idx & 63;
    const float* xr = x + (size_t)n * 28;
    float acc = b[c];
    #pragma unroll
    for (int k = 0; k < 28; k++) acc = fmaf(xr[k], w[k * 64 + c], acc);
    h[idx] = acc;
}

__global__ void k_bnstat(const float* __restrict__ h, float* __restrict__ stats, int N) {
    __shared__ float s_s[256], s_q[256];
    int tid = threadIdx.x;
    int c = tid & 63, g = tid >> 6;
    float s = 0.f, q = 0.f;
    for (int n = blockIdx.x * 4 + g; n < N; n += gridDim.x * 4) {
        float v = h[(size_t)n * 64 + c];
        s += v; q += v * v;
    }
    s_s[tid] = s; s_q[tid] = q;
    __syncthreads();
    if (tid < 64) {
        s = s_s[tid] + s_s[tid + 64] + s_s[tid + 128] + s_s[tid + 192];
        q = s_q[tid] + s_q[tid + 64] + s_q[tid + 128] + s_q[tid + 192];
        atomicAdd(&stats[tid], s);
        atomicAdd(&stats[64 + tid], q);
    }
}

__global__ void k_bnfin(const float* __restrict__ stats, float* __restrict__ prm,
                        const float* __restrict__ gamma, const float* __restrict__ beta,
                        float invN) {
    int c = threadIdx.x;  // 64 threads
    float mu = stats[c] * invN;
    float var = stats[64 + c] * invN - mu * mu;
    float sc = gamma[c] * rsqrtf(var + 1e-5f);
    prm[c] = sc;
    prm[64 + c] = beta[c] - mu * sc;
}

// ---------------- MFMA fe2: v16 = relu( relu(bn(h)) @ fe_w2 + b2 ), K=64 ----------------
__launch_bounds__(256, 4)
__global__ void k_fe2(const float* __restrict__ h, const float* __restrict__ prm,
                      const ushort* __restrict__ w2T, const float* __restrict__ b2,
                      ushort* __restrict__ v16, int N) {
    constexpr int LDP = 72;
    __shared__ _Float16 sH[64 * LDP];
    const int tid = threadIdx.x;
    const int n0 = blockIdx.x * 64;

    for (int i = tid; i < 64 * 16; i += 256) {
        int row = i >> 4, c4 = (i & 15) << 2;
        int gr = n0 + row;
        float4 hv = (gr < N) ? *(const float4*)&h[((size_t)gr << 6) + c4]
                             : make_float4(0.f, 0.f, 0.f, 0.f);
        float4 sc = *(const float4*)&prm[c4];
        float4 sh = *(const float4*)&prm[64 + c4];
        f16x4 o;
        o[0] = (_Float16)fmaxf(fmaf(hv.x, sc.x, sh.x), 0.f);
        o[1] = (_Float16)fmaxf(fmaf(hv.y, sc.y, sh.y), 0.f);
        o[2] = (_Float16)fmaxf(fmaf(hv.z, sc.z, sh.z), 0.f);
        o[3] = (_Float16)fmaxf(fmaf(hv.w, sc.w, sh.w), 0.f);
        *(f16x4*)&sH[row * LDP + c4] = o;
    }
    __syncthreads();

    const int wid = tid >> 6, lane = tid & 63;
    const int lr = lane & 15, lg = lane >> 4;
    const int kof = lg << 3;
    const int arow = wid * 16 + lr;
    const int drow0 = wid * 16 + (lg << 2);

    f16x8 a0 = *(const f16x8*)&sH[arow * LDP + kof];
    f16x8 a1 = *(const f16x8*)&sH[arow * LDP + 32 + kof];

    #pragma unroll
    for (int n = 0; n < 8; n++) {
        const ushort* bp = w2T + (((size_t)(n << 4) + lr) << 6);
        f32x4 c = {0.f, 0.f, 0.f, 0.f};
        c = MFMA16(a0, *(const f16x8*)(bp + kof), c);
        c = MFMA16(a1, *(const f16x8*)(bp + 32 + kof), c);
        int col = (n << 4) + lr;
        float bb = b2[col];
        #pragma unroll
        for (int r = 0; r < 4; r++) {
            int gr = n0 + drow0 + r;
            if (gr < N) v16[((size_t)gr << 7) + col] =
                __builtin_bit_cast(ushort, (_Float16)fmaxf(c[r] + bb, 0.f));
        }
    }
}

// ---------------- MFMA single GEMM: vlin(fp16) = v16 @ lin, K=128 ----------------
__launch_bounds__(256, 4)
__global__ void k_gemm_rb(const ushort* __restrict__ A, const ushort* __restrict__ wT,
                          ushort* __restrict__ C, int N) {
    constexpr int LDP = 136;
    __shared__ _Float16 sA[64 * LDP];
    const int tid = threadIdx.x;
    const int n0 = blockIdx.x * 64;

    for (int i = tid; i < 64 * 32; i += 256) {
        int row = i >> 5, c4 = (i & 31) << 2;
        int gr = n0 + row;
        uint2 val = (gr < N) ? *(const uint2*)&A[((size_t)gr << 7) + c4]
                             : make_uint2(0u, 0u);
        *(uint2*)&sA[row * LDP + c4] = val;
    }
    __syncthreads();

    const int wid = tid >> 6, lane = tid & 63;
    const int lr = lane & 15, lg = lane >> 4;
    const int kof = lg << 3;
    const int arow = wid * 16 + lr;
    const int drow0 = wid * 16 + (lg << 2);

    f16x8 a0 = *(const f16x8*)&sA[arow * LDP + kof];
    f16x8 a1 = *(const f16x8*)&sA[arow * LDP + 32 + kof];
    f16x8 a2 = *(const f16x8*)&sA[arow * LDP + 64 + kof];
    f16x8 a3 = *(const f16x8*)&sA[arow * LDP + 96 + kof];

    #pragma unroll
    for (int n = 0; n < 8; n++) {
        const ushort* bp = wT + (((size_t)(n << 4) + lr) << 7);
        f32x4 c = {0.f, 0.f, 0.f, 0.f};
        c = MFMA16(a0, *(const f16x8*)(bp + kof), c);
        c = MFMA16(a1, *(const f16x8*)(bp + 32 + kof), c);
        c = MFMA16(a2, *(const f16x8*)(bp + 64 + kof), c);
        c = MFMA16(a3, *(const f16x8*)(bp + 96 + kof), c);
        int col = (n << 4) + lr;
        #pragma unroll
        for (int r = 0; r < 4; r++) {
            int gr = n0 + drow0 + r;
            if (gr < N) C[((size_t)gr << 7) + col] =
                __builtin_bit_cast(ushort, (_Float16)c[r]);
        }
    }
}

// ---------------- MFMA fused layer update: 1 wave per 16-col block ----------------
__launch_bounds__(512, 8)
__global__ void k_update(const ushort* __restrict__ agg,
                         const ushort* __restrict__ w1T, const float* __restrict__ b1,
                         const ushort* __restrict__ w2T, const float* __restrict__ b2,
                         ushort* __restrict__ v16,
                         const ushort* __restrict__ linT, ushort* __restrict__ vlin, int N) {
    constexpr int LDP = 136;
    __shared__ _Float16 sA[64 * LDP];   // 17.4 KB
    __shared__ _Float16 sB[64 * LDP];   // 17.4 KB
    const int tid = threadIdx.x;
    const int n0 = blockIdx.x * 64;

    for (int i = tid; i < 64 * 32; i += 512) {
        int row = i >> 5, c4 = (i & 31) << 2;
        int gr = n0 + row;
        uint2 a = (gr < N) ? *(const uint2*)&agg[((size_t)gr << 7) + c4] : make_uint2(0u, 0u);
        uint2 b = (gr < N) ? *(const uint2*)&v16[((size_t)gr << 7) + c4] : make_uint2(0u, 0u);
        *(uint2*)&sA[row * LDP + c4] = a;
        *(uint2*)&sB[row * LDP + c4] = b;
    }
    __syncthreads();

    const int wid = tid >> 6, lane = tid & 63;
    const int lr = lane & 15, lg = lane >> 4;
    const int kof = lg << 3;
    const int col = (wid << 4) + lr;
    const int dr0 = lg << 2;

    f32x4 acc[4];

    // ---- GEMM 1: t = ssp(agg @ W1 + b1) ----
    {
        const ushort* bp = w1T + ((size_t)col << 7);
        f16x8 B0 = *(const f16x8*)(bp + kof);
        f16x8 B1 = *(const f16x8*)(bp + 32 + kof);
        f16x8 B2 = *(const f16x8*)(bp + 64 + kof);
        f16x8 B3 = *(const f16x8*)(bp + 96 + kof);
        #pragma unroll
        for (int rb = 0; rb < 4; rb++) {
            const _Float16* ap = &sA[((rb << 4) + lr) * LDP + kof];
            f32x4 c = {0.f, 0.f, 0.f, 0.f};
            c = MFMA16(*(const f16x8*)ap, B0, c);
            c = MFMA16(*(const f16x8*)(ap + 32), B1, c);
            c = MFMA16(*(const f16x8*)(ap + 64), B2, c);
            c = MFMA16(*(const f16x8*)(ap + 96), B3, c);
            acc[rb] = c;
        }
    }
    __syncthreads();
    {
        float bb = b1[col];
        #pragma unroll
        for (int rb = 0; rb < 4; rb++) {
            #pragma unroll
            for (int r = 0; r < 4; r++)
                sA[((rb << 4) + dr0 + r) * LDP + col] = (_Float16)sspf(acc[rb][r] + bb);
        }
    }
    __syncthreads();

    // ---- GEMM 2: v_new = t @ W2 + b2 + v_old ----
    {
        const ushort* bp = w2T + ((size_t)col << 7);
        f16x8 B0 = *(const f16x8*)(bp + kof);
        f16x8 B1 = *(const f16x8*)(bp + 32 + kof);
        f16x8 B2 = *(const f16x8*)(bp + 64 + kof);
        f16x8 B3 = *(const f16x8*)(bp + 96 + kof);
        #pragma unroll
        for (int rb = 0; rb < 4; rb++) {
            const _Float16* ap = &sA[((rb << 4) + lr) * LDP + kof];
            f32x4 c = {0.f, 0.f, 0.f, 0.f};
            c = MFMA16(*(const f16x8*)ap, B0, c);
            c = MFMA16(*(const f16x8*)(ap + 32), B1, c);
            c = MFMA16(*(const f16x8*)(ap + 64), B2, c);
            c = MFMA16(*(const f16x8*)(ap + 96), B3, c);
            acc[rb] = c;
        }
    }
    {
        float bb = b2[col];
        #pragma unroll
        for (int rb = 0; rb < 4; rb++) {
            #pragma unroll
            for (int r = 0; r < 4; r++) {
                _Float16* p = &sB[((rb << 4) + dr0 + r) * LDP + col];
                *p = (_Float16)(acc[rb][r] + bb + (float)*p);
            }
        }
    }
    __syncthreads();

    for (int i = tid; i < 64 * 32; i += 512) {
        int row = i >> 5, c4 = (i & 31) << 2;
        int gr = n0 + row;
        if (gr < N) *(uint2*)&v16[((size_t)gr << 7) + c4] = *(const uint2*)&sB[row * LDP + c4];
    }
    if (!linT) return;

    // ---- GEMM 3: vlin = v_new @ lin ----
    {
        const ushort* bp = linT + ((size_t)col << 7);
        f16x8 B0 = *(const f16x8*)(bp + kof);
        f16x8 B1 = *(const f16x8*)(bp + 32 + kof);
        f16x8 B2 = *(const f16x8*)(bp + 64 + kof);
        f16x8 B3 = *(const f16x8*)(bp + 96 + kof);
        #pragma unroll
        for (int rb = 0; rb < 4; rb++) {
            const _Float16* ap = &sB[((rb << 4) + lr) * LDP + kof];
            f32x4 c = {0.f, 0.f, 0.f, 0.f};
            c = MFMA16(*(const f16x8*)ap, B0, c);
            c = MFMA16(*(const f16x8*)(ap + 32), B1, c);
            c = MFMA16(*(const f16x8*)(ap + 64), B2, c);
            c = MFMA16(*(const f16x8*)(ap + 96), B3, c);
            acc[rb] = c;
        }
    }
    #pragma unroll
    for (int rb = 0; rb < 4; rb++) {
        #pragma unroll
        for (int r = 0; r < 4; r++)
            sA[((rb << 4) + dr0 + r) * LDP + col] = (_Float16)acc[rb][r];
    }
    __syncthreads();

    for (int i = tid; i < 64 * 32; i += 512) {
        int row = i >> 5, c4 = (i & 31) << 2;
        int gr = n0 + row;
        if (gr < N) *(uint2*)&vlin[((size_t)gr << 7) + c4] = *(const uint2*)&sA[row * LDP + c4];
    }
}

// ---------------- tiled fused readout (v16 input) ----------------
__launch_bounds__(256, 4)
__global__ void k_uout(const ushort* __restrict__ v16, const float* __restrict__ u1w,
                       const float* __restrict__ u1b, const float* __restrict__ u2w,
                       const float* __restrict__ u2b, const int* __restrict__ batch,
                       float* __restrict__ out, int N) {
    __shared__ float sA[64 * 128];
    const int tid = threadIdx.x;
    const int n0 = blockIdx.x * 64;

    for (int i = tid; i < 64 * 32; i += 256) {
        int row = i >> 5, cq = (i & 31) << 2;
        int gr = n0 + row;
        float4 val = make_float4(0.f, 0.f, 0.f, 0.f);
        if (gr < N) val = ld_h4(&v16[((size_t)gr << 7) + cq]);
        *(float4*)&sA[row * 128 + cq] = val;
    }
    __syncthreads();

    const int cg = tid & 31, rg = tid >> 5;
    const int r0 = rg << 3;
    const int c2 = cg << 1;

    float2 acc[8];
    {
        float2 b1v = *(const float2*)&u1b[c2];
        #pragma unroll
        for (int i = 0; i < 8; i++) acc[i] = b1v;
        #pragma unroll 4
        for (int k = 0; k < 128; k++) {
            float2 wv = *(const float2*)&u1w[(k << 6) + c2];
            #pragma unroll
            for (int i = 0; i < 8; i++) {
                float a = sA[(r0 + i) * 128 + k];
                acc[i].x = fmaf(a, wv.x, acc[i].x);
                acc[i].y = fmaf(a, wv.y, acc[i].y);
            }
        }
    }
    __syncthreads();
    #pragma unroll
    for (int i = 0; i < 8; i++) {
        sA[(r0 + i) * 64 + c2 + 0] = sspf(acc[i].x);
        sA[(r0 + i) * 64 + c2 + 1] = sspf(acc[i].y);
    }
    __syncthreads();

    float acc2[8];
    {
        float bb = u2b[cg];
        #pragma unroll
        for (int i = 0; i < 8; i++) acc2[i] = bb;
        #pragma unroll 4
        for (int k = 0; k < 64; k++) {
            float wv = u2w[(k << 5) + cg];
            #pragma unroll
            for (int i = 0; i < 8; i++)
                acc2[i] = fmaf(sA[(r0 + i) * 64 + k], wv, acc2[i]);
        }
    }

    int cur = -1;
    float run = 0.f;
    #pragma unroll
    for (int i = 0; i < 8; i++) {
        int gr = n0 + r0 + i;
        int g = (gr < N) ? batch[gr] : -1;
        if (g != cur) {
            if (cur >= 0) atomicAdd(&out[(size_t)cur * 32 + cg], run);
            cur = g;
            run = 0.f;
        }
        if (g >= 0) run += acc2[i];
    }
    if (cur >= 0) atomicAdd(&out[(size_t)cur * 32 + cg], run);
}

extern "C" void kernel_launch(void* const* d_in, const int* in_sizes, int n_in,
                              void* d_out, int out_size, void* d_ws, size_t ws_size,
                              hipStream_t stream) {
    const float* x      = (const float*)d_in[0];
    const float* pos    = (const float*)d_in[1];
    const int*   batch  = (const int*)d_in[2];
    const int*   ei     = (const int*)d_in[3];
    const float* fe_w1  = (const float*)d_in[4];
    const float* fe_b1  = (const float*)d_in[5];
    const float* bn_g   = (const float*)d_in[6];
    const float* bn_b   = (const float*)d_in[7];
    const float* fe_w2  = (const float*)d_in[8];
    const float* fe_b2  = (const float*)d_in[9];
    const float* lin_w  = (const float*)d_in[10];
    const float* mlp_w1 = (const float*)d_in[11];
    const float* mlp_b1 = (const float*)d_in[12];
    const float* mlp_w2 = (const float*)d_in[13];
    const float* mlp_b2 = (const float*)d_in[14];
    const float* v1_w   = (const float*)d_in[15];
    const float* v1_b   = (const float*)d_in[16];
    const float* v2_w   = (const float*)d_in[17];
    const float* v2_b   = (const float*)d_in[18];
    const float* u1_w   = (const float*)d_in[19];
    const float* u1_b   = (const float*)d_in[20];
    const float* u2_w   = (const float*)d_in[21];
    const float* u2_b   = (const float*)d_in[22];

    const int N = in_sizes[0] / 28;
    const int E = in_sizes[3] / 2;
    const int NB1 = (N + 1023) / 1024;

    char* ws = (char*)d_ws;
    size_t o = 0;
    auto alloc = [&](size_t bytes) { void* p = ws + o; o += (bytes + 255) & ~(size_t)255; return p; };
    int*    counts = (int*)   alloc((size_t)N * 4);
    int*    cursor = (int*)   alloc((size_t)N * 4);
    int*    rowptr = (int*)   alloc((size_t)N * 4);
    int*    bsum   = (int*)   alloc((size_t)NB1 * 4);
    uint*   s_ef   = (uint*)  alloc((size_t)E * 4);
    float*  stats  = (float*) alloc(128 * 4);
    float*  prm    = (float*) alloc(128 * 4);
    ushort* tab    = (ushort*)alloc((size_t)LAY * K_TAB * 128 * 2);  // 12.5 MB fp16 (NN)
    ushort* v16    = (ushort*)alloc((size_t)N * 128 * 2);            // fp16 node state
    ushort* vlin   = (ushort*)alloc((size_t)N * 128 * 2);            // fp16
    ushort* agg    = (ushort*)alloc((size_t)N * 128 * 2);            // fp16
    float*  h      = (float*) alloc((size_t)N * 64 * 4);
    int*    locex  = (int*)   alloc((size_t)N * 4);
    ushort* v1T    = (ushort*)alloc((size_t)LAY * 16384 * 2);   // fp16 transposed weights
    ushort* v2T    = (ushort*)alloc((size_t)LAY * 16384 * 2);
    ushort* linT   = (ushort*)alloc((size_t)LAY * 16384 * 2);
    ushort* mw2T   = (ushort*)alloc((size_t)LAY * 16384 * 2);   // mlp_w2 fp16 [c][k]
    ushort* mw1T   = (ushort*)alloc((size_t)LAY * 8192 * 2);    // mlp_w1 fp16 [c][64]
    ushort* fe2T   = (ushort*)alloc((size_t)8192 * 2);

    // -------- weight conversion (fp16, transposed) --------
    k_cvtT128<<<LAY, 256, 0, stream>>>(v1_w, v1T);
    k_cvtT128<<<LAY, 256, 0, stream>>>(v2_w, v2T);
    k_cvtT128<<<LAY, 256, 0, stream>>>(lin_w, linT);
    k_cvtT128<<<LAY, 256, 0, stream>>>(mlp_w2, mw2T);
    k_cvtT_w1<<<LAY, 256, 0, stream>>>(mlp_w1, mw1T);
    k_cvtT_fe<<<1, 256, 0, stream>>>(fe_w2, fe2T);

    // -------- one-time edge sort (dst-ordered CSR) --------
    hipMemsetAsync(counts, 0, (size_t)N * 4, stream);
    k_hist<<<(E + 255) / 256, 256, 0, stream>>>(ei, counts, E);
    k_scan1<<<NB1, 1024, 0, stream>>>(counts, locex, bsum, N);
    k_scan2<<<1, 1024, 0, stream>>>(bsum, NB1);
    k_scan3<<<(N + 255) / 256, 256, 0, stream>>>(locex, bsum, cursor, rowptr, N);
    k_scatter<<<(E + 255) / 256, 256, 0, stream>>>(ei, pos, cursor, s_ef, E);

    // -------- gate tables (fp16, nearest-neighbor, all-MFMA) --------
    k_tab_all<<<LAY * (K_TAB / 32), 256, 0, stream>>>(mw1T, mlp_b1, mw2T, mlp_b2, tab);

    // -------- feature embedding --------
    hipMemsetAsync(stats, 0, 128 * 4, stream);
    k_fe1<<<(N * 64 + 255) / 256, 256, 0, stream>>>(x, fe_w1, fe_b1, h, N);
    k_bnstat<<<256, 256, 0, stream>>>(h, stats, N);
    k_bnfin<<<1, 64, 0, stream>>>(stats, prm, bn_g, bn_b, 1.0f / (float)N);
    const int gblk = (N + 63) / 64;
    k_fe2<<<gblk, 256, 0, stream>>>(h, prm, fe2T, fe_b2, v16, N);

    // vlin for layer 0
    k_gemm_rb<<<gblk, 256, 0, stream>>>(v16, linT, vlin, N);

    // -------- interaction layers --------
    const int eblk = (N + 7) / 8;
    for (int l = 0; l < LAY; l++) {
        k_edge_csr<<<eblk, 256, 0, stream>>>(
            s_ef, rowptr, counts, vlin,
            tab + (size_t)l * K_TAB * 128, agg, N);
        const ushort* lin_next = (l + 1 < LAY) ? linT + (size_t)(l + 1) * 16384 : nullptr;
        k_update<<<gblk, 512, 0, stream>>>(
            agg, v1T + (size_t)l * 16384, v1_b + (size_t)l * 128,
            v2T + (size_t)l * 16384, v2_b + (size_t)l * 128,
            v16, lin_next, vlin, N);
    }

    // -------- fused readout --------
    hipMemsetAsync(d_out, 0, (size_t)out_size * 4, stream);
    k_uout<<<gblk, 256, 0, stream>>>(v16, u1_w, u1_b, u2_w, u2_b, batch, (float*)d_out, N);
}

// Round 20
// 590.441 us; speedup vs baseline: 1.6440x; 1.0186x over previous
//
#include <hip/hip_runtime.h>
#include <hip/hip_fp16.h>
#include <math.h>

#define DEV __device__ __forceinline__

constexpr int NGAUSS = 50;
constexpr int LAY = 6;
constexpr int K_TAB = 8192;                            // nearest-neighbor table
constexpr float DMAX = 40.0f;
constexpr float TSCALE = (float)(K_TAB - 1) / DMAX;    // knot = round(d * TSCALE)
constexpr float STEP = 6.0f / 49.0f;
constexpr float COEFF = -0.5f / (STEP * STEP);
constexpr float LN2F = 0.69314718055994531f;
constexpr float PI_OVER_CUT = 0.52359877559829887f;    // pi/6

using f16x8 = __attribute__((ext_vector_type(8))) _Float16;
using f16x4 = __attribute__((ext_vector_type(4))) _Float16;
using f32x4 = __attribute__((ext_vector_type(4))) float;
using f32x8 = __attribute__((ext_vector_type(8))) float;

#define MFMA16(a, b, c) __builtin_amdgcn_mfma_f32_16x16x32_f16(a, b, c, 0, 0, 0)

DEV float sspf(float x) {
    float ax = fabsf(x);
    float e = __expf(-ax);
    return fmaxf(x, 0.f) + __logf(1.f + e) - LN2F;
}

// ---- fp16 pack/unpack helpers (storage fp16, math f32) ----
DEV float4 ld_h4(const ushort* p) {          // 8B load -> 4 floats
    uint2 r = *(const uint2*)p;
    __half2 a = __builtin_bit_cast(__half2, r.x);
    __half2 b = __builtin_bit_cast(__half2, r.y);
    float2 fa = __half22float2(a), fb = __half22float2(b);
    return make_float4(fa.x, fa.y, fb.x, fb.y);
}

// ---------------- weight convert+transpose (fp32 [K][C] -> fp16 [C][K]) ----------------
__global__ void k_cvtT128(const float* __restrict__ src, ushort* __restrict__ dst) {
    const float* s = src + (size_t)blockIdx.x * 16384;
    ushort* d = dst + (size_t)blockIdx.x * 16384;
    for (int i = threadIdx.x; i < 16384; i += 256) {
        int k = i >> 7, c = i & 127;
        d[(c << 7) + k] = __builtin_bit_cast(ushort, (_Float16)s[i]);
    }
}
__global__ void k_cvtT_fe(const float* __restrict__ src, ushort* __restrict__ dst) {
    // fe_w2: [64][128] -> dst[c(128)][k(64)]
    for (int i = threadIdx.x; i < 8192; i += 256) {
        int k = i >> 7, c = i & 127;
        dst[(c << 6) + k] = __builtin_bit_cast(ushort, (_Float16)src[i]);
    }
}
__global__ void k_cvtT_w1(const float* __restrict__ src, ushort* __restrict__ dst) {
    // mlp_w1: [50][128] -> dst[c(128)][k(64)], zero-padded k>=50
    const float* s = src + (size_t)blockIdx.x * (NGAUSS * 128);
    ushort* d = dst + (size_t)blockIdx.x * (128 * 64);
    for (int i = threadIdx.x; i < 128 * 64; i += 256) {
        int c = i >> 6, k = i & 63;
        float v = (k < NGAUSS) ? s[k * 128 + c] : 0.f;
        d[(c << 6) + k] = __builtin_bit_cast(ushort, (_Float16)v);
    }
}

// ---------------- edge sort pre-pass (once per call) ----------------
// hist also captures each edge's rank within its dst bucket (the atomic's return value)
__global__ void k_hist(const int* __restrict__ ei, int* __restrict__ counts,
                       int* __restrict__ rank, int E) {
    int e = blockIdx.x * 256 + threadIdx.x;
    if (e < E) rank[e] = atomicAdd(&counts[ei[E + e]], 1);
}

__global__ void k_scan1(const int* __restrict__ counts, int* __restrict__ locex,
                        int* __restrict__ bsum, int n) {
    __shared__ int s_wsum[16];
    const int tid = threadIdx.x;
    const int i = blockIdx.x * 1024 + tid;
    const int lane = tid & 63, wv = tid >> 6;
    int v = (i < n) ? counts[i] : 0;
    int x = v;
    #pragma unroll
    for (int off = 1; off < 64; off <<= 1) {
        int y = __shfl_up(x, off, 64);
        if (lane >= off) x += y;
    }
    if (lane == 63) s_wsum[wv] = x;
    __syncthreads();
    if (wv == 0 && lane < 16) {
        int wval = s_wsum[lane];
        int wx = wval;
        #pragma unroll
        for (int off = 1; off < 16; off <<= 1) {
            int wy = __shfl_up(wx, off, 16);
            if (lane >= off) wx += wy;
        }
        s_wsum[lane] = wx - wval;
    }
    __syncthreads();
    if (i < n) locex[i] = s_wsum[wv] + x - v;
    if (tid == 1023) bsum[blockIdx.x] = s_wsum[15] + x;
}

__global__ void k_scan2(int* __restrict__ bsum, int nb) {
    __shared__ int s_wsum[16];
    const int tid = threadIdx.x;
    const int lane = tid & 63, wv = tid >> 6;
    int v = (tid < nb) ? bsum[tid] : 0;
    int x = v;
    #pragma unroll
    for (int off = 1; off < 64; off <<= 1) {
        int y = __shfl_up(x, off, 64);
        if (lane >= off) x += y;
    }
    if (lane == 63) s_wsum[wv] = x;
    __syncthreads();
    if (wv == 0 && lane < 16) {
        int wval = s_wsum[lane];
        int wx = wval;
        #pragma unroll
        for (int off = 1; off < 16; off <<= 1) {
            int wy = __shfl_up(wx, off, 16);
            if (lane >= off) wx += wy;
        }
        s_wsum[lane] = wx - wval;
    }
    __syncthreads();
    if (tid < nb) bsum[tid] = s_wsum[wv] + x - v;
}

__global__ void k_scan3(const int* __restrict__ locex, const int* __restrict__ bsumex,
                        int* __restrict__ rowptr, int n) {
    int i = blockIdx.x * 256 + threadIdx.x;
    if (i >= n) return;
    rowptr[i] = locex[i] + bsumex[i >> 10];
}

// scatter: p = rowptr[dst] + rank[e]; no atomics. packed {src(16b) | knot(13b)<<16}
__global__ void k_scatter(const int* __restrict__ ei, const float* __restrict__ pos,
                          const int* __restrict__ rowptr, const int* __restrict__ rank,
                          uint* __restrict__ s_ef, int E) {
    int e = blockIdx.x * 256 + threadIdx.x;
    if (e >= E) return;
    int r = ei[e], c = ei[E + e];
    float dx = pos[3 * r + 0] - pos[3 * c + 0];
    float dy = pos[3 * r + 1] - pos[3 * c + 1];
    float dz = pos[3 * r + 2] - pos[3 * c + 2];
    float d = sqrtf(dx * dx + dy * dy + dz * dz);
    int i0 = (int)(d * TSCALE + 0.5f);
    if (i0 > K_TAB - 1) i0 = K_TAB - 1;
    int p = rowptr[c] + rank[e];
    s_ef[p] = (uint)r | ((uint)i0 << 16);
}

// ---------------- gate table build: all-MFMA ----------------
// 32 knots per block; grid = LAY * (K_TAB/32)
__launch_bounds__(256)
__global__ void k_tab_all(const ushort* __restrict__ w1TA, const float* __restrict__ b1A,
                          const ushort* __restrict__ w2TA, const float* __restrict__ b2A,
                          ushort* __restrict__ tabA) {
    const int layer = blockIdx.x / (K_TAB / 32);
    const int k0 = (blockIdx.x % (K_TAB / 32)) * 32;
    const ushort* w1T = w1TA + (size_t)layer * 8192;    // [128][64] fp16
    const float* b1 = b1A + (size_t)layer * 128;
    const ushort* w2T = w2TA + (size_t)layer * 16384;   // [128][128] fp16
    const float* b2 = b2A + (size_t)layer * 128;
    ushort* tab = tabA + (size_t)layer * K_TAB * 128;

    constexpr int LDD = 72;
    constexpr int LDP = 136;
    __shared__ _Float16 sD[32 * LDD];   // demb fp16, K padded to 64 (4.5 KB)
    __shared__ _Float16 sT[32 * LDP];   // t1 fp16 (8.7 KB)
    __shared__ float s_cc[32];
    const int tid = threadIdx.x;

    for (int i = tid; i < 32 * 64; i += 256) {
        int r = i >> 6, g = i & 63;
        float val = 0.f;
        if (g < NGAUSS) {
            float d = (float)(k0 + r) * (1.0f / TSCALE);
            float t = d - g * STEP;
            val = __expf(COEFF * t * t);
        }
        sD[r * LDD + g] = (_Float16)val;
    }
    if (tid < 32) {
        float d = (float)(k0 + tid) * (1.0f / TSCALE);
        s_cc[tid] = 0.5f * (__cosf(d * PI_OVER_CUT) + 1.0f);
    }
    __syncthreads();

    const int wid = tid >> 6, lane = tid & 63;
    const int lr = lane & 15, lg = lane >> 4;
    const int kof = lg << 3;

    // GEMM1 (MFMA, K=64): t1 = ssp(demb @ w1 + b1) -> sT
    #pragma unroll
    for (int cb = 0; cb < 2; cb++) {
        const int col = ((2 * wid + cb) << 4) + lr;
        const ushort* bp = w1T + ((size_t)col << 6);
        f16x8 B0 = *(const f16x8*)(bp + kof);
        f16x8 B1 = *(const f16x8*)(bp + 32 + kof);
        float bb = b1[col];
        #pragma unroll
        for (int rt = 0; rt < 2; rt++) {
            const _Float16* ap = &sD[((rt << 4) + lr) * LDD + kof];
            f32x4 c = {0.f, 0.f, 0.f, 0.f};
            c = MFMA16(*(const f16x8*)ap, B0, c);
            c = MFMA16(*(const f16x8*)(ap + 32), B1, c);
            #pragma unroll
            for (int r = 0; r < 4; r++)
                sT[((rt << 4) + (lg << 2) + r) * LDP + col] = (_Float16)sspf(c[r] + bb);
        }
    }
    __syncthreads();

    // GEMM2 (MFMA, K=128): W = (t1 @ w2 + b2) * cosC -> tab
    #pragma unroll
    for (int cb = 0; cb < 2; cb++) {
        const int col = ((2 * wid + cb) << 4) + lr;
        const ushort* bp = w2T + ((size_t)col << 7);
        f16x8 B0 = *(const f16x8*)(bp + kof);
        f16x8 B1 = *(const f16x8*)(bp + 32 + kof);
        f16x8 B2 = *(const f16x8*)(bp + 64 + kof);
        f16x8 B3 = *(const f16x8*)(bp + 96 + kof);
        float bb = b2[col];
        #pragma unroll
        for (int rt = 0; rt < 2; rt++) {
            const _Float16* ap = &sT[((rt << 4) + lr) * LDP + kof];
            f32x4 c = {0.f, 0.f, 0.f, 0.f};
            c = MFMA16(*(const f16x8*)ap, B0, c);
            c = MFMA16(*(const f16x8*)(ap + 32), B1, c);
            c = MFMA16(*(const f16x8*)(ap + 64), B2, c);
            c = MFMA16(*(const f16x8*)(ap + 96), B3, c);
            #pragma unroll
            for (int r = 0; r < 4; r++) {
                int kr = (rt << 4) + (lg << 2) + r;
                tab[((size_t)(k0 + kr) << 7) + col] =
                    __builtin_bit_cast(ushort, (_Float16)((c[r] + bb) * s_cc[kr]));
            }
        }
    }
}

// ---------------- node-centric CSR edge kernel: full wave per node, 4 edge-parities ----------------
// lane = parity(h: lane>>4) x channel-octet(lc: lane&15); deg<=16 completes in ONE batch round.
__launch_bounds__(256, 8)
__global__ void k_edge_csr(const uint* __restrict__ s_ef,
                           const int* __restrict__ rowptr, const int* __restrict__ counts,
                           const ushort* __restrict__ vlin, const ushort* __restrict__ tab,
                           ushort* __restrict__ agg, int N) {
    const int tid = threadIdx.x;
    const int lane = tid & 63;
    const int h = lane >> 4;         // 0..3: edge parity
    const int lc = lane & 15;        // channel octet: channels 8lc..8lc+7
    const int n = blockIdx.x * 4 + (tid >> 6);
    if (n >= N) return;
    const ushort* tabc = tab + (lc << 3);
    const ushort* vlc  = vlin + (lc << 3);

    const int rs = rowptr[n];
    const int re = rs + counts[n];
    f32x8 acc = {0.f, 0.f, 0.f, 0.f, 0.f, 0.f, 0.f, 0.f};

    int e = rs + h;
    // main: 4 edges of this parity per iter (16 edges per wave-iter)
    for (; e + 12 < re; e += 16) {
        f16x8 TP[4], VL[4];
        #pragma unroll
        for (int j = 0; j < 4; j++) {
            uint pk = s_ef[e + 4 * j];
            TP[j] = *(const f16x8*)(tabc + ((size_t)(pk >> 16) << 7));
            VL[j] = *(const f16x8*)(vlc + ((size_t)(pk & 0xFFFFu) << 7));
        }
        f16x8 p0 = TP[0] * VL[0];
        p0 += TP[1] * VL[1];
        f16x8 p1 = TP[2] * VL[2];
        p1 += TP[3] * VL[3];
        acc += __builtin_convertvector(p0, f32x8);
        acc += __builtin_convertvector(p1, f32x8);
    }
    // tail: one edge of this parity at a time
    for (; e < re; e += 4) {
        uint pk = s_ef[e];
        f16x8 tp = *(const f16x8*)(tabc + ((size_t)(pk >> 16) << 7));
        f16x8 vl = *(const f16x8*)(vlc + ((size_t)(pk & 0xFFFFu) << 7));
        acc += __builtin_convertvector(tp * vl, f32x8);
    }
    // combine 4 parities: lanes i <-> i^16 <-> i^32
    #pragma unroll
    for (int i = 0; i < 8; i++) {
        acc[i] += __shfl_xor(acc[i], 16);
        acc[i] += __shfl_xor(acc[i], 32);
    }
    if (h == 0) {
        f16x8 o;
        #pragma unroll
        for (int i = 0; i < 8; i++) o[i] = (_Float16)acc[i];
        *(f16x8*)&agg[((size_t)n << 7) + (lc << 3)] = o;
    }
}

// ---------------- feature embedding ----------------
__global__ void k_fe1(const float* __restrict__ x, const float* __restrict__ w,
                      const float* __restrict__ b, float* __restrict__ h, int N) {
    int idx = blockIdx.x * 256 + threadIdx.x;
    if (idx >= N * 64) return;
    int n = idx >> 6, c = idx & 63;
    const float* xr = x + (size_t)n * 28;
    float acc = b[c];
    #pragma unroll
    for (int k = 0; k < 28; k++) acc = fmaf(xr[k], w[k * 64 + c], acc);
    h[idx] = acc;
}

__global__ void k_bnstat(const float* __restrict__ h, float* __restrict__ stats, int N) {
    __shared__ float s_s[256], s_q[256];
    int tid = threadIdx.x;
    int c = tid & 63, g = tid >> 6;
    float s = 0.f, q = 0.f;
    for (int n = blockIdx.x * 4 + g; n < N; n += gridDim.x * 4) {
        float v = h[(size_t)n * 64 + c];
        s += v; q += v * v;
    }
    s_s[tid] = s; s_q[tid] = q;
    __syncthreads();
    if (tid < 64) {
        s = s_s[tid] + s_s[tid + 64] + s_s[tid + 128] + s_s[tid + 192];
        q = s_q[tid] + s_q[tid + 64] + s_q[tid + 128] + s_q[tid + 192];
        atomicAdd(&stats[tid], s);
        atomicAdd(&stats[64 + tid], q);
    }
}

__global__ void k_bnfin(const float* __restrict__ stats, float* __restrict__ prm,
                        const float* __restrict__ gamma, const float* __restrict__ beta,
                        float invN) {
    int c = threadIdx.x;  // 64 threads
    float mu = stats[c] * invN;
    float var = stats[64 + c] * invN - mu * mu;
    float sc = gamma[c] * rsqrtf(var + 1e-5f);
    prm[c] = sc;
    prm[64 + c] = beta[c] - mu * sc;
}

// ---------------- MFMA fe2: v16 = relu( relu(bn(h)) @ fe_w2 + b2 ), K=64 ----------------
__launch_bounds__(256, 4)
__global__ void k_fe2(const float* __restrict__ h, const float* __restrict__ prm,
                      const ushort* __restrict__ w2T, const float* __restrict__ b2,
                      ushort* __restrict__ v16, int N) {
    constexpr int LDP = 72;
    __shared__ _Float16 sH[64 * LDP];
    const int tid = threadIdx.x;
    const int n0 = blockIdx.x * 64;

    for (int i = tid; i < 64 * 16; i += 256) {
        int row = i >> 4, c4 = (i & 15) << 2;
        int gr = n0 + row;
        float4 hv = (gr < N) ? *(const float4*)&h[((size_t)gr << 6) + c4]
                             : make_float4(0.f, 0.f, 0.f, 0.f);
        float4 sc = *(const float4*)&prm[c4];
        float4 sh = *(const float4*)&prm[64 + c4];
        f16x4 o;
        o[0] = (_Float16)fmaxf(fmaf(hv.x, sc.x, sh.x), 0.f);
        o[1] = (_Float16)fmaxf(fmaf(hv.y, sc.y, sh.y), 0.f);
        o[2] = (_Float16)fmaxf(fmaf(hv.z, sc.z, sh.z), 0.f);
        o[3] = (_Float16)fmaxf(fmaf(hv.w, sc.w, sh.w), 0.f);
        *(f16x4*)&sH[row * LDP + c4] = o;
    }
    __syncthreads();

    const int wid = tid >> 6, lane = tid & 63;
    const int lr = lane & 15, lg = lane >> 4;
    const int kof = lg << 3;
    const int arow = wid * 16 + lr;
    const int drow0 = wid * 16 + (lg << 2);

    f16x8 a0 = *(const f16x8*)&sH[arow * LDP + kof];
    f16x8 a1 = *(const f16x8*)&sH[arow * LDP + 32 + kof];

    #pragma unroll
    for (int n = 0; n < 8; n++) {
        const ushort* bp = w2T + (((size_t)(n << 4) + lr) << 6);
        f32x4 c = {0.f, 0.f, 0.f, 0.f};
        c = MFMA16(a0, *(const f16x8*)(bp + kof), c);
        c = MFMA16(a1, *(const f16x8*)(bp + 32 + kof), c);
        int col = (n << 4) + lr;
        float bb = b2[col];
        #pragma unroll
        for (int r = 0; r < 4; r++) {
            int gr = n0 + drow0 + r;
            if (gr < N) v16[((size_t)gr << 7) + col] =
                __builtin_bit_cast(ushort, (_Float16)fmaxf(c[r] + bb, 0.f));
        }
    }
}

// ---------------- MFMA single GEMM: vlin(fp16) = v16 @ lin, K=128 ----------------
__launch_bounds__(256, 4)
__global__ void k_gemm_rb(const ushort* __restrict__ A, const ushort* __restrict__ wT,
                          ushort* __restrict__ C, int N) {
    constexpr int LDP = 136;
    __shared__ _Float16 sA[64 * LDP];
    const int tid = threadIdx.x;
    const int n0 = blockIdx.x * 64;

    for (int i = tid; i < 64 * 32; i += 256) {
        int row = i >> 5, c4 = (i & 31) << 2;
        int gr = n0 + row;
        uint2 val = (gr < N) ? *(const uint2*)&A[((size_t)gr << 7) + c4]
                             : make_uint2(0u, 0u);
        *(uint2*)&sA[row * LDP + c4] = val;
    }
    __syncthreads();

    const int wid = tid >> 6, lane = tid & 63;
    const int lr = lane & 15, lg = lane >> 4;
    const int kof = lg << 3;
    const int arow = wid * 16 + lr;
    const int drow0 = wid * 16 + (lg << 2);

    f16x8 a0 = *(const f16x8*)&sA[arow * LDP + kof];
    f16x8 a1 = *(const f16x8*)&sA[arow * LDP + 32 + kof];
    f16x8 a2 = *(const f16x8*)&sA[arow * LDP + 64 + kof];
    f16x8 a3 = *(const f16x8*)&sA[arow * LDP + 96 + kof];

    #pragma unroll
    for (int n = 0; n < 8; n++) {
        const ushort* bp = wT + (((size_t)(n << 4) + lr) << 7);
        f32x4 c = {0.f, 0.f, 0.f, 0.f};
        c = MFMA16(a0, *(const f16x8*)(bp + kof), c);
        c = MFMA16(a1, *(const f16x8*)(bp + 32 + kof), c);
        c = MFMA16(a2, *(const f16x8*)(bp + 64 + kof), c);
        c = MFMA16(a3, *(const f16x8*)(bp + 96 + kof), c);
        int col = (n << 4) + lr;
        #pragma unroll
        for (int r = 0; r < 4; r++) {
            int gr = n0 + drow0 + r;
            if (gr < N) C[((size_t)gr << 7) + col] =
                __builtin_bit_cast(ushort, (_Float16)c[r]);
        }
    }
}

// ---------------- MFMA fused layer update: 1 wave per 16-col block ----------------
__launch_bounds__(512, 8)
__global__ void k_update(const ushort* __restrict__ agg,
                         const ushort* __restrict__ w1T, const float* __restrict__ b1,
                         const ushort* __restrict__ w2T, const float* __restrict__ b2,
                         ushort* __restrict__ v16,
                         const ushort* __restrict__ linT, ushort* __restrict__ vlin, int N) {
    constexpr int LDP = 136;
    __shared__ _Float16 sA[64 * LDP];   // 17.4 KB
    __shared__ _Float16 sB[64 * LDP];   // 17.4 KB
    const int tid = threadIdx.x;
    const int n0 = blockIdx.x * 64;

    for (int i = tid; i < 64 * 32; i += 512) {
        int row = i >> 5, c4 = (i & 31) << 2;
        int gr = n0 + row;
        uint2 a = (gr < N) ? *(const uint2*)&agg[((size_t)gr << 7) + c4] : make_uint2(0u, 0u);
        uint2 b = (gr < N) ? *(const uint2*)&v16[((size_t)gr << 7) + c4] : make_uint2(0u, 0u);
        *(uint2*)&sA[row * LDP + c4] = a;
        *(uint2*)&sB[row * LDP + c4] = b;
    }
    __syncthreads();

    const int wid = tid >> 6, lane = tid & 63;
    const int lr = lane & 15, lg = lane >> 4;
    const int kof = lg << 3;
    const int col = (wid << 4) + lr;
    const int dr0 = lg << 2;

    f32x4 acc[4];

    // ---- GEMM 1: t = ssp(agg @ W1 + b1) ----
    {
        const ushort* bp = w1T + ((size_t)col << 7);
        f16x8 B0 = *(const f16x8*)(bp + kof);
        f16x8 B1 = *(const f16x8*)(bp + 32 + kof);
        f16x8 B2 = *(const f16x8*)(bp + 64 + kof);
        f16x8 B3 = *(const f16x8*)(bp + 96 + kof);
        #pragma unroll
        for (int rb = 0; rb < 4; rb++) {
            const _Float16* ap = &sA[((rb << 4) + lr) * LDP + kof];
            f32x4 c = {0.f, 0.f, 0.f, 0.f};
            c = MFMA16(*(const f16x8*)ap, B0, c);
            c = MFMA16(*(const f16x8*)(ap + 32), B1, c);
            c = MFMA16(*(const f16x8*)(ap + 64), B2, c);
            c = MFMA16(*(const f16x8*)(ap + 96), B3, c);
            acc[rb] = c;
        }
    }
    __syncthreads();
    {
        float bb = b1[col];
        #pragma unroll
        for (int rb = 0; rb < 4; rb++) {
            #pragma unroll
            for (int r = 0; r < 4; r++)
                sA[((rb << 4) + dr0 + r) * LDP + col] = (_Float16)sspf(acc[rb][r] + bb);
        }
    }
    __syncthreads();

    // ---- GEMM 2: v_new = t @ W2 + b2 + v_old ----
    {
        const ushort* bp = w2T + ((size_t)col << 7);
        f16x8 B0 = *(const f16x8*)(bp + kof);
        f16x8 B1 = *(const f16x8*)(bp + 32 + kof);
        f16x8 B2 = *(const f16x8*)(bp + 64 + kof);
        f16x8 B3 = *(const f16x8*)(bp + 96 + kof);
        #pragma unroll
        for (int rb = 0; rb < 4; rb++) {
            const _Float16* ap = &sA[((rb << 4) + lr) * LDP + kof];
            f32x4 c = {0.f, 0.f, 0.f, 0.f};
            c = MFMA16(*(const f16x8*)ap, B0, c);
            c = MFMA16(*(const f16x8*)(ap + 32), B1, c);
            c = MFMA16(*(const f16x8*)(ap + 64), B2, c);
            c = MFMA16(*(const f16x8*)(ap + 96), B3, c);
            acc[rb] = c;
        }
    }
    {
        float bb = b2[col];
        #pragma unroll
        for (int rb = 0; rb < 4; rb++) {
            #pragma unroll
            for (int r = 0; r < 4; r++) {
                _Float16* p = &sB[((rb << 4) + dr0 + r) * LDP + col];
                *p = (_Float16)(acc[rb][r] + bb + (float)*p);
            }
        }
    }
    __syncthreads();

    for (int i = tid; i < 64 * 32; i += 512) {
        int row = i >> 5, c4 = (i & 31) << 2;
        int gr = n0 + row;
        if (gr < N) *(uint2*)&v16[((size_t)gr << 7) + c4] = *(const uint2*)&sB[row * LDP + c4];
    }
    if (!linT) return;

    // ---- GEMM 3: vlin = v_new @ lin ----
    {
        const ushort* bp = linT + ((size_t)col << 7);
        f16x8 B0 = *(const f16x8*)(bp + kof);
        f16x8 B1 = *(const f16x8*)(bp + 32 + kof);
        f16x8 B2 = *(const f16x8*)(bp + 64 + kof);
        f16x8 B3 = *(const f16x8*)(bp + 96 + kof);
        #pragma unroll
        for (int rb = 0; rb < 4; rb++) {
            const _Float16* ap = &sB[((rb << 4) + lr) * LDP + kof];
            f32x4 c = {0.f, 0.f, 0.f, 0.f};
            c = MFMA16(*(const f16x8*)ap, B0, c);
            c = MFMA16(*(const f16x8*)(ap + 32), B1, c);
            c = MFMA16(*(const f16x8*)(ap + 64), B2, c);
            c = MFMA16(*(const f16x8*)(ap + 96), B3, c);
            acc[rb] = c;
        }
    }
    #pragma unroll
    for (int rb = 0; rb < 4; rb++) {
        #pragma unroll
        for (int r = 0; r < 4; r++)
            sA[((rb << 4) + dr0 + r) * LDP + col] = (_Float16)acc[rb][r];
    }
    __syncthreads();

    for (int i = tid; i < 64 * 32; i += 512) {
        int row = i >> 5, c4 = (i & 31) << 2;
        int gr = n0 + row;
        if (gr < N) *(uint2*)&vlin[((size_t)gr << 7) + c4] = *(const uint2*)&sA[row * LDP + c4];
    }
}

// ---------------- tiled fused readout (v16 input) ----------------
__launch_bounds__(256, 4)
__global__ void k_uout(const ushort* __restrict__ v16, const float* __restrict__ u1w,
                       const float* __restrict__ u1b, const float* __restrict__ u2w,
                       const float* __restrict__ u2b, const int* __restrict__ batch,
                       float* __restrict__ out, int N) {
    __shared__ float sA[64 * 128];
    const int tid = threadIdx.x;
    const int n0 = blockIdx.x * 64;

    for (int i = tid; i < 64 * 32; i += 256) {
        int row = i >> 5, cq = (i & 31) << 2;
        int gr = n0 + row;
        float4 val = make_float4(0.f, 0.f, 0.f, 0.f);
        if (gr < N) val = ld_h4(&v16[((size_t)gr << 7) + cq]);
        *(float4*)&sA[row * 128 + cq] = val;
    }
    __syncthreads();

    const int cg = tid & 31, rg = tid >> 5;
    const int r0 = rg << 3;
    const int c2 = cg << 1;

    float2 acc[8];
    {
        float2 b1v = *(const float2*)&u1b[c2];
        #pragma unroll
        for (int i = 0; i < 8; i++) acc[i] = b1v;
        #pragma unroll 4
        for (int k = 0; k < 128; k++) {
            float2 wv = *(const float2*)&u1w[(k << 6) + c2];
            #pragma unroll
            for (int i = 0; i < 8; i++) {
                float a = sA[(r0 + i) * 128 + k];
                acc[i].x = fmaf(a, wv.x, acc[i].x);
                acc[i].y = fmaf(a, wv.y, acc[i].y);
            }
        }
    }
    __syncthreads();
    #pragma unroll
    for (int i = 0; i < 8; i++) {
        sA[(r0 + i) * 64 + c2 + 0] = sspf(acc[i].x);
        sA[(r0 + i) * 64 + c2 + 1] = sspf(acc[i].y);
    }
    __syncthreads();

    float acc2[8];
    {
        float bb = u2b[cg];
        #pragma unroll
        for (int i = 0; i < 8; i++) acc2[i] = bb;
        #pragma unroll 4
        for (int k = 0; k < 64; k++) {
            float wv = u2w[(k << 5) + cg];
            #pragma unroll
            for (int i = 0; i < 8; i++)
                acc2[i] = fmaf(sA[(r0 + i) * 64 + k], wv, acc2[i]);
        }
    }

    int cur = -1;
    float run = 0.f;
    #pragma unroll
    for (int i = 0; i < 8; i++) {
        int gr = n0 + r0 + i;
        int g = (gr < N) ? batch[gr] : -1;
        if (g != cur) {
            if (cur >= 0) atomicAdd(&out[(size_t)cur * 32 + cg], run);
            cur = g;
            run = 0.f;
        }
        if (g >= 0) run += acc2[i];
    }
    if (cur >= 0) atomicAdd(&out[(size_t)cur * 32 + cg], run);
}

extern "C" void kernel_launch(void* const* d_in, const int* in_sizes, int n_in,
                              void* d_out, int out_size, void* d_ws, size_t ws_size,
                              hipStream_t stream) {
    const float* x      = (const float*)d_in[0];
    const float* pos    = (const float*)d_in[1];
    const int*   batch  = (const int*)d_in[2];
    const int*   ei     = (const int*)d_in[3];
    const float* fe_w1  = (const float*)d_in[4];
    const float* fe_b1  = (const float*)d_in[5];
    const float* bn_g   = (const float*)d_in[6];
    const float* bn_b   = (const float*)d_in[7];
    const float* fe_w2  = (const float*)d_in[8];
    const float* fe_b2  = (const float*)d_in[9];
    const float* lin_w  = (const float*)d_in[10];
    const float* mlp_w1 = (const float*)d_in[11];
    const float* mlp_b1 = (const float*)d_in[12];
    const float* mlp_w2 = (const float*)d_in[13];
    const float* mlp_b2 = (const float*)d_in[14];
    const float* v1_w   = (const float*)d_in[15];
    const float* v1_b   = (const float*)d_in[16];
    const float* v2_w   = (const float*)d_in[17];
    const float* v2_b   = (const float*)d_in[18];
    const float* u1_w   = (const float*)d_in[19];
    const float* u1_b   = (const float*)d_in[20];
    const float* u2_w   = (const float*)d_in[21];
    const float* u2_b   = (const float*)d_in[22];

    const int N = in_sizes[0] / 28;
    const int E = in_sizes[3] / 2;
    const int NB1 = (N + 1023) / 1024;

    char* ws = (char*)d_ws;
    size_t o = 0;
    auto alloc = [&](size_t bytes) { void* p = ws + o; o += (bytes + 255) & ~(size_t)255; return p; };
    int*    counts = (int*)   alloc((size_t)N * 4);
    int*    rowptr = (int*)   alloc((size_t)N * 4);
    int*    bsum   = (int*)   alloc((size_t)NB1 * 4);
    int*    rank   = (int*)   alloc((size_t)E * 4);
    uint*   s_ef   = (uint*)  alloc((size_t)E * 4);
    float*  stats  = (float*) alloc(128 * 4);
    float*  prm    = (float*) alloc(128 * 4);
    ushort* tab    = (ushort*)alloc((size_t)LAY * K_TAB * 128 * 2);  // 12.5 MB fp16 (NN)
    ushort* v16    = (ushort*)alloc((size_t)N * 128 * 2);            // fp16 node state
    ushort* vlin   = (ushort*)alloc((size_t)N * 128 * 2);            // fp16
    ushort* agg    = (ushort*)alloc((size_t)N * 128 * 2);            // fp16
    float*  h      = (float*) alloc((size_t)N * 64 * 4);
    int*    locex  = (int*)   alloc((size_t)N * 4);
    ushort* v1T    = (ushort*)alloc((size_t)LAY * 16384 * 2);   // fp16 transposed weights
    ushort* v2T    = (ushort*)alloc((size_t)LAY * 16384 * 2);
    ushort* linT   = (ushort*)alloc((size_t)LAY * 16384 * 2);
    ushort* mw2T   = (ushort*)alloc((size_t)LAY * 16384 * 2);   // mlp_w2 fp16 [c][k]
    ushort* mw1T   = (ushort*)alloc((size_t)LAY * 8192 * 2);    // mlp_w1 fp16 [c][64]
    ushort* fe2T   = (ushort*)alloc((size_t)8192 * 2);

    // -------- weight conversion (fp16, transposed) --------
    k_cvtT128<<<LAY, 256, 0, stream>>>(v1_w, v1T);
    k_cvtT128<<<LAY, 256, 0, stream>>>(v2_w, v2T);
    k_cvtT128<<<LAY, 256, 0, stream>>>(lin_w, linT);
    k_cvtT128<<<LAY, 256, 0, stream>>>(mlp_w2, mw2T);
    k_cvtT_w1<<<LAY, 256, 0, stream>>>(mlp_w1, mw1T);
    k_cvtT_fe<<<1, 256, 0, stream>>>(fe_w2, fe2T);

    // -------- one-time edge sort (dst-ordered CSR, atomic-free scatter) --------
    hipMemsetAsync(counts, 0, (size_t)N * 4, stream);
    k_hist<<<(E + 255) / 256, 256, 0, stream>>>(ei, counts, rank, E);
    k_scan1<<<NB1, 1024, 0, stream>>>(counts, locex, bsum, N);
    k_scan2<<<1, 1024, 0, stream>>>(bsum, NB1);
    k_scan3<<<(N + 255) / 256, 256, 0, stream>>>(locex, bsum, rowptr, N);
    k_scatter<<<(E + 255) / 256, 256, 0, stream>>>(ei, pos, rowptr, rank, s_ef, E);

    // -------- gate tables (fp16, nearest-neighbor, all-MFMA) --------
    k_tab_all<<<LAY * (K_TAB / 32), 256, 0, stream>>>(mw1T, mlp_b1, mw2T, mlp_b2, tab);

    // -------- feature embedding --------
    hipMemsetAsync(stats, 0, 128 * 4, stream);
    k_fe1<<<(N * 64 + 255) / 256, 256, 0, stream>>>(x, fe_w1, fe_b1, h, N);
    k_bnstat<<<256, 256, 0, stream>>>(h, stats, N);
    k_bnfin<<<1, 64, 0, stream>>>(stats, prm, bn_g, bn_b, 1.0f / (float)N);
    const int gblk = (N + 63) / 64;
    k_fe2<<<gblk, 256, 0, stream>>>(h, prm, fe2T, fe_b2, v16, N);

    // vlin for layer 0
    k_gemm_rb<<<gblk, 256, 0, stream>>>(v16, linT, vlin, N);

    // -------- interaction layers --------
    const int eblk = (N + 3) / 4;
    for (int l = 0; l < LAY; l++) {
        k_edge_csr<<<eblk, 256, 0, stream>>>(
            s_ef, rowptr, counts, vlin,
            tab + (size_t)l * K_TAB * 128, agg, N);
        const ushort* lin_next = (l + 1 < LAY) ? linT + (size_t)(l + 1) * 16384 : nullptr;
        k_update<<<gblk, 512, 0, stream>>>(
            agg, v1T + (size_t)l * 16384, v1_b + (size_t)l * 128,
            v2T + (size_t)l * 16384, v2_b + (size_t)l * 128,
            v16, lin_next, vlin, N);
    }

    // -------- fused readout --------
    hipMemsetAsync(d_out, 0, (size_t)out_size * 4, stream);
    k_uout<<<gblk, 256, 0, stream>>>(v16, u1_w, u1_b, u2_w, u2_b, batch, (float*)d_out, N);
}

// Round 21
// 587.297 us; speedup vs baseline: 1.6528x; 1.0054x over previous
//
#include <hip/hip_runtime.h>
#include <hip/hip_fp16.h>
#include <math.h>

#define DEV __device__ __forceinline__

constexpr int NGAUSS = 50;
constexpr int LAY = 6;
constexpr int K_TAB = 8192;                            // nearest-neighbor table
constexpr float DMAX = 40.0f;
constexpr float TSCALE = (float)(K_TAB - 1) / DMAX;    // knot = round(d * TSCALE)
constexpr float STEP = 6.0f / 49.0f;
constexpr float COEFF = -0.5f / (STEP * STEP);
constexpr float LN2F = 0.69314718055994531f;
constexpr float PI_OVER_CUT = 0.52359877559829887f;    // pi/6

using f16x8 = __attribute__((ext_vector_type(8))) _Float16;
using f16x4 = __attribute__((ext_vector_type(4))) _Float16;
using f32x4 = __attribute__((ext_vector_type(4))) float;
using f32x8 = __attribute__((ext_vector_type(8))) float;

#define MFMA16(a, b, c) __builtin_amdgcn_mfma_f32_16x16x32_f16(a, b, c, 0, 0, 0)

DEV float sspf(float x) {
    float ax = fabsf(x);
    float e = __expf(-ax);
    return fmaxf(x, 0.f) + __logf(1.f + e) - LN2F;
}

// ---- fp16 pack/unpack helpers (storage fp16, math f32) ----
DEV float4 ld_h4(const ushort* p) {          // 8B load -> 4 floats
    uint2 r = *(const uint2*)p;
    __half2 a = __builtin_bit_cast(__half2, r.x);
    __half2 b = __builtin_bit_cast(__half2, r.y);
    float2 fa = __half22float2(a), fb = __half22float2(b);
    return make_float4(fa.x, fa.y, fb.x, fb.y);
}

// ---------------- weight convert+transpose (fp32 [K][C] -> fp16 [C][K]) ----------------
__global__ void k_cvtT128(const float* __restrict__ src, ushort* __restrict__ dst) {
    const float* s = src + (size_t)blockIdx.x * 16384;
    ushort* d = dst + (size_t)blockIdx.x * 16384;
    for (int i = threadIdx.x; i < 16384; i += 256) {
        int k = i >> 7, c = i & 127;
        d[(c << 7) + k] = __builtin_bit_cast(ushort, (_Float16)s[i]);
    }
}
__global__ void k_cvtT_fe(const float* __restrict__ src, ushort* __restrict__ dst) {
    // fe_w2: [64][128] -> dst[c(128)][k(64)]
    for (int i = threadIdx.x; i < 8192; i += 256) {
        int k = i >> 7, c = i & 127;
        dst[(c << 6) + k] = __builtin_bit_cast(ushort, (_Float16)src[i]);
    }
}
__global__ void k_cvtT_w1(const float* __restrict__ src, ushort* __restrict__ dst) {
    // mlp_w1: [50][128] -> dst[c(128)][k(64)], zero-padded k>=50
    const float* s = src + (size_t)blockIdx.x * (NGAUSS * 128);
    ushort* d = dst + (size_t)blockIdx.x * (128 * 64);
    for (int i = threadIdx.x; i < 128 * 64; i += 256) {
        int c = i >> 6, k = i & 63;
        float v = (k < NGAUSS) ? s[k * 128 + c] : 0.f;
        d[(c << 6) + k] = __builtin_bit_cast(ushort, (_Float16)v);
    }
}

// ---------------- edge prep: geometry + hist + rank in ONE pass ----------------
// pay_aux[e] = { src | knot<<16 , dst | rank<<16 }  (N<65536, deg<65536, K_TAB<=65536)
__global__ void k_prep(const int* __restrict__ ei, const float* __restrict__ pos,
                       int* __restrict__ counts, uint2* __restrict__ pay_aux, int E) {
    int e = blockIdx.x * 256 + threadIdx.x;
    if (e >= E) return;
    int r = ei[e], c = ei[E + e];
    float dx = pos[3 * r + 0] - pos[3 * c + 0];
    float dy = pos[3 * r + 1] - pos[3 * c + 1];
    float dz = pos[3 * r + 2] - pos[3 * c + 2];
    float d = sqrtf(dx * dx + dy * dy + dz * dz);
    int i0 = (int)(d * TSCALE + 0.5f);
    if (i0 > K_TAB - 1) i0 = K_TAB - 1;
    int rk = atomicAdd(&counts[c], 1);
    pay_aux[e] = make_uint2((uint)r | ((uint)i0 << 16), (uint)c | ((uint)rk << 16));
}

__global__ void k_scan1(const int* __restrict__ counts, int* __restrict__ locex,
                        int* __restrict__ bsum, int n) {
    __shared__ int s_wsum[16];
    const int tid = threadIdx.x;
    const int i = blockIdx.x * 1024 + tid;
    const int lane = tid & 63, wv = tid >> 6;
    int v = (i < n) ? counts[i] : 0;
    int x = v;
    #pragma unroll
    for (int off = 1; off < 64; off <<= 1) {
        int y = __shfl_up(x, off, 64);
        if (lane >= off) x += y;
    }
    if (lane == 63) s_wsum[wv] = x;
    __syncthreads();
    if (wv == 0 && lane < 16) {
        int wval = s_wsum[lane];
        int wx = wval;
        #pragma unroll
        for (int off = 1; off < 16; off <<= 1) {
            int wy = __shfl_up(wx, off, 16);
            if (lane >= off) wx += wy;
        }
        s_wsum[lane] = wx - wval;
    }
    __syncthreads();
    if (i < n) locex[i] = s_wsum[wv] + x - v;
    if (tid == 1023) bsum[blockIdx.x] = s_wsum[15] + x;
}

__global__ void k_scan2(int* __restrict__ bsum, int nb) {
    __shared__ int s_wsum[16];
    const int tid = threadIdx.x;
    const int lane = tid & 63, wv = tid >> 6;
    int v = (tid < nb) ? bsum[tid] : 0;
    int x = v;
    #pragma unroll
    for (int off = 1; off < 64; off <<= 1) {
        int y = __shfl_up(x, off, 64);
        if (lane >= off) x += y;
    }
    if (lane == 63) s_wsum[wv] = x;
    __syncthreads();
    if (wv == 0 && lane < 16) {
        int wval = s_wsum[lane];
        int wx = wval;
        #pragma unroll
        for (int off = 1; off < 16; off <<= 1) {
            int wy = __shfl_up(wx, off, 16);
            if (lane >= off) wx += wy;
        }
        s_wsum[lane] = wx - wval;
    }
    __syncthreads();
    if (tid < nb) bsum[tid] = s_wsum[wv] + x - v;
}

__global__ void k_scan3(const int* __restrict__ locex, const int* __restrict__ bsumex,
                        int* __restrict__ rowptr, int n) {
    int i = blockIdx.x * 256 + threadIdx.x;
    if (i >= n) return;
    rowptr[i] = locex[i] + bsumex[i >> 10];
}

// scatter: pure permutation. p = rowptr[dst] + rank
__global__ void k_scatter(const uint2* __restrict__ pay_aux, const int* __restrict__ rowptr,
                          uint* __restrict__ s_ef, int E) {
    int e = blockIdx.x * 256 + threadIdx.x;
    if (e >= E) return;
    uint2 a = pay_aux[e];
    int dst = (int)(a.y & 0xFFFFu);
    int rk  = (int)(a.y >> 16);
    s_ef[rowptr[dst] + rk] = a.x;
}

// ---------------- gate table build: all-MFMA ----------------
// 32 knots per block; grid = LAY * (K_TAB/32)
__launch_bounds__(256)
__global__ void k_tab_all(const ushort* __restrict__ w1TA, const float* __restrict__ b1A,
                          const ushort* __restrict__ w2TA, const float* __restrict__ b2A,
                          ushort* __restrict__ tabA) {
    const int layer = blockIdx.x / (K_TAB / 32);
    const int k0 = (blockIdx.x % (K_TAB / 32)) * 32;
    const ushort* w1T = w1TA + (size_t)layer * 8192;    // [128][64] fp16
    const float* b1 = b1A + (size_t)layer * 128;
    const ushort* w2T = w2TA + (size_t)layer * 16384;   // [128][128] fp16
    const float* b2 = b2A + (size_t)layer * 128;
    ushort* tab = tabA + (size_t)layer * K_TAB * 128;

    constexpr int LDD = 72;
    constexpr int LDP = 136;
    __shared__ _Float16 sD[32 * LDD];   // demb fp16, K padded to 64 (4.5 KB)
    __shared__ _Float16 sT[32 * LDP];   // t1 fp16 (8.7 KB)
    __shared__ float s_cc[32];
    const int tid = threadIdx.x;

    for (int i = tid; i < 32 * 64; i += 256) {
        int r = i >> 6, g = i & 63;
        float val = 0.f;
        if (g < NGAUSS) {
            float d = (float)(k0 + r) * (1.0f / TSCALE);
            float t = d - g * STEP;
            val = __expf(COEFF * t * t);
        }
        sD[r * LDD + g] = (_Float16)val;
    }
    if (tid < 32) {
        float d = (float)(k0 + tid) * (1.0f / TSCALE);
        s_cc[tid] = 0.5f * (__cosf(d * PI_OVER_CUT) + 1.0f);
    }
    __syncthreads();

    const int wid = tid >> 6, lane = tid & 63;
    const int lr = lane & 15, lg = lane >> 4;
    const int kof = lg << 3;

    // GEMM1 (MFMA, K=64): t1 = ssp(demb @ w1 + b1) -> sT
    #pragma unroll
    for (int cb = 0; cb < 2; cb++) {
        const int col = ((2 * wid + cb) << 4) + lr;
        const ushort* bp = w1T + ((size_t)col << 6);
        f16x8 B0 = *(const f16x8*)(bp + kof);
        f16x8 B1 = *(const f16x8*)(bp + 32 + kof);
        float bb = b1[col];
        #pragma unroll
        for (int rt = 0; rt < 2; rt++) {
            const _Float16* ap = &sD[((rt << 4) + lr) * LDD + kof];
            f32x4 c = {0.f, 0.f, 0.f, 0.f};
            c = MFMA16(*(const f16x8*)ap, B0, c);
            c = MFMA16(*(const f16x8*)(ap + 32), B1, c);
            #pragma unroll
            for (int r = 0; r < 4; r++)
                sT[((rt << 4) + (lg << 2) + r) * LDP + col] = (_Float16)sspf(c[r] + bb);
        }
    }
    __syncthreads();

    // GEMM2 (MFMA, K=128): W = (t1 @ w2 + b2) * cosC -> tab
    #pragma unroll
    for (int cb = 0; cb < 2; cb++) {
        const int col = ((2 * wid + cb) << 4) + lr;
        const ushort* bp = w2T + ((size_t)col << 7);
        f16x8 B0 = *(const f16x8*)(bp + kof);
        f16x8 B1 = *(const f16x8*)(bp + 32 + kof);
        f16x8 B2 = *(const f16x8*)(bp + 64 + kof);
        f16x8 B3 = *(const f16x8*)(bp + 96 + kof);
        float bb = b2[col];
        #pragma unroll
        for (int rt = 0; rt < 2; rt++) {
            const _Float16* ap = &sT[((rt << 4) + lr) * LDP + kof];
            f32x4 c = {0.f, 0.f, 0.f, 0.f};
            c = MFMA16(*(const f16x8*)ap, B0, c);
            c = MFMA16(*(const f16x8*)(ap + 32), B1, c);
            c = MFMA16(*(const f16x8*)(ap + 64), B2, c);
            c = MFMA16(*(const f16x8*)(ap + 96), B3, c);
            #pragma unroll
            for (int r = 0; r < 4; r++) {
                int kr = (rt << 4) + (lg << 2) + r;
                tab[((size_t)(k0 + kr) << 7) + col] =
                    __builtin_bit_cast(ushort, (_Float16)((c[r] + bb) * s_cc[kr]));
            }
        }
    }
}

// ---------------- node-centric CSR edge kernel: full wave per node, 4 edge-parities ----------------
__launch_bounds__(256, 8)
__global__ void k_edge_csr(const uint* __restrict__ s_ef,
                           const int* __restrict__ rowptr, const int* __restrict__ counts,
                           const ushort* __restrict__ vlin, const ushort* __restrict__ tab,
                           ushort* __restrict__ agg, int N) {
    const int tid = threadIdx.x;
    const int lane = tid & 63;
    const int h = lane >> 4;         // 0..3: edge parity
    const int lc = lane & 15;        // channel octet: channels 8lc..8lc+7
    const int n = blockIdx.x * 4 + (tid >> 6);
    if (n >= N) return;
    const ushort* tabc = tab + (lc << 3);
    const ushort* vlc  = vlin + (lc << 3);

    const int rs = rowptr[n];
    const int re = rs + counts[n];
    f32x8 acc = {0.f, 0.f, 0.f, 0.f, 0.f, 0.f, 0.f, 0.f};

    int e = rs + h;
    for (; e + 12 < re; e += 16) {
        f16x8 TP[4], VL[4];
        #pragma unroll
        for (int j = 0; j < 4; j++) {
            uint pk = s_ef[e + 4 * j];
            TP[j] = *(const f16x8*)(tabc + ((size_t)(pk >> 16) << 7));
            VL[j] = *(const f16x8*)(vlc + ((size_t)(pk & 0xFFFFu) << 7));
        }
        f16x8 p0 = TP[0] * VL[0];
        p0 += TP[1] * VL[1];
        f16x8 p1 = TP[2] * VL[2];
        p1 += TP[3] * VL[3];
        acc += __builtin_convertvector(p0, f32x8);
        acc += __builtin_convertvector(p1, f32x8);
    }
    for (; e < re; e += 4) {
        uint pk = s_ef[e];
        f16x8 tp = *(const f16x8*)(tabc + ((size_t)(pk >> 16) << 7));
        f16x8 vl = *(const f16x8*)(vlc + ((size_t)(pk & 0xFFFFu) << 7));
        acc += __builtin_convertvector(tp * vl, f32x8);
    }
    #pragma unroll
    for (int i = 0; i < 8; i++) {
        acc[i] += __shfl_xor(acc[i], 16);
        acc[i] += __shfl_xor(acc[i], 32);
    }
    if (h == 0) {
        f16x8 o;
        #pragma unroll
        for (int i = 0; i < 8; i++) o[i] = (_Float16)acc[i];
        *(f16x8*)&agg[((size_t)n << 7) + (lc << 3)] = o;
    }
}

// ---------------- feature embedding ----------------
__global__ void k_fe1(const float* __restrict__ x, const float* __restrict__ w,
                      const float* __restrict__ b, float* __restrict__ h, int N) {
    int idx = blockIdx.x * 256 + threadIdx.x;
    if (idx >= N * 64) return;
    int n = idx >> 6, c = idx & 63;
    const float* xr = x + (size_t)n * 28;
    float acc = b[c];
    #pragma unroll
    for (int k = 0; k < 28; k++) acc = fmaf(xr[k], w[k * 64 + c], acc);
    h[idx] = acc;
}

__global__ void k_bnstat(const float* __restrict__ h, float* __restrict__ stats, int N) {
    __shared__ float s_s[256], s_q[256];
    int tid = threadIdx.x;
    int c = tid & 63, g = tid >> 6;
    float s = 0.f, q = 0.f;
    for (int n = blockIdx.x * 4 + g; n < N; n += gridDim.x * 4) {
        float v = h[(size_t)n * 64 + c];
        s += v; q += v * v;
    }
    s_s[tid] = s; s_q[tid] = q;
    __syncthreads();
    if (tid < 64) {
        s = s_s[tid] + s_s[tid + 64] + s_s[tid + 128] + s_s[tid + 192];
        q = s_q[tid] + s_q[tid + 64] + s_q[tid + 128] + s_q[tid + 192];
        atomicAdd(&stats[tid], s);
        atomicAdd(&stats[64 + tid], q);
    }
}

__global__ void k_bnfin(const float* __restrict__ stats, float* __restrict__ prm,
                        const float* __restrict__ gamma, const float* __restrict__ beta,
                        float invN) {
    int c = threadIdx.x;  // 64 threads
    float mu = stats[c] * invN;
    float var = stats[64 + c] * invN - mu * mu;
    float sc = gamma[c] * rsqrtf(var + 1e-5f);
    prm[c] = sc;
    prm[64 + c] = beta[c] - mu * sc;
}

// ---------------- MFMA fe2: v16 = relu( relu(bn(h)) @ fe_w2 + b2 ), K=64 ----------------
__launch_bounds__(256, 4)
__global__ void k_fe2(const float* __restrict__ h, const float* __restrict__ prm,
                      const ushort* __restrict__ w2T, const float* __restrict__ b2,
                      ushort* __restrict__ v16, int N) {
    constexpr int LDP = 72;
    __shared__ _Float16 sH[64 * LDP];
    const int tid = threadIdx.x;
    const int n0 = blockIdx.x * 64;

    for (int i = tid; i < 64 * 16; i += 256) {
        int row = i >> 4, c4 = (i & 15) << 2;
        int gr = n0 + row;
        float4 hv = (gr < N) ? *(const float4*)&h[((size_t)gr << 6) + c4]
                             : make_float4(0.f, 0.f, 0.f, 0.f);
        float4 sc = *(const float4*)&prm[c4];
        float4 sh = *(const float4*)&prm[64 + c4];
        f16x4 o;
        o[0] = (_Float16)fmaxf(fmaf(hv.x, sc.x, sh.x), 0.f);
        o[1] = (_Float16)fmaxf(fmaf(hv.y, sc.y, sh.y), 0.f);
        o[2] = (_Float16)fmaxf(fmaf(hv.z, sc.z, sh.z), 0.f);
        o[3] = (_Float16)fmaxf(fmaf(hv.w, sc.w, sh.w), 0.f);
        *(f16x4*)&sH[row * LDP + c4] = o;
    }
    __syncthreads();

    const int wid = tid >> 6, lane = tid & 63;
    const int lr = lane & 15, lg = lane >> 4;
    const int kof = lg << 3;
    const int arow = wid * 16 + lr;
    const int drow0 = wid * 16 + (lg << 2);

    f16x8 a0 = *(const f16x8*)&sH[arow * LDP + kof];
    f16x8 a1 = *(const f16x8*)&sH[arow * LDP + 32 + kof];

    #pragma unroll
    for (int n = 0; n < 8; n++) {
        const ushort* bp = w2T + (((size_t)(n << 4) + lr) << 6);
        f32x4 c = {0.f, 0.f, 0.f, 0.f};
        c = MFMA16(a0, *(const f16x8*)(bp + kof), c);
        c = MFMA16(a1, *(const f16x8*)(bp + 32 + kof), c);
        int col = (n << 4) + lr;
        float bb = b2[col];
        #pragma unroll
        for (int r = 0; r < 4; r++) {
            int gr = n0 + drow0 + r;
            if (gr < N) v16[((size_t)gr << 7) + col] =
                __builtin_bit_cast(ushort, (_Float16)fmaxf(c[r] + bb, 0.f));
        }
    }
}

// ---------------- MFMA single GEMM: vlin(fp16) = v16 @ lin, K=128 ----------------
__launch_bounds__(256, 4)
__global__ void k_gemm_rb(const ushort* __restrict__ A, const ushort* __restrict__ wT,
                          ushort* __restrict__ C, int N) {
    constexpr int LDP = 136;
    __shared__ _Float16 sA[64 * LDP];
    const int tid = threadIdx.x;
    const int n0 = blockIdx.x * 64;

    for (int i = tid; i < 64 * 32; i += 256) {
        int row = i >> 5, c4 = (i & 31) << 2;
        int gr = n0 + row;
        uint2 val = (gr < N) ? *(const uint2*)&A[((size_t)gr << 7) + c4]
                             : make_uint2(0u, 0u);
        *(uint2*)&sA[row * LDP + c4] = val;
    }
    __syncthreads();

    const int wid = tid >> 6, lane = tid & 63;
    const int lr = lane & 15, lg = lane >> 4;
    const int kof = lg << 3;
    const int arow = wid * 16 + lr;
    const int drow0 = wid * 16 + (lg << 2);

    f16x8 a0 = *(const f16x8*)&sA[arow * LDP + kof];
    f16x8 a1 = *(const f16x8*)&sA[arow * LDP + 32 + kof];
    f16x8 a2 = *(const f16x8*)&sA[arow * LDP + 64 + kof];
    f16x8 a3 = *(const f16x8*)&sA[arow * LDP + 96 + kof];

    #pragma unroll
    for (int n = 0; n < 8; n++) {
        const ushort* bp = wT + (((size_t)(n << 4) + lr) << 7);
        f32x4 c = {0.f, 0.f, 0.f, 0.f};
        c = MFMA16(a0, *(const f16x8*)(bp + kof), c);
        c = MFMA16(a1, *(const f16x8*)(bp + 32 + kof), c);
        c = MFMA16(a2, *(const f16x8*)(bp + 64 + kof), c);
        c = MFMA16(a3, *(const f16x8*)(bp + 96 + kof), c);
        int col = (n << 4) + lr;
        #pragma unroll
        for (int r = 0; r < 4; r++) {
            int gr = n0 + drow0 + r;
            if (gr < N) C[((size_t)gr << 7) + col] =
                __builtin_bit_cast(ushort, (_Float16)c[r]);
        }
    }
}

// ---------------- MFMA fused layer update: 1 wave per 16-col block ----------------
__launch_bounds__(512, 8)
__global__ void k_update(const ushort* __restrict__ agg,
                         const ushort* __restrict__ w1T, const float* __restrict__ b1,
                         const ushort* __restrict__ w2T, const float* __restrict__ b2,
                         ushort* __restrict__ v16,
                         const ushort* __restrict__ linT, ushort* __restrict__ vlin, int N) {
    constexpr int LDP = 136;
    __shared__ _Float16 sA[64 * LDP];   // 17.4 KB
    __shared__ _Float16 sB[64 * LDP];   // 17.4 KB
    const int tid = threadIdx.x;
    const int n0 = blockIdx.x * 64;

    for (int i = tid; i < 64 * 32; i += 512) {
        int row = i >> 5, c4 = (i & 31) << 2;
        int gr = n0 + row;
        uint2 a = (gr < N) ? *(const uint2*)&agg[((size_t)gr << 7) + c4] : make_uint2(0u, 0u);
        uint2 b = (gr < N) ? *(const uint2*)&v16[((size_t)gr << 7) + c4] : make_uint2(0u, 0u);
        *(uint2*)&sA[row * LDP + c4] = a;
        *(uint2*)&sB[row * LDP + c4] = b;
    }
    __syncthreads();

    const int wid = tid >> 6, lane = tid & 63;
    const int lr = lane & 15, lg = lane >> 4;
    const int kof = lg << 3;
    const int col = (wid << 4) + lr;
    const int dr0 = lg << 2;

    f32x4 acc[4];

    // ---- GEMM 1: t = ssp(agg @ W1 + b1) ----
    {
        const ushort* bp = w1T + ((size_t)col << 7);
        f16x8 B0 = *(const f16x8*)(bp + kof);
        f16x8 B1 = *(const f16x8*)(bp + 32 + kof);
        f16x8 B2 = *(const f16x8*)(bp + 64 + kof);
        f16x8 B3 = *(const f16x8*)(bp + 96 + kof);
        #pragma unroll
        for (int rb = 0; rb < 4; rb++) {
            const _Float16* ap = &sA[((rb << 4) + lr) * LDP + kof];
            f32x4 c = {0.f, 0.f, 0.f, 0.f};
            c = MFMA16(*(const f16x8*)ap, B0, c);
            c = MFMA16(*(const f16x8*)(ap + 32), B1, c);
            c = MFMA16(*(const f16x8*)(ap + 64), B2, c);
            c = MFMA16(*(const f16x8*)(ap + 96), B3, c);
            acc[rb] = c;
        }
    }
    __syncthreads();
    {
        float bb = b1[col];
        #pragma unroll
        for (int rb = 0; rb < 4; rb++) {
            #pragma unroll
            for (int r = 0; r < 4; r++)
                sA[((rb << 4) + dr0 + r) * LDP + col] = (_Float16)sspf(acc[rb][r] + bb);
        }
    }
    __syncthreads();

    // ---- GEMM 2: v_new = t @ W2 + b2 + v_old ----
    {
        const ushort* bp = w2T + ((size_t)col << 7);
        f16x8 B0 = *(const f16x8*)(bp + kof);
        f16x8 B1 = *(const f16x8*)(bp + 32 + kof);
        f16x8 B2 = *(const f16x8*)(bp + 64 + kof);
        f16x8 B3 = *(const f16x8*)(bp + 96 + kof);
        #pragma unroll
        for (int rb = 0; rb < 4; rb++) {
            const _Float16* ap = &sA[((rb << 4) + lr) * LDP + kof];
            f32x4 c = {0.f, 0.f, 0.f, 0.f};
            c = MFMA16(*(const f16x8*)ap, B0, c);
            c = MFMA16(*(const f16x8*)(ap + 32), B1, c);
            c = MFMA16(*(const f16x8*)(ap + 64), B2, c);
            c = MFMA16(*(const f16x8*)(ap + 96), B3, c);
            acc[rb] = c;
        }
    }
    {
        float bb = b2[col];
        #pragma unroll
        for (int rb = 0; rb < 4; rb++) {
            #pragma unroll
            for (int r = 0; r < 4; r++) {
                _Float16* p = &sB[((rb << 4) + dr0 + r) * LDP + col];
                *p = (_Float16)(acc[rb][r] + bb + (float)*p);
            }
        }
    }
    __syncthreads();

    if (!linT) {
        for (int i = tid; i < 64 * 32; i += 512) {
            int row = i >> 5, c4 = (i & 31) << 2;
            int gr = n0 + row;
            if (gr < N) *(uint2*)&v16[((size_t)gr << 7) + c4] = *(const uint2*)&sB[row * LDP + c4];
        }
        return;
    }

    // ---- GEMM 3 first (reads sB), then drain the v16 copy under its latency ----
    {
        const ushort* bp = linT + ((size_t)col << 7);
        f16x8 B0 = *(const f16x8*)(bp + kof);
        f16x8 B1 = *(const f16x8*)(bp + 32 + kof);
        f16x8 B2 = *(const f16x8*)(bp + 64 + kof);
        f16x8 B3 = *(const f16x8*)(bp + 96 + kof);
        #pragma unroll
        for (int rb = 0; rb < 4; rb++) {
            const _Float16* ap = &sB[((rb << 4) + lr) * LDP + kof];
            f32x4 c = {0.f, 0.f, 0.f, 0.f};
            c = MFMA16(*(const f16x8*)ap, B0, c);
            c = MFMA16(*(const f16x8*)(ap + 32), B1, c);
            c = MFMA16(*(const f16x8*)(ap + 64), B2, c);
            c = MFMA16(*(const f16x8*)(ap + 96), B3, c);
            acc[rb] = c;
        }
    }
    // coalesced store sB -> v16 (overlaps with MFMA results latency)
    for (int i = tid; i < 64 * 32; i += 512) {
        int row = i >> 5, c4 = (i & 31) << 2;
        int gr = n0 + row;
        if (gr < N) *(uint2*)&v16[((size_t)gr << 7) + c4] = *(const uint2*)&sB[row * LDP + c4];
    }
    // park GEMM3 output in sA (t-tile reads finished before last barrier)
    #pragma unroll
    for (int rb = 0; rb < 4; rb++) {
        #pragma unroll
        for (int r = 0; r < 4; r++)
            sA[((rb << 4) + dr0 + r) * LDP + col] = (_Float16)acc[rb][r];
    }
    __syncthreads();

    for (int i = tid; i < 64 * 32; i += 512) {
        int row = i >> 5, c4 = (i & 31) << 2;
        int gr = n0 + row;
        if (gr < N) *(uint2*)&vlin[((size_t)gr << 7) + c4] = *(const uint2*)&sA[row * LDP + c4];
    }
}

// ---------------- tiled fused readout (v16 input) ----------------
__launch_bounds__(256, 4)
__global__ void k_uout(const ushort* __restrict__ v16, const float* __restrict__ u1w,
                       const float* __restrict__ u1b, const float* __restrict__ u2w,
                       const float* __restrict__ u2b, const int* __restrict__ batch,
                       float* __restrict__ out, int N) {
    __shared__ float sA[64 * 128];
    const int tid = threadIdx.x;
    const int n0 = blockIdx.x * 64;

    for (int i = tid; i < 64 * 32; i += 256) {
        int row = i >> 5, cq = (i & 31) << 2;
        int gr = n0 + row;
        float4 val = make_float4(0.f, 0.f, 0.f, 0.f);
        if (gr < N) val = ld_h4(&v16[((size_t)gr << 7) + cq]);
        *(float4*)&sA[row * 128 + cq] = val;
    }
    __syncthreads();

    const int cg = tid & 31, rg = tid >> 5;
    const int r0 = rg << 3;
    const int c2 = cg << 1;

    float2 acc[8];
    {
        float2 b1v = *(const float2*)&u1b[c2];
        #pragma unroll
        for (int i = 0; i < 8; i++) acc[i] = b1v;
        #pragma unroll 4
        for (int k = 0; k < 128; k++) {
            float2 wv = *(const float2*)&u1w[(k << 6) + c2];
            #pragma unroll
            for (int i = 0; i < 8; i++) {
                float a = sA[(r0 + i) * 128 + k];
                acc[i].x = fmaf(a, wv.x, acc[i].x);
                acc[i].y = fmaf(a, wv.y, acc[i].y);
            }
        }
    }
    __syncthreads();
    #pragma unroll
    for (int i = 0; i < 8; i++) {
        sA[(r0 + i) * 64 + c2 + 0] = sspf(acc[i].x);
        sA[(r0 + i) * 64 + c2 + 1] = sspf(acc[i].y);
    }
    __syncthreads();

    float acc2[8];
    {
        float bb = u2b[cg];
        #pragma unroll
        for (int i = 0; i < 8; i++) acc2[i] = bb;
        #pragma unroll 4
        for (int k = 0; k < 64; k++) {
            float wv = u2w[(k << 5) + cg];
            #pragma unroll
            for (int i = 0; i < 8; i++)
                acc2[i] = fmaf(sA[(r0 + i) * 64 + k], wv, acc2[i]);
        }
    }

    int cur = -1;
    float run = 0.f;
    #pragma unroll
    for (int i = 0; i < 8; i++) {
        int gr = n0 + r0 + i;
        int g = (gr < N) ? batch[gr] : -1;
        if (g != cur) {
            if (cur >= 0) atomicAdd(&out[(size_t)cur * 32 + cg], run);
            cur = g;
            run = 0.f;
        }
        if (g >= 0) run += acc2[i];
    }
    if (cur >= 0) atomicAdd(&out[(size_t)cur * 32 + cg], run);
}

extern "C" void kernel_launch(void* const* d_in, const int* in_sizes, int n_in,
                              void* d_out, int out_size, void* d_ws, size_t ws_size,
                              hipStream_t stream) {
    const float* x      = (const float*)d_in[0];
    const float* pos    = (const float*)d_in[1];
    const int*   batch  = (const int*)d_in[2];
    const int*   ei     = (const int*)d_in[3];
    const float* fe_w1  = (const float*)d_in[4];
    const float* fe_b1  = (const float*)d_in[5];
    const float* bn_g   = (const float*)d_in[6];
    const float* bn_b   = (const float*)d_in[7];
    const float* fe_w2  = (const float*)d_in[8];
    const float* fe_b2  = (const float*)d_in[9];
    const float* lin_w  = (const float*)d_in[10];
    const float* mlp_w1 = (const float*)d_in[11];
    const float* mlp_b1 = (const float*)d_in[12];
    const float* mlp_w2 = (const float*)d_in[13];
    const float* mlp_b2 = (const float*)d_in[14];
    const float* v1_w   = (const float*)d_in[15];
    const float* v1_b   = (const float*)d_in[16];
    const float* v2_w   = (const float*)d_in[17];
    const float* v2_b   = (const float*)d_in[18];
    const float* u1_w   = (const float*)d_in[19];
    const float* u1_b   = (const float*)d_in[20];
    const float* u2_w   = (const float*)d_in[21];
    const float* u2_b   = (const float*)d_in[22];

    const int N = in_sizes[0] / 28;
    const int E = in_sizes[3] / 2;
    const int NB1 = (N + 1023) / 1024;

    char* ws = (char*)d_ws;
    size_t o = 0;
    auto alloc = [&](size_t bytes) { void* p = ws + o; o += (bytes + 255) & ~(size_t)255; return p; };
    int*    counts = (int*)   alloc((size_t)N * 4);
    int*    rowptr = (int*)   alloc((size_t)N * 4);
    int*    bsum   = (int*)   alloc((size_t)NB1 * 4);
    uint2*  payA   = (uint2*) alloc((size_t)E * 8);
    uint*   s_ef   = (uint*)  alloc((size_t)E * 4);
    float*  stats  = (float*) alloc(128 * 4);
    float*  prm    = (float*) alloc(128 * 4);
    ushort* tab    = (ushort*)alloc((size_t)LAY * K_TAB * 128 * 2);  // 12.5 MB fp16 (NN)
    ushort* v16    = (ushort*)alloc((size_t)N * 128 * 2);            // fp16 node state
    ushort* vlin   = (ushort*)alloc((size_t)N * 128 * 2);            // fp16
    ushort* agg    = (ushort*)alloc((size_t)N * 128 * 2);            // fp16
    float*  h      = (float*) alloc((size_t)N * 64 * 4);
    int*    locex  = (int*)   alloc((size_t)N * 4);
    ushort* v1T    = (ushort*)alloc((size_t)LAY * 16384 * 2);   // fp16 transposed weights
    ushort* v2T    = (ushort*)alloc((size_t)LAY * 16384 * 2);
    ushort* linT   = (ushort*)alloc((size_t)LAY * 16384 * 2);
    ushort* mw2T   = (ushort*)alloc((size_t)LAY * 16384 * 2);   // mlp_w2 fp16 [c][k]
    ushort* mw1T   = (ushort*)alloc((size_t)LAY * 8192 * 2);    // mlp_w1 fp16 [c][64]
    ushort* fe2T   = (ushort*)alloc((size_t)8192 * 2);

    // -------- weight conversion (fp16, transposed) --------
    k_cvtT128<<<LAY, 256, 0, stream>>>(v1_w, v1T);
    k_cvtT128<<<LAY, 256, 0, stream>>>(v2_w, v2T);
    k_cvtT128<<<LAY, 256, 0, stream>>>(lin_w, linT);
    k_cvtT128<<<LAY, 256, 0, stream>>>(mlp_w2, mw2T);
    k_cvtT_w1<<<LAY, 256, 0, stream>>>(mlp_w1, mw1T);
    k_cvtT_fe<<<1, 256, 0, stream>>>(fe_w2, fe2T);

    // -------- one-time edge sort (dst-ordered CSR; fused geometry prep) --------
    hipMemsetAsync(counts, 0, (size_t)N * 4, stream);
    k_prep<<<(E + 255) / 256, 256, 0, stream>>>(ei, pos, counts, payA, E);
    k_scan1<<<NB1, 1024, 0, stream>>>(counts, locex, bsum, N);
    k_scan2<<<1, 1024, 0, stream>>>(bsum, NB1);
    k_scan3<<<(N + 255) / 256, 256, 0, stream>>>(locex, bsum, rowptr, N);
    k_scatter<<<(E + 255) / 256, 256, 0, stream>>>(payA, rowptr, s_ef, E);

    // -------- gate tables (fp16, nearest-neighbor, all-MFMA) --------
    k_tab_all<<<LAY * (K_TAB / 32), 256, 0, stream>>>(mw1T, mlp_b1, mw2T, mlp_b2, tab);

    // -------- feature embedding --------
    hipMemsetAsync(stats, 0, 128 * 4, stream);
    k_fe1<<<(N * 64 + 255) / 256, 256, 0, stream>>>(x, fe_w1, fe_b1, h, N);
    k_bnstat<<<256, 256, 0, stream>>>(h, stats, N);
    k_bnfin<<<1, 64, 0, stream>>>(stats, prm, bn_g, bn_b, 1.0f / (float)N);
    const int gblk = (N + 63) / 64;
    k_fe2<<<gblk, 256, 0, stream>>>(h, prm, fe2T, fe_b2, v16, N);

    // vlin for layer 0
    k_gemm_rb<<<gblk, 256, 0, stream>>>(v16, linT, vlin, N);

    // -------- interaction layers --------
    const int eblk = (N + 3) / 4;
    for (int l = 0; l < LAY; l++) {
        k_edge_csr<<<eblk, 256, 0, stream>>>(
            s_ef, rowptr, counts, vlin,
            tab + (size_t)l * K_TAB * 128, agg, N);
        const ushort* lin_next = (l + 1 < LAY) ? linT + (size_t)(l + 1) * 16384 : nullptr;
        k_update<<<gblk, 512, 0, stream>>>(
            agg, v1T + (size_t)l * 16384, v1_b + (size_t)l * 128,
            v2T + (size_t)l * 16384, v2_b + (size_t)l * 128,
            v16, lin_next, vlin, N);
    }

    // -------- fused readout --------
    hipMemsetAsync(d_out, 0, (size_t)out_size * 4, stream);
    k_uout<<<gblk, 256, 0, stream>>>(v16, u1_w, u1_b, u2_w, u2_b, batch, (float*)d_out, N);
}